// Round 4
// baseline (5859.376 us; speedup 1.0000x reference)
//
#include <hip/hip_runtime.h>
#include <math.h>

#define TPB 1024
#define NBLK 160
#define NBATCH 32
#define NT 64
#define NH 512
#define NM 128
#define NR 4
#define NW 64
#define NI 768          // controller input size (H + R*W)
#define NXI 471         // interface vector size
#define EPSF 1e-6f
#define MS 65           // mem row stride (+1 pad)

// roles: [0,32) state (xi+DNC+out) | [32,160) gates blocks (4 units x 4 gates + LSTM)

typedef float f4 __attribute__((ext_vector_type(4)));

// ws layout (float offsets). pub* parity double-buffered.
#define WS_PUBH  0                                 // [2][32][512] (written by gates)
#define WS_PUBRV (WS_PUBH + 2*NBATCH*NH)           // [2][32][256]
#define WS_FLAGS (WS_PUBRV + 2*NBATCH*NR*NW)
// packed flag dwords: 16 flags per 64B line (parallel coalesced polls)
#define D_G 0        // 128 gate blocks: h(t) published -> t+1
#define D_R 128      // 32 state blocks: rv(t) published -> t+1
#define D_TOTAL 160

__device__ __forceinline__ float sigm(float x){ return 1.0f/(1.0f+expf(-x)); }
__device__ __forceinline__ float sftp(float x){ return fmaxf(x,0.0f)+log1pf(expf(-fabsf(x))); }
__device__ __forceinline__ float dot4(f4 a, f4 b){
    return a.x*b.x + a.y*b.y + a.z*b.z + a.w*b.w;
}
__device__ __forceinline__ float wave_red(float v){
    #pragma unroll
    for (int o = 32; o > 0; o >>= 1) v += __shfl_down(v, o);
    return v;
}

// ---- coherent (LLC write-through, device-visible) accessors: sc0 sc1 ----
// waitcnt INSIDE each asm statement => no rule-18 hoist hazard.
__device__ __forceinline__ f4 cload4(const float* p){
    f4 v;
    asm volatile("global_load_dwordx4 %0, %1, off sc0 sc1\n\t"
                 "s_waitcnt vmcnt(0)"
                 : "=&v"(v) : "v"(p) : "memory");
    return v;
}
__device__ __forceinline__ void cload4x2(const float* p0, const float* p1,
                                         f4& a, f4& b){
    asm volatile("global_load_dwordx4 %0, %2, off sc0 sc1\n\t"
                 "global_load_dwordx4 %1, %3, off sc0 sc1\n\t"
                 "s_waitcnt vmcnt(0)"
                 : "=&v"(a), "=&v"(b) : "v"(p0), "v"(p1) : "memory");
}
__device__ __forceinline__ void cload4x4(const float* p0, const float* p1,
                                         const float* p2, const float* p3,
                                         f4& a, f4& b, f4& c, f4& d){
    asm volatile("global_load_dwordx4 %0, %4, off sc0 sc1\n\t"
                 "global_load_dwordx4 %1, %5, off sc0 sc1\n\t"
                 "global_load_dwordx4 %2, %6, off sc0 sc1\n\t"
                 "global_load_dwordx4 %3, %7, off sc0 sc1\n\t"
                 "s_waitcnt vmcnt(0)"
                 : "=&v"(a), "=&v"(b), "=&v"(c), "=&v"(d)
                 : "v"(p0), "v"(p1), "v"(p2), "v"(p3) : "memory");
}
__device__ __forceinline__ void cstore4(float* p, f4 v){
    asm volatile("global_store_dwordx4 %0, %1, off sc0 sc1"
                 :: "v"(p), "v"(v) : "memory");
}

// ---- packed-flag protocol: coalesced parallel polls, no RMW, no RELEASE ----
__device__ __forceinline__ void multi_wait_d(const unsigned int* f, int n,
                                             unsigned int tgt, int tid){
    if (tid < n) {
        const unsigned int* p = f + tid;          // consecutive dwords: coalesced
        while (__hip_atomic_load(p, __ATOMIC_RELAXED,
                                 __HIP_MEMORY_SCOPE_AGENT) < tgt)
            __builtin_amdgcn_s_sleep(2);
    }
    __syncthreads();
}
// all data stores are sc0 sc1 (write-through to coherence point); per-wave
// vmcnt(0) drain + barrier + RELAXED flag store is a correct release.
__device__ __forceinline__ void flag_set_d(unsigned int* f, unsigned int v, int tid){
    asm volatile("s_waitcnt vmcnt(0)" ::: "memory");
    __syncthreads();
    if (tid == 0)
        __hip_atomic_store(f, v, __ATOMIC_RELAXED, __HIP_MEMORY_SCOPE_AGENT);
}

__global__ void dnc_zero(float* ws){
    unsigned int* z = (unsigned int*)(ws + WS_FLAGS);
    for (int e = threadIdx.x; e < D_TOTAL; e += blockDim.x) z[e] = 0u;
}

// ---- pooled LDS (floats) ----
#define O_MEM  0        // 8320 (128 x 65)
#define O_H    8320     // 512
#define O_RW   8832     // 512
#define O_WWN  9344     // 128
#define O_USG  9472     // 128
#define O_PRC  9600     // 128
#define O_XI   9728     // 480
#define O_KEY  10208    // 256
#define O_WK   10464    // 64
#define O_ER   10528    // 64
#define O_WV   10592    // 64
#define O_RS   10656    // 4
#define O_FG   10660    // 4
#define O_MD   10664    // 12
#define O_NK   10676    // 4
#define O_SC   10680    // 8
#define O_NRM  10688    // 2 x 128 (double-buffered mem row norms)
#define O_WCW  10944    // 128
#define O_UU   11072    // 128
#define O_SU   11200    // 128 (su, then reused for alloc)
#define O_CUM  11328    // 128
#define O_RNK  11456    // 128 (int)
#define O_RNK4 11584    // 512 (int) rank partials
#define O_CCW  12096    // 512
#define O_FWD  12608    // 512
#define O_RWN  13120    // 512 (new read weights)
#define O_RV   13632    // 256
#define O_RED  13888    // 16
#define O_OS   13904    // 512 out staging
#define O_LK   14416    // 16384 link matrix
#define S_SZ   30800    // 123,200 B; 1 block/CU
// gates role (disjoint): x/rv staging S[0..8191]
#define G_ACC 8192      // [32][17] acc (stride 17: conflict-free LSTM reads)
#define G_C   8736      // [32][5]  cell state (stride 5: conflict-free)
#define G_H   8896      // 16384: all 32 batches' h(t-1)

__global__ __launch_bounds__(TPB) void dnc_pipe2(
    const float* __restrict__ x, const float* __restrict__ W_ih,
    const float* __restrict__ W_hh, const float* __restrict__ b_ih,
    const float* __restrict__ b_hh, const float* __restrict__ W_xi,
    const float* __restrict__ b_xi, const float* __restrict__ W_o,
    const float* __restrict__ b_o, float* __restrict__ out,
    float* __restrict__ ws)
{
    __shared__ __align__(16) float S[S_SZ];

    const int tid = threadIdx.x;
    const int wv  = tid >> 6;
    const int l   = tid & 63;
    const int bid = blockIdx.x;

    float* __restrict__ pubH  = ws + WS_PUBH;
    float* __restrict__ pubRV = ws + WS_PUBRV;
    unsigned int* __restrict__ FLGD = (unsigned int*)(ws + WS_FLAGS);

    if (bid < NBATCH) {
        // ========================= STATE block =========================
        const int b = bid;
        float* lk = S+O_LK;
        float* mem = S+O_MEM;  float* hS = S+O_H;
        float* rwS = S+O_RW;   float* wwN = S+O_WWN;
        float* usg = S+O_USG;  float* prc = S+O_PRC; float* xiS = S+O_XI;
        float* keys = S+O_KEY; float* wkey = S+O_WK; float* ers = S+O_ER;
        float* wvec = S+O_WV;  float* rstr = S+O_RS; float* fgte = S+O_FG;
        float* modes = S+O_MD; float* nkey = S+O_NK; float* sc = S+O_SC;
        float* nrm = S+O_NRM;  float* wcw = S+O_WCW;
        float* uu = S+O_UU;    float* su = S+O_SU;   float* cum = S+O_CUM;
        int*   rnk = (int*)(S+O_RNK);
        int*   rnk4 = (int*)(S+O_RNK4);
        float* ccw = S+O_CCW;  float* fwdT = S+O_FWD; float* rwN = S+O_RWN;
        float* rv = S+O_RV;    float* red = S+O_RED;  float* oS = S+O_OS;

        for (int e = tid; e < NM*NM; e += TPB) lk[e] = 0.0f;
        for (int e = tid; e < NM*NW; e += TPB) mem[(e>>6)*MS + (e&63)] = EPSF;
        for (int e = tid; e < NR*NM; e += TPB) rwS[e]=0.0f;
        for (int e = tid; e < NM; e += TPB){
            usg[e]=0.0f; prc[e]=0.0f;
            nrm[e] = 8.0f*EPSF;      // ||EPS row||_2 = sqrt(64*EPS^2)
        }
        __syncthreads();

        for (int t = 0; t < NT; ++t) {
            const int par = t & 1;
            float* nmo = nrm + 128*(t & 1);        // old norms = prev step's new
            float* nmn = nrm + 128*((t+1) & 1);

            // P0: h(t) ready from all 128 gate blocks; load h
            multi_wait_d(&FLGD[D_G], 128, (unsigned)(t+1), tid);
            if (tid < 128)
                *(f4*)&hS[tid*4] =
                    cload4(&pubH[(size_t)par*NBATCH*NH + b*NH + tid*4]);
            __syncthreads();

            // P1: xi(t) in-state: 30 rows/wave
            {
                const f4* H4 = (const f4*)hS;
                const int r0 = wv*30;
                #pragma unroll 5
                for (int i = 0; i < 30; ++i) {
                    const int row = r0 + i;
                    if (row < NXI) {
                        const f4* WX = (const f4*)(W_xi + (size_t)row*NH);
                        float a = dot4(WX[l], H4[l]) + dot4(WX[l+64], H4[l+64]);
                        a = wave_red(a);
                        if (l == 0) xiS[row] = a + b_xi[row];
                    }
                }
            }
            __syncthreads();

            // P2: E1 unpack interface
            if (tid < 256)       keys[tid] = tanhf(xiS[tid]);
            else if (tid < 260)  rstr[tid-256] = sftp(xiS[tid]);
            else if (tid < 324)  wkey[tid-260] = tanhf(xiS[tid]);
            else if (tid == 324) sc[0] = sftp(xiS[324]);
            else if (tid < 389)  ers[tid-325] = sigm(xiS[tid]);
            else if (tid < 453)  wvec[tid-389] = tanhf(xiS[tid]);
            else if (tid < 457)  fgte[tid-453] = sigm(xiS[tid]);
            else if (tid == 457) sc[1] = sigm(xiS[457]);
            else if (tid == 458) sc[2] = sigm(xiS[458]);
            else if (tid < 463) {
                int r = tid - 459;
                float a0=xiS[459+3*r], a1=xiS[460+3*r], a2=xiS[461+3*r];
                float mx = fmaxf(a0, fmaxf(a1, a2));
                float e0=expf(a0-mx), e1=expf(a1-mx), e2=expf(a2-mx);
                float si = 1.0f/(e0+e1+e2);
                modes[3*r]=e0*si; modes[3*r+1]=e1*si; modes[3*r+2]=e2*si;
            }
            __syncthreads();

            // P2b: key norms (wave-parallel) ∥ usage psi + uu
            if (tid < 256) {                       // waves 0-3: read-key norms
                int r = tid >> 6;
                float v = keys[r*NW + l];
                float s2 = wave_red(v*v);
                if (l == 0) nkey[r] = sqrtf(s2);
            } else if (tid < 320) {                // wave 4: write-key norm
                float v = wkey[l];
                float s2 = wave_red(v*v);
                if (l == 0) sc[3] = sqrtf(s2);
            } else if (tid >= 384 && tid < 512) {  // psi product (stage-1 hoisted)
                int m = tid - 384;
                float psi = 1.0f;
                #pragma unroll
                for (int r = 0; r < NR; ++r) psi *= (1.0f - fgte[r]*rwS[r*NM+m]);
                float u = usg[m]*psi;
                usg[m] = u;
                uu[m] = 5e-6f + (1.0f - 5e-6f)*u;
            }
            __syncthreads();

            // P3: F1 write-content logits (0-127) ∥ G2 rank 4-way partials
            if (tid < NM) {
                float d = 0.0f;
                for (int w = 0; w < NW; ++w) d += wkey[w]*mem[tid*MS+w];
                wcw[tid] = d/(sc[3]*nmo[tid] + EPSF) * sc[0];
            } else if (tid >= 256 && tid < 768) {
                int q = tid - 256, m = q >> 2, jq = q & 3;
                float um = uu[m]; int rk = 0;
                const int j0 = jq*32;
                #pragma unroll 8
                for (int j = j0; j < j0+32; ++j) {
                    float uj = uu[j];
                    rk += (uj < um) || (uj == um && j < m);
                }
                rnk4[m*4 + jq] = rk;
            }
            __syncthreads();

            // P4: wcw softmax fully in wave 0 ∥ rank combine (128-255)
            if (tid < 64) {
                float w0 = wcw[l], w1 = wcw[l+64];
                float mx = fmaxf(w0, w1);
                #pragma unroll
                for (int o = 32; o > 0; o >>= 1) mx = fmaxf(mx, __shfl_down(mx, o));
                float M = __shfl(mx, 0);
                float e0 = expf(w0 - M), e1 = expf(w1 - M);
                float s = wave_red(e0 + e1);
                float inv = 1.0f/__shfl(s, 0);
                wcw[l] = e0*inv; wcw[l+64] = e1*inv;
            } else if (tid >= 128 && tid < 256) {
                int m = tid - 128;
                int rk = rnk4[4*m] + rnk4[4*m+1] + rnk4[4*m+2] + rnk4[4*m+3];
                rnk[m] = rk;
                su[rk] = uu[m];
            }
            __syncthreads();

            // P5: product scan (wave 2)
            if (tid >= 128 && tid < 192) {
                int ll = tid - 128;
                float a = su[ll], bb = su[64+ll];
                #pragma unroll
                for (int o = 1; o < 64; o <<= 1) {
                    float ta = __shfl_up(a, o);
                    float tb = __shfl_up(bb, o);
                    if (ll >= o) { a *= ta; bb *= tb; }
                }
                float P0 = __shfl(a, 63);
                cum[ll] = a;
                cum[64+ll] = P0*bb;
            }
            __syncthreads();

            // P6: alloc + wwN (fused, waves 1-2) + alloc-sum partials
            if (tid >= 64 && tid < 192) {
                int m = tid - 64;
                int rk = rnk[m];
                float excl = (rk == 0) ? 1.0f : cum[rk-1];
                float al = (1.0f - uu[m])*excl;
                wwN[m] = sc[2]*(sc[1]*al + (1.0f - sc[1])*wcw[m]);
                float s = wave_red(al);
                if (l == 0) red[1 + (tid>>6)] = s;   // wave1->red[2], wave2->red[3]
            }
            __syncthreads();

            // P8: H fused: mem erase/write + new norms + link; sc[4] analytic
            if (tid == 1023)
                sc[4] = sc[2]*(sc[1]*(red[2]+red[3]) + (1.0f - sc[1]));
            #pragma unroll
            for (int ri = 0; ri < 8; ++ri) {
                int row = wv*8 + ri;
                float wm = wwN[row];
                float v = mem[row*MS + l];
                float nv = v*(1.0f - wm*ers[l]) + wm*wvec[l];
                mem[row*MS + l] = nv;
                float s2 = wave_red(nv*nv);
                if (l == 0) nmn[row] = sqrtf(s2);
            }
            #pragma unroll
            for (int k = 0; k < 16; ++k) {
                int e = tid + k*TPB;
                int i = e >> 7, j = e & 127;
                float nl = (i == j) ? 0.0f
                         : (1.0f - wwN[i] - wwN[j])*lk[e] + wwN[i]*prc[j];
                lk[e] = nl;
            }
            __syncthreads();

            // P9: I read-content logits (0-511) ∥ H3 precedence (512-639)
            if (tid < NR*NM) {
                int r = tid >> 7, m = tid & 127;
                float d = 0.0f;
                for (int w = 0; w < NW; ++w) d += keys[r*NW+w]*mem[m*MS+w];
                ccw[tid] = d/(nkey[r]*nmn[m] + EPSF) * rstr[r];
            } else if (tid < 640) {
                int m = tid - 512;
                prc[m] = (1.0f - sc[4])*prc[m] + wwN[m];
            }
            __syncthreads();

            // P10: ccw softmax in waves 0-3 (one r each) ∥ J1 fwd in waves 4-15
            if (wv < 4) {
                float v0 = ccw[wv*NM + l], v1 = ccw[wv*NM + 64 + l];
                float mx = fmaxf(v0, v1);
                #pragma unroll
                for (int o = 32; o > 0; o >>= 1) mx = fmaxf(mx, __shfl_down(mx, o));
                float M = __shfl(mx, 0);
                float e0 = expf(v0 - M), e1 = expf(v1 - M);
                float s = wave_red(e0 + e1);
                float inv = 1.0f/__shfl(s, 0);
                ccw[wv*NM + l] = e0*inv; ccw[wv*NM + 64 + l] = e1*inv;
            } else {
                const int pbase = (wv - 4)*43;
                #pragma unroll 4
                for (int i = 0; i < 43; ++i) {
                    const int p = pbase + i;
                    if (p < NR*NM) {
                        const int r = p >> 7, m = p & 127;
                        float partial = lk[m*NM + l]*rwS[r*NM + l]
                                      + lk[m*NM + 64 + l]*rwS[r*NM + 64 + l];
                        partial = wave_red(partial);
                        if (l == 0) fwdT[p] = partial;
                    }
                }
            }
            __syncthreads();

            // P11: J2 bwd + mode mix -> rwN
            if (tid < NR*NM) {
                int r = tid >> 7, m = tid & 127;
                float bw = 0.0f;
                #pragma unroll 4
                for (int i = 0; i < NM; ++i) bw += lk[i*NM+m]*rwS[r*NM+i];
                rwN[tid] = modes[3*r]*bw + modes[3*r+1]*fwdT[tid]
                         + modes[3*r+2]*ccw[tid];
            }
            __syncthreads();

            // P12: K read vectors (0-255) ∥ rwS <- rwN (256-767)
            if (tid < NR*NW) {
                int r = tid >> 6, w = tid & 63;
                float ssum = 0.0f;
                #pragma unroll 4
                for (int m = 0; m < NM; ++m) ssum += rwN[r*NM+m]*mem[m*MS+w];
                rv[tid] = ssum;
            } else if (tid < 768) {
                rwS[tid-256] = rwN[tid-256];
            }
            __syncthreads();

            // P13: publish rv
            if (tid < 64)
                cstore4(&pubRV[(size_t)par*NBATCH*NR*NW + b*NR*NW + tid*4],
                        *(const f4*)&rv[tid*4]);
            flag_set_d(&FLGD[D_R + b], (unsigned)(t+1), tid);

            // P14: usage stage-1 (hoisted) + out(t) in the gates slack
            if (tid < NM) usg[tid] = usg[tid] + (1.0f - usg[tid])*wwN[tid];
            {
                const f4* H4 = (const f4*)hS;
                const f4* RV4 = (const f4*)rv;
                const int r0 = wv*32;
                #pragma unroll 4
                for (int i = 0; i < 32; ++i) {
                    const int row = r0 + i;
                    const f4* WO = (const f4*)(W_o + (size_t)row*NI);
                    float a = dot4(WO[l], H4[l]) + dot4(WO[l+64], H4[l+64])
                            + dot4(WO[128+l], RV4[l]);
                    a = wave_red(a);
                    if (l == 0) oS[row] = a + b_o[row];
                }
            }
            __syncthreads();
            if (tid < 128)
                *(f4*)&out[((size_t)b*NT + t)*NH + tid*4] = *(const f4*)&oS[tid*4];
            // loop-top multi_wait has its own barrier
        }
    } else {
        // ================= GATES block (4 hidden units, 16 rows, +LSTM) =====
        const int g = bid - 32;            // owns units u = 4g .. 4g+3
        const int gate = wv >> 2, j = wv & 3;
        const int r = gate*NH + 4*g + j;   // weight row: gate, unit 4g+j
        const f4* WA = (const f4*)(W_ih + (size_t)r*NI);
        f4 wx0 = WA[l], wx1 = WA[l+64], wrv = WA[128+l];
        const f4* WB = (const f4*)(W_hh + (size_t)r*NH);
        f4 wh0 = WB[l], wh1 = WB[l+64];
        const float bias = b_ih[r] + b_hh[r];
        float* accS = S + G_ACC;   // [32][17] (stride 17: conflict-free)
        float* cSg  = S + G_C;     // [32][5]  (stride 5: conflict-free)
        float* hStg = S + G_H;     // [32][512] h(t-1) staging
        const int sbi = tid >> 7, sk4 = (tid & 127) << 2;

        if (tid < 160) cSg[tid] = 0.0f;
        for (int e = tid; e < NBATCH*NH; e += TPB) hStg[e] = 0.0f;  // h(-1)=0
        __syncthreads();

        for (int t = 0; t < NT; ++t) {
            const int par = t & 1, parp = (t+1) & 1;   // parp = parity of t-1
            // EARLY: stage ALL h(t-1) in one 4-load batch (one LLC latency)
            if (t > 0) {
                multi_wait_d(&FLGD[D_G], 128, (unsigned)t, tid);   // h(t-1) all
                const float* hIn = pubH + (size_t)parp*NBATCH*NH;
                f4 a0, a1, a2, a3;
                cload4x4(hIn + tid*4, hIn + (tid+1024)*4,
                         hIn + (tid+2048)*4, hIn + (tid+3072)*4,
                         a0, a1, a2, a3);
                *(f4*)&hStg[tid*4]          = a0;
                *(f4*)&hStg[(tid+1024)*4]   = a1;
                *(f4*)&hStg[(tid+2048)*4]   = a2;
                *(f4*)&hStg[(tid+3072)*4]   = a3;
            }
            for (int p = 0; p < 4; ++p) {
                const int b0 = p*8;
                // x: 8 batches x 512 (plain cached f4)
                *(f4*)&S[sbi*512 + sk4] =
                    *(const f4*)&x[((size_t)(b0+sbi)*NT + t)*NH + sk4];
                __syncthreads();
                #pragma unroll
                for (int bi = 0; bi < 8; ++bi) {
                    const f4* X4 = (const f4*)(S + bi*512);
                    const f4* H4 = (const f4*)(hStg + (b0+bi)*512);
                    float a = dot4(wx0, X4[l]) + dot4(wx1, X4[l+64])
                            + dot4(wh0, H4[l]) + dot4(wh1, H4[l+64]);
                    a = wave_red(a);
                    if (l == 0) accS[(b0+bi)*17 + wv] = a + bias;
                }
                __syncthreads();
            }
            // LATE: rv(t-1) — the only critical-path part
            {
                const int bi0 = tid >> 6, k40 = (tid & 63) << 2;
                if (t > 0) {
                    multi_wait_d(&FLGD[D_R], 32, (unsigned)t, tid);
                    const float* rIn = pubRV + (size_t)parp*NBATCH*NR*NW;
                    f4 a0, a1;
                    cload4x2(&rIn[bi0*256 + k40], &rIn[(bi0+16)*256 + k40], a0, a1);
                    *(f4*)&S[bi0*256 + k40] = a0;
                    *(f4*)&S[(bi0+16)*256 + k40] = a1;
                } else {
                    f4 z = {0.0f, 0.0f, 0.0f, 0.0f};
                    *(f4*)&S[bi0*256 + k40] = z;
                    *(f4*)&S[(bi0+16)*256 + k40] = z;
                }
            }
            __syncthreads();
            #pragma unroll
            for (int bi = 0; bi < 32; ++bi) {
                const f4* RV4 = (const f4*)(S + bi*256);
                float d = dot4(wrv, RV4[l]);
                d = wave_red(d);
                if (l == 0) accS[bi*17 + wv] += d;
            }
            __syncthreads();
            // LSTM cell for this block's 4 units x 32 batches, publish h-chunk
            if (tid < 32) {
                const int bi = tid;
                const float* acc = accS + bi*17;
                f4 hq;
                #pragma unroll
                for (int jj = 0; jj < 4; ++jj) {
                    float i_ = sigm(acc[0*4 + jj]);
                    float f_ = sigm(acc[1*4 + jj]);
                    float g_ = tanhf(acc[2*4 + jj]);
                    float o_ = sigm(acc[3*4 + jj]);
                    float c  = f_*cSg[bi*5 + jj] + i_*g_;
                    cSg[bi*5 + jj] = c;
                    hq[jj] = o_*tanhf(c);
                }
                cstore4(&pubH[(size_t)par*NBATCH*NH + (size_t)bi*NH + 4*g], hq);
            }
            flag_set_d(&FLGD[D_G + g], (unsigned)(t+1), tid);
        }
    }
}

extern "C" void kernel_launch(void* const* d_in, const int* in_sizes, int n_in,
                              void* d_out, int out_size, void* d_ws, size_t ws_size,
                              hipStream_t stream) {
    (void)in_sizes; (void)n_in; (void)out_size; (void)ws_size;
    const float* x    = (const float*)d_in[0];
    const float* W_ih = (const float*)d_in[1];
    const float* W_hh = (const float*)d_in[2];
    const float* b_ih = (const float*)d_in[3];
    const float* b_hh = (const float*)d_in[4];
    const float* W_xi = (const float*)d_in[5];
    const float* b_xi = (const float*)d_in[6];
    const float* W_o  = (const float*)d_in[7];
    const float* b_o  = (const float*)d_in[8];
    float* out = (float*)d_out;
    float* ws  = (float*)d_ws;

    dnc_zero<<<1, 256, 0, stream>>>(ws);

    void* args[] = { (void*)&x, (void*)&W_ih, (void*)&W_hh, (void*)&b_ih,
                     (void*)&b_hh, (void*)&W_xi, (void*)&b_xi, (void*)&W_o,
                     (void*)&b_o, (void*)&out, (void*)&ws };
    hipLaunchCooperativeKernel((void*)dnc_pipe2, dim3(NBLK), dim3(TPB),
                               args, 0, stream);
}

// Round 5
// 3505.551 us; speedup vs baseline: 1.6715x; 1.6715x over previous
//
#include <hip/hip_runtime.h>
#include <math.h>

#define TPB 1024
#define NBLK 160
#define NBATCH 32
#define NT 64
#define NH 512
#define NM 128
#define NR 4
#define NW 64
#define NI 768          // controller input size (H + R*W)
#define NXI 471         // interface vector size
#define EPSF 1e-6f
#define MS 65           // mem row stride (+1 pad)

// roles: [0,32) state (DNC machinery only) |
//        [32,160) gates blocks: 4 hidden units (16 gate rows) + LSTM cell
//                 + 4 xi rows + 4 out rows (distributed W_xi / W_o streams)

typedef float f4 __attribute__((ext_vector_type(4)));

// ws layout (float offsets). pub* parity double-buffered.
#define WS_PUBH  0                                 // [2][32][512] (gates)
#define WS_PUBRV (WS_PUBH + 2*NBATCH*NH)           // [2][32][256] (state)
#define WS_PUBXI (WS_PUBRV + 2*NBATCH*NR*NW)       // [2][32][480] (gates)
#define WS_FLAGS (WS_PUBXI + 2*NBATCH*480)
// packed flag dwords
#define D_G 0        // 128 gate blocks: h(t) published -> t+1
#define D_R 128      // 32 state blocks: rv(t) published -> t+1
#define D_X 160      // 118 gate blocks: xi(t-1) published -> t
#define D_TOTAL 288
#define NXB 118      // gate blocks that own xi rows (4*118 >= 471)

__device__ __forceinline__ float sigm(float x){ return 1.0f/(1.0f+expf(-x)); }
__device__ __forceinline__ float sftp(float x){ return fmaxf(x,0.0f)+log1pf(expf(-fabsf(x))); }
__device__ __forceinline__ float dot4(f4 a, f4 b){
    return a.x*b.x + a.y*b.y + a.z*b.z + a.w*b.w;
}
__device__ __forceinline__ float wave_red(float v){
    #pragma unroll
    for (int o = 32; o > 0; o >>= 1) v += __shfl_down(v, o);
    return v;
}

// ---- coherent (LLC write-through, device-visible) accessors: sc0 sc1 ----
// waitcnt INSIDE each asm statement => no rule-18 hoist hazard.
__device__ __forceinline__ f4 cload4(const float* p){
    f4 v;
    asm volatile("global_load_dwordx4 %0, %1, off sc0 sc1\n\t"
                 "s_waitcnt vmcnt(0)"
                 : "=&v"(v) : "v"(p) : "memory");
    return v;
}
__device__ __forceinline__ void cload4x2(const float* p0, const float* p1,
                                         f4& a, f4& b){
    asm volatile("global_load_dwordx4 %0, %2, off sc0 sc1\n\t"
                 "global_load_dwordx4 %1, %3, off sc0 sc1\n\t"
                 "s_waitcnt vmcnt(0)"
                 : "=&v"(a), "=&v"(b) : "v"(p0), "v"(p1) : "memory");
}
__device__ __forceinline__ void cload4x4(const float* p0, const float* p1,
                                         const float* p2, const float* p3,
                                         f4& a, f4& b, f4& c, f4& d){
    asm volatile("global_load_dwordx4 %0, %4, off sc0 sc1\n\t"
                 "global_load_dwordx4 %1, %5, off sc0 sc1\n\t"
                 "global_load_dwordx4 %2, %6, off sc0 sc1\n\t"
                 "global_load_dwordx4 %3, %7, off sc0 sc1\n\t"
                 "s_waitcnt vmcnt(0)"
                 : "=&v"(a), "=&v"(b), "=&v"(c), "=&v"(d)
                 : "v"(p0), "v"(p1), "v"(p2), "v"(p3) : "memory");
}
__device__ __forceinline__ void cstore4(float* p, f4 v){
    asm volatile("global_store_dwordx4 %0, %1, off sc0 sc1"
                 :: "v"(p), "v"(v) : "memory");
}

// ---- packed-flag protocol: coalesced parallel polls, no RMW, no RELEASE ----
__device__ __forceinline__ void multi_wait_d(const unsigned int* f, int n,
                                             unsigned int tgt, int tid){
    if (tid < n) {
        const unsigned int* p = f + tid;          // consecutive dwords: coalesced
        while (__hip_atomic_load(p, __ATOMIC_RELAXED,
                                 __HIP_MEMORY_SCOPE_AGENT) < tgt)
            __builtin_amdgcn_s_sleep(2);
    }
    __syncthreads();
}
// all cross-block data stores are sc0 sc1 (write-through to coherence point);
// per-wave vmcnt(0) drain + barrier + RELAXED flag store is a correct release.
__device__ __forceinline__ void flag_set_d(unsigned int* f, unsigned int v, int tid){
    asm volatile("s_waitcnt vmcnt(0)" ::: "memory");
    __syncthreads();
    if (tid == 0)
        __hip_atomic_store(f, v, __ATOMIC_RELAXED, __HIP_MEMORY_SCOPE_AGENT);
}

__global__ void dnc_zero(float* ws){
    unsigned int* z = (unsigned int*)(ws + WS_FLAGS);
    for (int e = threadIdx.x; e < D_TOTAL; e += blockDim.x) z[e] = 0u;
}

// ---- pooled LDS (floats) — r3-proven state map ----
#define O_MEM 0
#define O_H   8320      // (unused, kept for map stability)
#define O_RW  9344
#define O_WWO 9856
#define O_WWN 9984
#define O_USG 10112
#define O_PRC 10240
#define O_XI  10368     // 480
#define O_KEY 10848
#define O_WK  11104
#define O_ER  11168
#define O_WV  11232
#define O_RS  11296
#define O_FG  11300
#define O_MD  11304
#define O_NK  11316
#define O_SC  11320
#define O_NMO 11328
#define O_NMN 11456
#define O_WCW 11584
#define O_UU  11712
#define O_SU  11840
#define O_CUM 11968
#define O_RNK 12096
#define O_CCW 12224
#define O_FWD 12736
#define O_RV  13248
#define O_RED 13504
#define O_LK  14024     // 16384 link matrix in LDS
#define S_SZ  30408
// gates role (disjoint): x/rv staging S[0..8191]
#define G_ACC 8192      // [32][17] (stride 17: conflict-free LSTM reads)
#define G_C   8736      // [32][5]  (stride 5: conflict-free)
#define G_H   8896      // [32][512] h(t-1) staging

__global__ __launch_bounds__(TPB) void dnc_pipe2(
    const float* __restrict__ x, const float* __restrict__ W_ih,
    const float* __restrict__ W_hh, const float* __restrict__ b_ih,
    const float* __restrict__ b_hh, const float* __restrict__ W_xi,
    const float* __restrict__ b_xi, const float* __restrict__ W_o,
    const float* __restrict__ b_o, float* __restrict__ out,
    float* __restrict__ ws)
{
    __shared__ __align__(16) float S[S_SZ];

    const int tid = threadIdx.x;
    const int wv  = tid >> 6;
    const int l   = tid & 63;
    const int bid = blockIdx.x;

    float* __restrict__ pubH  = ws + WS_PUBH;
    float* __restrict__ pubRV = ws + WS_PUBRV;
    float* __restrict__ pubXI = ws + WS_PUBXI;
    unsigned int* __restrict__ FLGD = (unsigned int*)(ws + WS_FLAGS);

    if (bid < NBATCH) {
        // ========================= STATE block (r3 machinery) ===============
        const int b = bid;
        float* lk = S+O_LK;
        float* mem = S+O_MEM;
        float* rwS = S+O_RW;   float* wwO = S+O_WWO; float* wwN = S+O_WWN;
        float* usg = S+O_USG;  float* prc = S+O_PRC; float* xiS = S+O_XI;
        float* keys = S+O_KEY; float* wkey = S+O_WK; float* ers = S+O_ER;
        float* wvec = S+O_WV;  float* rstr = S+O_RS; float* fgte = S+O_FG;
        float* modes = S+O_MD; float* nkey = S+O_NK; float* sc = S+O_SC;
        float* nmo = S+O_NMO;  float* nmn = S+O_NMN; float* wcw = S+O_WCW;
        float* uu = S+O_UU;    float* su = S+O_SU;   float* cum = S+O_CUM;
        int*   rnk = (int*)(S+O_RNK);
        float* ccw = S+O_CCW;  float* fwdT = S+O_FWD; float* rv = S+O_RV;
        float* red = S+O_RED;

        for (int e = tid; e < NM*NM; e += TPB) lk[e] = 0.0f;
        for (int e = tid; e < NM*NW; e += TPB) mem[(e>>6)*MS + (e&63)] = EPSF;
        for (int e = tid; e < NR*NM; e += TPB) rwS[e]=0.0f;
        for (int e = tid; e < NM; e += TPB){ wwO[e]=0.0f; usg[e]=0.0f; prc[e]=0.0f; }
        __syncthreads();

        for (int t = 0; t < NT; ++t) {
            const int par = t & 1;

            // nmo — old mem norms (overlaps gates' xi production)
            #pragma unroll
            for (int ri = 0; ri < 8; ++ri) {
                int row = wv*8 + ri;
                float v = mem[row*MS + l];
                float s2 = wave_red(v*v);
                if (l == 0) nmo[row] = sqrtf(s2);
            }
            // xi(t) ready from the 118 xi-owning gate blocks
            multi_wait_d(&FLGD[D_X], NXB, (unsigned)(t+1), tid);
            if (tid < 120)
                *(f4*)&xiS[tid*4] =
                    cload4(&pubXI[(size_t)par*NBATCH*480 + b*480 + tid*4]);
            __syncthreads();

            // E1: unpack interface
            if (tid < 256)       keys[tid] = tanhf(xiS[tid]);
            else if (tid < 260)  rstr[tid-256] = sftp(xiS[tid]);
            else if (tid < 324)  wkey[tid-260] = tanhf(xiS[tid]);
            else if (tid == 324) sc[0] = sftp(xiS[324]);
            else if (tid < 389)  ers[tid-325] = sigm(xiS[tid]);
            else if (tid < 453)  wvec[tid-389] = tanhf(xiS[tid]);
            else if (tid < 457)  fgte[tid-453] = sigm(xiS[tid]);
            else if (tid == 457) sc[1] = sigm(xiS[457]);
            else if (tid == 458) sc[2] = sigm(xiS[458]);
            else if (tid < 463) {
                int r = tid - 459;
                float a0=xiS[459+3*r], a1=xiS[460+3*r], a2=xiS[461+3*r];
                float mx = fmaxf(a0, fmaxf(a1, a2));
                float e0=expf(a0-mx), e1=expf(a1-mx), e2=expf(a2-mx);
                float si = 1.0f/(e0+e1+e2);
                modes[3*r]=e0*si; modes[3*r+1]=e1*si; modes[3*r+2]=e2*si;
            }
            __syncthreads();

            // E2a: key norms
            if (tid < NR) {
                float ssum = 0.0f;
                for (int w = 0; w < NW; ++w) { float v = keys[tid*NW+w]; ssum += v*v; }
                nkey[tid] = sqrtf(ssum);
            } else if (tid == NR) {
                float ssum = 0.0f;
                for (int w = 0; w < NW; ++w) { float v = wkey[w]; ssum += v*v; }
                sc[3] = sqrtf(ssum);
            }
            // E2b: usage + uu (fused)
            if (tid >= 64 && tid < 64+NM) {
                int m = tid - 64;
                float u = usg[m];
                u = u + (1.0f - u)*wwO[m];
                float psi = 1.0f;
                #pragma unroll
                for (int r = 0; r < NR; ++r) psi *= (1.0f - fgte[r]*rwS[r*NM+m]);
                u *= psi;
                usg[m] = u;
                uu[m] = 5e-6f + (1.0f - 5e-6f)*u;
            }
            __syncthreads();

            // F1: write-content logits
            if (tid < NM) {
                float d = 0.0f;
                for (int w = 0; w < NW; ++w) d += wkey[w]*mem[tid*MS+w];
                wcw[tid] = d/(sc[3]*nmo[tid] + EPSF) * sc[0];
            }
            __syncthreads();
            // F2: softmax over 128
            if (tid < 64) {
                float v = fmaxf(wcw[tid], wcw[tid+64]);
                #pragma unroll
                for (int o = 32; o > 0; o >>= 1) v = fmaxf(v, __shfl_down(v, o));
                if (tid == 0) red[0] = v;
            }
            __syncthreads();
            if (tid < NM) wcw[tid] = expf(wcw[tid] - red[0]);
            __syncthreads();
            if (tid < 64) {
                float v = wave_red(wcw[tid] + wcw[tid+64]);
                if (tid == 0) red[0] = 1.0f/v;
            }
            __syncthreads();
            if (tid < NM) wcw[tid] *= red[0];
            __syncthreads();

            // G2: stable rank
            if (tid < NM) {
                float um = uu[tid]; int rk = 0;
                for (int j = 0; j < NM; ++j) {
                    float uj = uu[j];
                    rk += (uj < um) || (uj == um && j < tid);
                }
                rnk[tid] = rk;
                su[rk] = um;
            }
            __syncthreads();
            // G3: product scan (wave 0)
            if (tid < 64) {
                float a = su[tid], bb = su[64+tid];
                #pragma unroll
                for (int o = 1; o < 64; o <<= 1) {
                    float ta = __shfl_up(a, o);
                    float tb = __shfl_up(bb, o);
                    if (tid >= o) { a *= ta; bb *= tb; }
                }
                float P0 = __shfl(a, 63);
                cum[tid] = a;
                cum[64+tid] = P0*bb;
            }
            __syncthreads();
            // G4: alloc + write weighting
            if (tid < NM) {
                int rk = rnk[tid];
                float excl = (rk == 0) ? 1.0f : cum[rk-1];
                float al = (1.0f - uu[tid])*excl;
                wwN[tid] = sc[2]*(sc[1]*al + (1.0f - sc[1])*wcw[tid]);
            }
            __syncthreads();
            // G5: sum(wwN)
            if (tid < 64) {
                float v = wave_red(wwN[tid] + wwN[tid+64]);
                if (tid == 0) sc[4] = v;
            }
            __syncthreads();

            // H (fused): mem erase/write + new norms + link
            #pragma unroll
            for (int ri = 0; ri < 8; ++ri) {
                int row = wv*8 + ri;
                float wm = wwN[row];
                float v = mem[row*MS + l];
                float nv = v*(1.0f - wm*ers[l]) + wm*wvec[l];
                mem[row*MS + l] = nv;
                float s2 = wave_red(nv*nv);
                if (l == 0) nmn[row] = sqrtf(s2);
            }
            for (int e = tid; e < NM*NM; e += TPB) {
                int i = e >> 7, j = e & 127;
                float nl = (i == j) ? 0.0f
                         : (1.0f - wwN[i] - wwN[j])*lk[e] + wwN[i]*prc[j];
                lk[e] = nl;
            }
            __syncthreads();
            // H3: precedence
            if (tid < NM) prc[tid] = (1.0f - sc[4])*prc[tid] + wwN[tid];
            __syncthreads();

            // I: read-content logits + per-r softmax
            if (tid < NR*NM) {
                int r = tid >> 7, m = tid & 127;
                float d = 0.0f;
                for (int w = 0; w < NW; ++w) d += keys[r*NW+w]*mem[m*MS+w];
                ccw[tid] = d/(nkey[r]*nmn[m] + EPSF) * rstr[r];
            }
            __syncthreads();
            if (tid < 256) {
                int r = tid >> 6, ll = tid & 63;
                float v = fmaxf(ccw[r*NM+ll], ccw[r*NM+ll+64]);
                #pragma unroll
                for (int o = 32; o > 0; o >>= 1) v = fmaxf(v, __shfl_down(v, o));
                if (ll == 0) red[r] = v;
            }
            __syncthreads();
            if (tid < NR*NM) ccw[tid] = expf(ccw[tid] - red[tid>>7]);
            __syncthreads();
            if (tid < 256) {
                int r = tid >> 6, ll = tid & 63;
                float v = wave_red(ccw[r*NM+ll] + ccw[r*NM+ll+64]);
                if (ll == 0) red[4+r] = 1.0f/v;
            }
            __syncthreads();
            if (tid < NR*NM) ccw[tid] *= red[4+(tid>>7)];
            __syncthreads();

            // J1: fwd[r][m]
            {
                const int p0 = wv*32;
                for (int i = 0; i < 32; ++i) {
                    const int p = p0 + i, r = p >> 7, m = p & 127;
                    float partial = lk[m*NM + l]*rwS[r*NM + l]
                                  + lk[m*NM + 64 + l]*rwS[r*NM + 64 + l];
                    partial = wave_red(partial);
                    if (l == 0) fwdT[p] = partial;
                }
            }
            __syncthreads();
            // J2: bwd + mode mix
            float rwnew = 0.0f;
            if (tid < NR*NM) {
                int r = tid >> 7, m = tid & 127;
                float bw = 0.0f;
                for (int i = 0; i < NM; ++i) bw += lk[i*NM+m]*rwS[r*NM+i];
                rwnew = modes[3*r]*bw + modes[3*r+1]*fwdT[tid] + modes[3*r+2]*ccw[tid];
            }
            __syncthreads();
            if (tid < NR*NM) rwS[tid] = rwnew;
            __syncthreads();

            // K: read vectors + publish rv
            if (tid < NR*NW) {
                int r = tid >> 6, w = tid & 63;
                float ssum = 0.0f;
                for (int m = 0; m < NM; ++m) ssum += rwS[r*NM+m]*mem[m*MS+w];
                rv[tid] = ssum;
            }
            __syncthreads();
            if (tid < 64)
                cstore4(&pubRV[(size_t)par*NBATCH*NR*NW + b*NR*NW + tid*4],
                        *(const f4*)&rv[tid*4]);
            flag_set_d(&FLGD[D_R + b], (unsigned)(t+1), tid);

            if (tid < NM) wwO[tid] = wwN[tid];
            __syncthreads();
        }
    } else {
        // ===== GATES block: 4 units (16 gate rows) + LSTM + 4 xi + 4 out ====
        const int g = bid - 32;            // owns units u = 4g .. 4g+3
        const int gate = wv >> 2, j = wv & 3;
        const int r = gate*NH + 4*g + j;   // weight row: gate, unit 4g+j
        const f4* WA = (const f4*)(W_ih + (size_t)r*NI);
        f4 wx0 = WA[l], wx1 = WA[l+64], wrv = WA[128+l];
        const f4* WB = (const f4*)(W_hh + (size_t)r*NH);
        f4 wh0 = WB[l], wh1 = WB[l+64];
        const float bias = b_ih[r] + b_hh[r];
        float* accS = S + G_ACC;   // [32][17] (stride 17: conflict-free)
        float* cSg  = S + G_C;     // [32][5]  (stride 5: conflict-free)
        float* hStg = S + G_H;     // [32][512] h(t-1) staging
        const int sbi = tid >> 7, sk4 = (tid & 127) << 2;

        if (tid < 160) cSg[tid] = 0.0f;
        for (int e = tid; e < NBATCH*NH; e += TPB) hStg[e] = 0.0f;  // h(-1)=0
        __syncthreads();

        for (int t = 0; t <= NT; ++t) {          // NT+1 iters (epilogue at NT)
            const int par = t & 1, parp = (t+1) & 1;   // parp = parity of t-1

            // A: stage ALL h(t-1); then xi(t-1) from our 8KB W_xi slice
            if (t >= 1) {
                multi_wait_d(&FLGD[D_G], 128, (unsigned)t, tid);   // h(t-1) all
                const float* hIn = pubH + (size_t)parp*NBATCH*NH;
                f4 a0, a1, a2, a3;
                cload4x4(hIn + tid*4, hIn + (tid+1024)*4,
                         hIn + (tid+2048)*4, hIn + (tid+3072)*4,
                         a0, a1, a2, a3);
                *(f4*)&hStg[tid*4]          = a0;
                *(f4*)&hStg[(tid+1024)*4]   = a1;
                *(f4*)&hStg[(tid+2048)*4]   = a2;
                *(f4*)&hStg[(tid+3072)*4]   = a3;
                __syncthreads();
                if (g < NXB) {
                    float* xOut = pubXI + (size_t)parp*NBATCH*480;
                    #pragma unroll
                    for (int bb = 0; bb < 2; ++bb) {
                        const int bi = 2*wv + bb;
                        const f4* H4 = (const f4*)(hStg + bi*512);
                        f4 res = {0.0f, 0.0f, 0.0f, 0.0f};
                        #pragma unroll
                        for (int jj = 0; jj < 4; ++jj) {
                            const int row = 4*g + jj;
                            if (row < NXI) {
                                const f4* WX = (const f4*)(W_xi + (size_t)row*NH);
                                float a = dot4(WX[l], H4[l])
                                        + dot4(WX[l+64], H4[l+64]);
                                a = wave_red(a);
                                res[jj] = a + b_xi[row];
                            }
                        }
                        if (l == 0) cstore4(&xOut[(size_t)bi*480 + 4*g], res);
                    }
                    flag_set_d(&FLGD[D_X + g], (unsigned)t, tid);
                }
            }

            // B: heavy phase x(t)·W_ih + h(t-1)·W_hh (off critical path)
            if (t < NT) {
                for (int p = 0; p < 4; ++p) {
                    const int b0 = p*8;
                    *(f4*)&S[sbi*512 + sk4] =
                        *(const f4*)&x[((size_t)(b0+sbi)*NT + t)*NH + sk4];
                    __syncthreads();
                    #pragma unroll
                    for (int bi = 0; bi < 8; ++bi) {
                        const f4* X4 = (const f4*)(S + bi*512);
                        const f4* H4 = (const f4*)(hStg + (b0+bi)*512);
                        float a = dot4(wx0, X4[l]) + dot4(wx1, X4[l+64])
                                + dot4(wh0, H4[l]) + dot4(wh1, H4[l+64]);
                        a = wave_red(a);
                        if (l == 0) accS[(b0+bi)*17 + wv] = a + bias;
                    }
                    __syncthreads();
                }
            }

            // C: rv(t-1) — the critical-path input
            {
                const int bi0 = tid >> 6, k40 = (tid & 63) << 2;
                if (t >= 1) {
                    multi_wait_d(&FLGD[D_R], 32, (unsigned)t, tid);
                    const float* rIn = pubRV + (size_t)parp*NBATCH*NR*NW;
                    f4 a0, a1;
                    cload4x2(&rIn[bi0*256 + k40], &rIn[(bi0+16)*256 + k40], a0, a1);
                    *(f4*)&S[bi0*256 + k40] = a0;
                    *(f4*)&S[(bi0+16)*256 + k40] = a1;
                } else {
                    f4 z = {0.0f, 0.0f, 0.0f, 0.0f};
                    *(f4*)&S[bi0*256 + k40] = z;
                    *(f4*)&S[(bi0+16)*256 + k40] = z;
                }
            }
            __syncthreads();

            // D: rv dot + LSTM + publish h(t)
            if (t < NT) {
                #pragma unroll
                for (int bi = 0; bi < 32; ++bi) {
                    const f4* RV4 = (const f4*)(S + bi*256);
                    float d = dot4(wrv, RV4[l]);
                    d = wave_red(d);
                    if (l == 0) accS[bi*17 + wv] += d;
                }
                __syncthreads();
                if (tid < 32) {
                    const int bi = tid;
                    const float* acc = accS + bi*17;
                    f4 hq;
                    #pragma unroll
                    for (int jj = 0; jj < 4; ++jj) {
                        float i_ = sigm(acc[0*4 + jj]);
                        float f_ = sigm(acc[1*4 + jj]);
                        float g_ = tanhf(acc[2*4 + jj]);
                        float o_ = sigm(acc[3*4 + jj]);
                        float c  = f_*cSg[bi*5 + jj] + i_*g_;
                        cSg[bi*5 + jj] = c;
                        hq[jj] = o_*tanhf(c);
                    }
                    cstore4(&pubH[(size_t)par*NBATCH*NH + (size_t)bi*NH + 4*g], hq);
                }
                flag_set_d(&FLGD[D_G + g], (unsigned)(t+1), tid);
            }

            // E: out(t-1) from hStg (h(t-1)) + staged rv(t-1) — idle shadow
            if (t >= 1) {
                #pragma unroll
                for (int bb = 0; bb < 2; ++bb) {
                    const int bi = 2*wv + bb;
                    const f4* H4 = (const f4*)(hStg + bi*512);
                    const f4* RV4 = (const f4*)(S + bi*256);
                    f4 res;
                    #pragma unroll
                    for (int jj = 0; jj < 4; ++jj) {
                        const int row = 4*g + jj;
                        const f4* WO = (const f4*)(W_o + (size_t)row*NI);
                        float a = dot4(WO[l], H4[l]) + dot4(WO[l+64], H4[l+64])
                                + dot4(WO[128+l], RV4[l]);
                        a = wave_red(a);
                        res[jj] = a + b_o[row];
                    }
                    if (l == 0)
                        *(f4*)&out[((size_t)bi*NT + (t-1))*NH + 4*g] = res;
                }
            }
            // next iter's D_G multi_wait barrier orders these reads vs restaging
        }
    }
}

extern "C" void kernel_launch(void* const* d_in, const int* in_sizes, int n_in,
                              void* d_out, int out_size, void* d_ws, size_t ws_size,
                              hipStream_t stream) {
    (void)in_sizes; (void)n_in; (void)out_size; (void)ws_size;
    const float* x    = (const float*)d_in[0];
    const float* W_ih = (const float*)d_in[1];
    const float* W_hh = (const float*)d_in[2];
    const float* b_ih = (const float*)d_in[3];
    const float* b_hh = (const float*)d_in[4];
    const float* W_xi = (const float*)d_in[5];
    const float* b_xi = (const float*)d_in[6];
    const float* W_o  = (const float*)d_in[7];
    const float* b_o  = (const float*)d_in[8];
    float* out = (float*)d_out;
    float* ws  = (float*)d_ws;

    dnc_zero<<<1, 512, 0, stream>>>(ws);

    void* args[] = { (void*)&x, (void*)&W_ih, (void*)&W_hh, (void*)&b_ih,
                     (void*)&b_hh, (void*)&W_xi, (void*)&b_xi, (void*)&W_o,
                     (void*)&b_o, (void*)&out, (void*)&ws };
    hipLaunchCooperativeKernel((void*)dnc_pipe2, dim3(NBLK), dim3(TPB),
                               args, 0, stream);
}

// Round 6
// 3054.823 us; speedup vs baseline: 1.9181x; 1.1475x over previous
//
#include <hip/hip_runtime.h>
#include <math.h>

#define TPB 1024
#define NBLK 160
#define NBATCH 32
#define NT 64
#define NH 512
#define NM 128
#define NR 4
#define NW 64
#define NI 768          // controller input size (H + R*W)
#define NXI 471         // interface vector size
#define EPSF 1e-6f
#define MS 65           // mem row stride (+1 pad)
#define LKS 129         // link matrix row stride (+1 pad: conflict-free row dots)

// roles: [0,32) state (DNC machinery only) |
//        [32,160) gates blocks: 4 hidden units (16 gate rows) + LSTM cell
//                 + 4 xi rows + 4 out rows (distributed W_xi / W_o streams)

typedef float f4 __attribute__((ext_vector_type(4)));

// ws layout (float offsets). pub* parity double-buffered.
#define WS_PUBH  0                                 // [2][32][512] (gates)
#define WS_PUBRV (WS_PUBH + 2*NBATCH*NH)           // [2][32][256] (state)
#define WS_PUBXI (WS_PUBRV + 2*NBATCH*NR*NW)       // [2][32][480] (gates)
#define WS_FLAGS (WS_PUBXI + 2*NBATCH*480)
// packed flag dwords
#define D_G 0        // 128 gate blocks: h(t) published -> t+1
#define D_R 128      // 32 state blocks: rv(t) published -> t+1
#define D_X 160      // 118 gate blocks: xi(t-1) published -> t
#define D_TOTAL 288
#define NXB 118      // gate blocks that own xi rows (4*118 >= 471)

__device__ __forceinline__ float sigm(float x){ return 1.0f/(1.0f+expf(-x)); }
__device__ __forceinline__ float sftp(float x){ return fmaxf(x,0.0f)+log1pf(expf(-fabsf(x))); }
__device__ __forceinline__ float dot4(f4 a, f4 b){
    return a.x*b.x + a.y*b.y + a.z*b.z + a.w*b.w;
}
__device__ __forceinline__ float wave_red(float v){
    #pragma unroll
    for (int o = 32; o > 0; o >>= 1) v += __shfl_down(v, o);
    return v;
}

// ---- coherent (LLC write-through, device-visible) accessors: sc0 sc1 ----
// waitcnt INSIDE each asm statement => no rule-18 hoist hazard.
__device__ __forceinline__ f4 cload4(const float* p){
    f4 v;
    asm volatile("global_load_dwordx4 %0, %1, off sc0 sc1\n\t"
                 "s_waitcnt vmcnt(0)"
                 : "=&v"(v) : "v"(p) : "memory");
    return v;
}
__device__ __forceinline__ void cload4x2(const float* p0, const float* p1,
                                         f4& a, f4& b){
    asm volatile("global_load_dwordx4 %0, %2, off sc0 sc1\n\t"
                 "global_load_dwordx4 %1, %3, off sc0 sc1\n\t"
                 "s_waitcnt vmcnt(0)"
                 : "=&v"(a), "=&v"(b) : "v"(p0), "v"(p1) : "memory");
}
__device__ __forceinline__ void cload4x4(const float* p0, const float* p1,
                                         const float* p2, const float* p3,
                                         f4& a, f4& b, f4& c, f4& d){
    asm volatile("global_load_dwordx4 %0, %4, off sc0 sc1\n\t"
                 "global_load_dwordx4 %1, %5, off sc0 sc1\n\t"
                 "global_load_dwordx4 %2, %6, off sc0 sc1\n\t"
                 "global_load_dwordx4 %3, %7, off sc0 sc1\n\t"
                 "s_waitcnt vmcnt(0)"
                 : "=&v"(a), "=&v"(b), "=&v"(c), "=&v"(d)
                 : "v"(p0), "v"(p1), "v"(p2), "v"(p3) : "memory");
}
__device__ __forceinline__ void cstore4(float* p, f4 v){
    asm volatile("global_store_dwordx4 %0, %1, off sc0 sc1"
                 :: "v"(p), "v"(v) : "memory");
}

// ---- packed-flag protocol: coalesced parallel polls, no RMW, no RELEASE ----
__device__ __forceinline__ void multi_wait_d(const unsigned int* f, int n,
                                             unsigned int tgt, int tid){
    if (tid < n) {
        const unsigned int* p = f + tid;          // consecutive dwords: coalesced
        while (__hip_atomic_load(p, __ATOMIC_RELAXED,
                                 __HIP_MEMORY_SCOPE_AGENT) < tgt)
            __builtin_amdgcn_s_sleep(2);
    }
    __syncthreads();
}
// all cross-block data stores are sc0 sc1 (write-through to coherence point);
// per-wave vmcnt(0) drain + barrier + RELAXED flag store is a correct release.
__device__ __forceinline__ void flag_set_d(unsigned int* f, unsigned int v, int tid){
    asm volatile("s_waitcnt vmcnt(0)" ::: "memory");
    __syncthreads();
    if (tid == 0)
        __hip_atomic_store(f, v, __ATOMIC_RELAXED, __HIP_MEMORY_SCOPE_AGENT);
}

__global__ void dnc_zero(float* ws){
    unsigned int* z = (unsigned int*)(ws + WS_FLAGS);
    for (int e = threadIdx.x; e < D_TOTAL; e += blockDim.x) z[e] = 0u;
}

// ---- pooled LDS (floats) ----
#define O_MEM 0
#define O_RW  9344
#define O_WWO 9856
#define O_WWN 9984
#define O_USG 10112
#define O_PRC 10240
#define O_XI  10368     // 480
#define O_KEY 10848
#define O_WK  11104
#define O_ER  11168
#define O_WV  11232
#define O_RS  11296
#define O_FG  11300
#define O_MD  11304
#define O_NK  11316
#define O_SC  11320
#define O_NMO 11328
#define O_NMN 11456
#define O_WCW 11584
#define O_UU  11712
#define O_SU  11840
#define O_CUM 11968
#define O_RNK 12096
#define O_CCW 12224
#define O_FWD 12736
#define O_RV  13248
#define O_RED 13504
#define O_LK  14024     // 128*129 link matrix (padded stride)
#define S_SZ  (14024 + NM*LKS)     // 30536 floats = 122,144 B; 1 block/CU
// gates role (disjoint): x/rv staging S[0..8191]
#define G_ACC 8192      // [32][17] (stride 17: conflict-free LSTM reads)
#define G_C   8736      // [32][5]  (stride 5: conflict-free)
#define G_H   8896      // [32][512] h(t-1) staging

__global__ __launch_bounds__(TPB) void dnc_pipe2(
    const float* __restrict__ x, const float* __restrict__ W_ih,
    const float* __restrict__ W_hh, const float* __restrict__ b_ih,
    const float* __restrict__ b_hh, const float* __restrict__ W_xi,
    const float* __restrict__ b_xi, const float* __restrict__ W_o,
    const float* __restrict__ b_o, float* __restrict__ out,
    float* __restrict__ ws)
{
    __shared__ __align__(16) float S[S_SZ];

    const int tid = threadIdx.x;
    const int wv  = tid >> 6;
    const int l   = tid & 63;
    const int bid = blockIdx.x;

    float* __restrict__ pubH  = ws + WS_PUBH;
    float* __restrict__ pubRV = ws + WS_PUBRV;
    float* __restrict__ pubXI = ws + WS_PUBXI;
    unsigned int* __restrict__ FLGD = (unsigned int*)(ws + WS_FLAGS);

    if (bid < NBATCH) {
        // ========================= STATE block =========================
        const int b = bid;
        float* lk = S+O_LK;
        float* mem = S+O_MEM;
        float* rwS = S+O_RW;   float* wwO = S+O_WWO; float* wwN = S+O_WWN;
        float* usg = S+O_USG;  float* prc = S+O_PRC; float* xiS = S+O_XI;
        float* keys = S+O_KEY; float* wkey = S+O_WK; float* ers = S+O_ER;
        float* wvec = S+O_WV;  float* rstr = S+O_RS; float* fgte = S+O_FG;
        float* modes = S+O_MD; float* nkey = S+O_NK; float* sc = S+O_SC;
        float* nmo = S+O_NMO;  float* nmn = S+O_NMN; float* wcw = S+O_WCW;
        float* uu = S+O_UU;    float* su = S+O_SU;   float* cum = S+O_CUM;
        int*   rnk = (int*)(S+O_RNK);
        float* ccw = S+O_CCW;  float* fwdT = S+O_FWD; float* rv = S+O_RV;
        float* red = S+O_RED;

        for (int e = tid; e < NM*LKS; e += TPB) lk[e] = 0.0f;
        for (int e = tid; e < NM*NW; e += TPB) mem[(e>>6)*MS + (e&63)] = EPSF;
        for (int e = tid; e < NR*NM; e += TPB) rwS[e]=0.0f;
        for (int e = tid; e < NM; e += TPB){ wwO[e]=0.0f; usg[e]=0.0f; prc[e]=0.0f; }
        __syncthreads();

        for (int t = 0; t < NT; ++t) {
            const int par = t & 1;

            // nmo — old mem norms (overlaps gates' xi production)
            #pragma unroll
            for (int ri = 0; ri < 8; ++ri) {
                int row = wv*8 + ri;
                float v = mem[row*MS + l];
                float s2 = wave_red(v*v);
                if (l == 0) nmo[row] = sqrtf(s2);
            }
            // xi(t) ready from the 118 xi-owning gate blocks
            multi_wait_d(&FLGD[D_X], NXB, (unsigned)(t+1), tid);
            if (tid < 120)
                *(f4*)&xiS[tid*4] =
                    cload4(&pubXI[(size_t)par*NBATCH*480 + b*480 + tid*4]);
            __syncthreads();

            // E1: unpack interface
            if (tid < 256)       keys[tid] = tanhf(xiS[tid]);
            else if (tid < 260)  rstr[tid-256] = sftp(xiS[tid]);
            else if (tid < 324)  wkey[tid-260] = tanhf(xiS[tid]);
            else if (tid == 324) sc[0] = sftp(xiS[324]);
            else if (tid < 389)  ers[tid-325] = sigm(xiS[tid]);
            else if (tid < 453)  wvec[tid-389] = tanhf(xiS[tid]);
            else if (tid < 457)  fgte[tid-453] = sigm(xiS[tid]);
            else if (tid == 457) sc[1] = sigm(xiS[457]);
            else if (tid == 458) sc[2] = sigm(xiS[458]);
            else if (tid < 463) {
                int r = tid - 459;
                float a0=xiS[459+3*r], a1=xiS[460+3*r], a2=xiS[461+3*r];
                float mx = fmaxf(a0, fmaxf(a1, a2));
                float e0=expf(a0-mx), e1=expf(a1-mx), e2=expf(a2-mx);
                float si = 1.0f/(e0+e1+e2);
                modes[3*r]=e0*si; modes[3*r+1]=e1*si; modes[3*r+2]=e2*si;
            }
            __syncthreads();

            // E2: key norms (waves 0-4, wave-parallel) ∥ usage+uu (waves 6-7)
            if (wv < 4) {
                float v = keys[wv*NW + l];
                float s2 = wave_red(v*v);
                if (l == 0) nkey[wv] = sqrtf(s2);
            } else if (wv == 4) {
                float v = wkey[l];
                float s2 = wave_red(v*v);
                if (l == 0) sc[3] = sqrtf(s2);
            } else if (wv == 6 || wv == 7) {
                int m = tid - 384;
                float u = usg[m];
                u = u + (1.0f - u)*wwO[m];
                float psi = 1.0f;
                #pragma unroll
                for (int r = 0; r < NR; ++r) psi *= (1.0f - fgte[r]*rwS[r*NM+m]);
                u *= psi;
                usg[m] = u;
                uu[m] = 5e-6f + (1.0f - 5e-6f)*u;
            }
            __syncthreads();

            // F1: write-content logits — 8 threads per row (8 iters + 3 shfl)
            {
                const int m = tid >> 3, s = tid & 7;
                const int w0 = s*8;
                float d = 0.0f;
                #pragma unroll
                for (int k = 0; k < 8; ++k) d += wkey[w0+k]*mem[m*MS+w0+k];
                d += __shfl_down(d, 4); d += __shfl_down(d, 2); d += __shfl_down(d, 1);
                if (s == 0) wcw[m] = d/(sc[3]*nmo[m] + EPSF) * sc[0];
            }
            __syncthreads();
            // F2: softmax over 128
            if (tid < 64) {
                float v = fmaxf(wcw[tid], wcw[tid+64]);
                #pragma unroll
                for (int o = 32; o > 0; o >>= 1) v = fmaxf(v, __shfl_down(v, o));
                if (tid == 0) red[0] = v;
            }
            __syncthreads();
            if (tid < NM) wcw[tid] = expf(wcw[tid] - red[0]);
            __syncthreads();
            if (tid < 64) {
                float v = wave_red(wcw[tid] + wcw[tid+64]);
                if (tid == 0) red[0] = 1.0f/v;
            }
            __syncthreads();
            if (tid < NM) wcw[tid] *= red[0];
            __syncthreads();

            // G2: stable rank — 8 threads per row (16 iters + 3 shfl)
            {
                const int m = tid >> 3, s = tid & 7;
                const float um = uu[m];
                const int j0 = s*16;
                int rk = 0;
                #pragma unroll
                for (int k = 0; k < 16; ++k) {
                    int j = j0 + k;
                    float uj = uu[j];
                    rk += (uj < um) || (uj == um && j < m);
                }
                rk += __shfl_down(rk, 4); rk += __shfl_down(rk, 2); rk += __shfl_down(rk, 1);
                if (s == 0) { rnk[m] = rk; su[rk] = um; }
            }
            __syncthreads();
            // G3: product scan (wave 0)
            if (tid < 64) {
                float a = su[tid], bb = su[64+tid];
                #pragma unroll
                for (int o = 1; o < 64; o <<= 1) {
                    float ta = __shfl_up(a, o);
                    float tb = __shfl_up(bb, o);
                    if (tid >= o) { a *= ta; bb *= tb; }
                }
                float P0 = __shfl(a, 63);
                cum[tid] = a;
                cum[64+tid] = P0*bb;
            }
            __syncthreads();
            // G4: alloc + write weighting
            if (tid < NM) {
                int rk = rnk[tid];
                float excl = (rk == 0) ? 1.0f : cum[rk-1];
                float al = (1.0f - uu[tid])*excl;
                wwN[tid] = sc[2]*(sc[1]*al + (1.0f - sc[1])*wcw[tid]);
            }
            __syncthreads();
            // G5: sum(wwN)
            if (tid < 64) {
                float v = wave_red(wwN[tid] + wwN[tid+64]);
                if (tid == 0) sc[4] = v;
            }
            __syncthreads();

            // H (fused): mem erase/write + new norms + link (stride-129)
            #pragma unroll
            for (int ri = 0; ri < 8; ++ri) {
                int row = wv*8 + ri;
                float wm = wwN[row];
                float v = mem[row*MS + l];
                float nv = v*(1.0f - wm*ers[l]) + wm*wvec[l];
                mem[row*MS + l] = nv;
                float s2 = wave_red(nv*nv);
                if (l == 0) nmn[row] = sqrtf(s2);
            }
            for (int e = tid; e < NM*NM; e += TPB) {
                int i = e >> 7, j = e & 127;
                int a = i*LKS + j;
                float nl = (i == j) ? 0.0f
                         : (1.0f - wwN[i] - wwN[j])*lk[a] + wwN[i]*prc[j];
                lk[a] = nl;
            }
            __syncthreads();
            // H3: precedence
            if (tid < NM) prc[tid] = (1.0f - sc[4])*prc[tid] + wwN[tid];
            __syncthreads();

            // I: read-content logits — 2 threads per dot (32 iters + 1 shfl)
            {
                const int p = tid >> 1, s = tid & 1;
                const int r = p >> 7, m = p & 127, w0 = s*32;
                float d = 0.0f;
                #pragma unroll 8
                for (int k = 0; k < 32; ++k)
                    d += keys[r*NW + w0 + k]*mem[m*MS + w0 + k];
                d += __shfl_down(d, 1);
                if (s == 0) ccw[p] = d/(nkey[r]*nmn[m] + EPSF) * rstr[r];
            }
            __syncthreads();
            // ccw per-r softmax
            if (tid < 256) {
                int r = tid >> 6, ll = tid & 63;
                float v = fmaxf(ccw[r*NM+ll], ccw[r*NM+ll+64]);
                #pragma unroll
                for (int o = 32; o > 0; o >>= 1) v = fmaxf(v, __shfl_down(v, o));
                if (ll == 0) red[r] = v;
            }
            __syncthreads();
            if (tid < NR*NM) ccw[tid] = expf(ccw[tid] - red[tid>>7]);
            __syncthreads();
            if (tid < 256) {
                int r = tid >> 6, ll = tid & 63;
                float v = wave_red(ccw[r*NM+ll] + ccw[r*NM+ll+64]);
                if (ll == 0) red[4+r] = 1.0f/v;
            }
            __syncthreads();
            if (tid < NR*NM) ccw[tid] *= red[4+(tid>>7)];
            __syncthreads();

            // J1: fwd — 2 threads per dot, row-major lk (stride 129, no conflict)
            {
                const int p = tid >> 1, s = tid & 1;
                const int r = p >> 7, m = p & 127, i0 = s*64;
                float d = 0.0f;
                #pragma unroll 8
                for (int k = 0; k < 64; ++k)
                    d += lk[m*LKS + i0 + k]*rwS[r*NM + i0 + k];
                d += __shfl_down(d, 1);
                if (s == 0) fwdT[p] = d;
            }
            __syncthreads();
            // J2: bwd + mode mix — 2 threads per dot (column reads, spread banks)
            float rwnew = 0.0f;
            {
                const int p = tid >> 1, s = tid & 1;
                const int r = p >> 7, m = p & 127, i0 = s*64;
                float bw = 0.0f;
                #pragma unroll 8
                for (int k = 0; k < 64; ++k)
                    bw += lk[(i0+k)*LKS + m]*rwS[r*NM + i0 + k];
                bw += __shfl_down(bw, 1);
                if (s == 0)
                    rwnew = modes[3*r]*bw + modes[3*r+1]*fwdT[p]
                          + modes[3*r+2]*ccw[p];
            }
            __syncthreads();
            if ((tid & 1) == 0) rwS[tid >> 1] = rwnew;
            __syncthreads();

            // K: read vectors — 4 threads per (r,w) (32 iters + 2 shfl)
            {
                const int r = tid >> 8, q = tid & 255, w = q >> 2, mg = q & 3;
                const int m0 = mg*32;
                float ssum = 0.0f;
                #pragma unroll 8
                for (int k = 0; k < 32; ++k)
                    ssum += rwS[r*NM + m0 + k]*mem[(m0+k)*MS + w];
                ssum += __shfl_down(ssum, 1); ssum += __shfl_down(ssum, 2);
                if (mg == 0) rv[r*NW + w] = ssum;
            }
            __syncthreads();
            if (tid < 64)
                cstore4(&pubRV[(size_t)par*NBATCH*NR*NW + b*NR*NW + tid*4],
                        *(const f4*)&rv[tid*4]);
            flag_set_d(&FLGD[D_R + b], (unsigned)(t+1), tid);

            if (tid < NM) wwO[tid] = wwN[tid];
            __syncthreads();
        }
    } else {
        // ===== GATES block: 4 units (16 gate rows) + LSTM + 4 xi + 4 out ====
        const int g = bid - 32;            // owns units u = 4g .. 4g+3
        const int gate = wv >> 2, j = wv & 3;
        const int r = gate*NH + 4*g + j;   // weight row: gate, unit 4g+j
        const f4* WA = (const f4*)(W_ih + (size_t)r*NI);
        f4 wx0 = WA[l], wx1 = WA[l+64], wrv = WA[128+l];
        const f4* WB = (const f4*)(W_hh + (size_t)r*NH);
        f4 wh0 = WB[l], wh1 = WB[l+64];
        const float bias = b_ih[r] + b_hh[r];
        float* accS = S + G_ACC;   // [32][17] (stride 17: conflict-free)
        float* cSg  = S + G_C;     // [32][5]  (stride 5: conflict-free)
        float* hStg = S + G_H;     // [32][512] h(t-1) staging
        const int sbi = tid >> 7, sk4 = (tid & 127) << 2;

        if (tid < 160) cSg[tid] = 0.0f;
        for (int e = tid; e < NBATCH*NH; e += TPB) hStg[e] = 0.0f;  // h(-1)=0
        __syncthreads();

        for (int t = 0; t <= NT; ++t) {          // NT+1 iters (epilogue at NT)
            const int par = t & 1, parp = (t+1) & 1;   // parp = parity of t-1

            // A: stage ALL h(t-1); then xi(t-1) from our 8KB W_xi slice
            if (t >= 1) {
                multi_wait_d(&FLGD[D_G], 128, (unsigned)t, tid);   // h(t-1) all
                const float* hIn = pubH + (size_t)parp*NBATCH*NH;
                f4 a0, a1, a2, a3;
                cload4x4(hIn + tid*4, hIn + (tid+1024)*4,
                         hIn + (tid+2048)*4, hIn + (tid+3072)*4,
                         a0, a1, a2, a3);
                *(f4*)&hStg[tid*4]          = a0;
                *(f4*)&hStg[(tid+1024)*4]   = a1;
                *(f4*)&hStg[(tid+2048)*4]   = a2;
                *(f4*)&hStg[(tid+3072)*4]   = a3;
                __syncthreads();
                if (g < NXB) {
                    float* xOut = pubXI + (size_t)parp*NBATCH*480;
                    #pragma unroll
                    for (int bb = 0; bb < 2; ++bb) {
                        const int bi = 2*wv + bb;
                        const f4* H4 = (const f4*)(hStg + bi*512);
                        f4 res = {0.0f, 0.0f, 0.0f, 0.0f};
                        #pragma unroll
                        for (int jj = 0; jj < 4; ++jj) {
                            const int row = 4*g + jj;
                            if (row < NXI) {
                                const f4* WX = (const f4*)(W_xi + (size_t)row*NH);
                                float a = dot4(WX[l], H4[l])
                                        + dot4(WX[l+64], H4[l+64]);
                                a = wave_red(a);
                                res[jj] = a + b_xi[row];
                            }
                        }
                        if (l == 0) cstore4(&xOut[(size_t)bi*480 + 4*g], res);
                    }
                    flag_set_d(&FLGD[D_X + g], (unsigned)t, tid);
                }
            }

            // B: heavy phase x(t)·W_ih + h(t-1)·W_hh (off critical path)
            if (t < NT) {
                for (int p = 0; p < 4; ++p) {
                    const int b0 = p*8;
                    *(f4*)&S[sbi*512 + sk4] =
                        *(const f4*)&x[((size_t)(b0+sbi)*NT + t)*NH + sk4];
                    __syncthreads();
                    #pragma unroll
                    for (int bi = 0; bi < 8; ++bi) {
                        const f4* X4 = (const f4*)(S + bi*512);
                        const f4* H4 = (const f4*)(hStg + (b0+bi)*512);
                        float a = dot4(wx0, X4[l]) + dot4(wx1, X4[l+64])
                                + dot4(wh0, H4[l]) + dot4(wh1, H4[l+64]);
                        a = wave_red(a);
                        if (l == 0) accS[(b0+bi)*17 + wv] = a + bias;
                    }
                    __syncthreads();
                }
            }

            // C: rv(t-1) — the critical-path input
            {
                const int bi0 = tid >> 6, k40 = (tid & 63) << 2;
                if (t >= 1) {
                    multi_wait_d(&FLGD[D_R], 32, (unsigned)t, tid);
                    const float* rIn = pubRV + (size_t)parp*NBATCH*NR*NW;
                    f4 a0, a1;
                    cload4x2(&rIn[bi0*256 + k40], &rIn[(bi0+16)*256 + k40], a0, a1);
                    *(f4*)&S[bi0*256 + k40] = a0;
                    *(f4*)&S[(bi0+16)*256 + k40] = a1;
                } else {
                    f4 z = {0.0f, 0.0f, 0.0f, 0.0f};
                    *(f4*)&S[bi0*256 + k40] = z;
                    *(f4*)&S[(bi0+16)*256 + k40] = z;
                }
            }
            __syncthreads();

            // D: rv dot + LSTM + publish h(t)
            if (t < NT) {
                #pragma unroll
                for (int bi = 0; bi < 32; ++bi) {
                    const f4* RV4 = (const f4*)(S + bi*256);
                    float d = dot4(wrv, RV4[l]);
                    d = wave_red(d);
                    if (l == 0) accS[bi*17 + wv] += d;
                }
                __syncthreads();
                if (tid < 32) {
                    const int bi = tid;
                    const float* acc = accS + bi*17;
                    f4 hq;
                    #pragma unroll
                    for (int jj = 0; jj < 4; ++jj) {
                        float i_ = sigm(acc[0*4 + jj]);
                        float f_ = sigm(acc[1*4 + jj]);
                        float g_ = tanhf(acc[2*4 + jj]);
                        float o_ = sigm(acc[3*4 + jj]);
                        float c  = f_*cSg[bi*5 + jj] + i_*g_;
                        cSg[bi*5 + jj] = c;
                        hq[jj] = o_*tanhf(c);
                    }
                    cstore4(&pubH[(size_t)par*NBATCH*NH + (size_t)bi*NH + 4*g], hq);
                }
                flag_set_d(&FLGD[D_G + g], (unsigned)(t+1), tid);
            }

            // E: out(t-1) from hStg (h(t-1)) + staged rv(t-1) — idle shadow
            if (t >= 1) {
                #pragma unroll
                for (int bb = 0; bb < 2; ++bb) {
                    const int bi = 2*wv + bb;
                    const f4* H4 = (const f4*)(hStg + bi*512);
                    const f4* RV4 = (const f4*)(S + bi*256);
                    f4 res;
                    #pragma unroll
                    for (int jj = 0; jj < 4; ++jj) {
                        const int row = 4*g + jj;
                        const f4* WO = (const f4*)(W_o + (size_t)row*NI);
                        float a = dot4(WO[l], H4[l]) + dot4(WO[l+64], H4[l+64])
                                + dot4(WO[128+l], RV4[l]);
                        a = wave_red(a);
                        res[jj] = a + b_o[row];
                    }
                    if (l == 0)
                        *(f4*)&out[((size_t)bi*NT + (t-1))*NH + 4*g] = res;
                }
            }
            // next iter's D_G multi_wait barrier orders these reads vs restaging
        }
    }
}

extern "C" void kernel_launch(void* const* d_in, const int* in_sizes, int n_in,
                              void* d_out, int out_size, void* d_ws, size_t ws_size,
                              hipStream_t stream) {
    (void)in_sizes; (void)n_in; (void)out_size; (void)ws_size;
    const float* x    = (const float*)d_in[0];
    const float* W_ih = (const float*)d_in[1];
    const float* W_hh = (const float*)d_in[2];
    const float* b_ih = (const float*)d_in[3];
    const float* b_hh = (const float*)d_in[4];
    const float* W_xi = (const float*)d_in[5];
    const float* b_xi = (const float*)d_in[6];
    const float* W_o  = (const float*)d_in[7];
    const float* b_o  = (const float*)d_in[8];
    float* out = (float*)d_out;
    float* ws  = (float*)d_ws;

    dnc_zero<<<1, 512, 0, stream>>>(ws);

    void* args[] = { (void*)&x, (void*)&W_ih, (void*)&W_hh, (void*)&b_ih,
                     (void*)&b_hh, (void*)&W_xi, (void*)&b_xi, (void*)&W_o,
                     (void*)&b_o, (void*)&out, (void*)&ws };
    hipLaunchCooperativeKernel((void*)dnc_pipe2, dim3(NBLK), dim3(TPB),
                               args, 0, stream);
}

// Round 7
// 3023.374 us; speedup vs baseline: 1.9380x; 1.0104x over previous
//
#include <hip/hip_runtime.h>
#include <math.h>

#define TPB 1024
#define NBLK 160
#define NBATCH 32
#define NT 64
#define NH 512
#define NM 128
#define NR 4
#define NW 64
#define NI 768          // controller input size (H + R*W)
#define NXI 471         // interface vector size
#define EPSF 1e-6f
#define MS 65           // mem row stride (+1 pad)
#define LKS 129         // link matrix row stride (+1 pad: conflict-free row dots)

// roles: [0,32) state (DNC machinery only) |
//        [32,160) gates blocks: 4 hidden units (16 gate rows) + LSTM cell
//                 + 4 xi rows + 4 out rows (distributed W_xi / W_o streams)

typedef float f4 __attribute__((ext_vector_type(4)));

// ws layout (float offsets). pub* parity double-buffered.
#define WS_PUBH  0                                 // [2][32][512] (gates)
#define WS_PUBRV (WS_PUBH + 2*NBATCH*NH)           // [2][32][256] (state)
#define WS_PUBXI (WS_PUBRV + 2*NBATCH*NR*NW)       // [2][32][480] (gates)
#define WS_FLAGS (WS_PUBXI + 2*NBATCH*480)
// packed flag dwords
#define D_G 0        // 128 gate blocks: h(t) published -> t+1
#define D_R 128      // 32 state blocks: rv(t) published -> t+1
#define D_X 160      // 118 gate blocks: xi(t-1) published -> t
#define D_TOTAL 288
#define NXB 118      // gate blocks that own xi rows (4*118 >= 471)

__device__ __forceinline__ float sigm(float x){ return 1.0f/(1.0f+expf(-x)); }
__device__ __forceinline__ float sftp(float x){ return fmaxf(x,0.0f)+log1pf(expf(-fabsf(x))); }
__device__ __forceinline__ float dot4(f4 a, f4 b){
    return a.x*b.x + a.y*b.y + a.z*b.z + a.w*b.w;
}
__device__ __forceinline__ float wave_red(float v){
    #pragma unroll
    for (int o = 32; o > 0; o >>= 1) v += __shfl_down(v, o);
    return v;
}

// ---- coherent (LLC write-through, device-visible) accessors: sc0 sc1 ----
// waitcnt INSIDE each asm statement => no rule-18 hoist hazard.
__device__ __forceinline__ f4 cload4(const float* p){
    f4 v;
    asm volatile("global_load_dwordx4 %0, %1, off sc0 sc1\n\t"
                 "s_waitcnt vmcnt(0)"
                 : "=&v"(v) : "v"(p) : "memory");
    return v;
}
__device__ __forceinline__ void cload4x2(const float* p0, const float* p1,
                                         f4& a, f4& b){
    asm volatile("global_load_dwordx4 %0, %2, off sc0 sc1\n\t"
                 "global_load_dwordx4 %1, %3, off sc0 sc1\n\t"
                 "s_waitcnt vmcnt(0)"
                 : "=&v"(a), "=&v"(b) : "v"(p0), "v"(p1) : "memory");
}
__device__ __forceinline__ void cload4x4(const float* p0, const float* p1,
                                         const float* p2, const float* p3,
                                         f4& a, f4& b, f4& c, f4& d){
    asm volatile("global_load_dwordx4 %0, %4, off sc0 sc1\n\t"
                 "global_load_dwordx4 %1, %5, off sc0 sc1\n\t"
                 "global_load_dwordx4 %2, %6, off sc0 sc1\n\t"
                 "global_load_dwordx4 %3, %7, off sc0 sc1\n\t"
                 "s_waitcnt vmcnt(0)"
                 : "=&v"(a), "=&v"(b), "=&v"(c), "=&v"(d)
                 : "v"(p0), "v"(p1), "v"(p2), "v"(p3) : "memory");
}
__device__ __forceinline__ void cstore4(float* p, f4 v){
    asm volatile("global_store_dwordx4 %0, %1, off sc0 sc1"
                 :: "v"(p), "v"(v) : "memory");
}

// ---- packed-flag protocol: coalesced parallel polls, no RMW, no RELEASE ----
__device__ __forceinline__ void multi_wait_d(const unsigned int* f, int n,
                                             unsigned int tgt, int tid){
    if (tid < n) {
        const unsigned int* p = f + tid;          // consecutive dwords: coalesced
        while (__hip_atomic_load(p, __ATOMIC_RELAXED,
                                 __HIP_MEMORY_SCOPE_AGENT) < tgt)
            __builtin_amdgcn_s_sleep(2);
    }
    __syncthreads();
}
// all cross-block data stores are sc0 sc1 (write-through to coherence point);
// per-wave vmcnt(0) drain + barrier + RELAXED flag store is a correct release.
__device__ __forceinline__ void flag_set_d(unsigned int* f, unsigned int v, int tid){
    asm volatile("s_waitcnt vmcnt(0)" ::: "memory");
    __syncthreads();
    if (tid == 0)
        __hip_atomic_store(f, v, __ATOMIC_RELAXED, __HIP_MEMORY_SCOPE_AGENT);
}

__global__ void dnc_zero(float* ws){
    unsigned int* z = (unsigned int*)(ws + WS_FLAGS);
    for (int e = threadIdx.x; e < D_TOTAL; e += blockDim.x) z[e] = 0u;
}

// ---- pooled LDS (floats) ----
#define O_MEM 0         // 8320 (128 x 65)
#define O_RW  8320      // 512
#define O_RWN 8832      // 512
#define O_WWO 9344      // 128
#define O_WWN 9472      // 128
#define O_USG 9600      // 128
#define O_PRC 9728      // 128
#define O_XI  9856      // 480
#define O_KEY 10336     // 256
#define O_WK  10592     // 64
#define O_ER  10656     // 64
#define O_WV  10720     // 64
#define O_RS  10784     // 4
#define O_FG  10788     // 4
#define O_MD  10792     // 12
#define O_NK  10804     // 4
#define O_SC  10808     // 8
#define O_NRM 10816     // 2 x 128 double-buffered row norms
#define O_WCW 11072     // 128
#define O_UU  11200     // 128
#define O_SU  11328     // 128
#define O_CUM 11456     // 128
#define O_RNK 11584     // 128 (int)
#define O_CCW 11712     // 512
#define O_FWD 12224     // 512
#define O_RV  12736     // 256
#define O_RED 12992     // 16
#define O_LK  13008     // 128*129 link matrix (padded stride)
#define S_SZ  (13008 + NM*LKS)     // 29520 floats = 118,080 B; 1 block/CU
// gates role (disjoint): x/rv staging S[0..8191]
#define G_ACC 8192      // [32][17] (stride 17: conflict-free LSTM reads)
#define G_C   8736      // [32][5]  (stride 5: conflict-free)
#define G_H   8896      // [32][512] h(t-1) staging

__global__ __launch_bounds__(TPB) void dnc_pipe2(
    const float* __restrict__ x, const float* __restrict__ W_ih,
    const float* __restrict__ W_hh, const float* __restrict__ b_ih,
    const float* __restrict__ b_hh, const float* __restrict__ W_xi,
    const float* __restrict__ b_xi, const float* __restrict__ W_o,
    const float* __restrict__ b_o, float* __restrict__ out,
    float* __restrict__ ws)
{
    __shared__ __align__(16) float S[S_SZ];

    const int tid = threadIdx.x;
    const int wv  = tid >> 6;
    const int l   = tid & 63;
    const int bid = blockIdx.x;

    float* __restrict__ pubH  = ws + WS_PUBH;
    float* __restrict__ pubRV = ws + WS_PUBRV;
    float* __restrict__ pubXI = ws + WS_PUBXI;
    unsigned int* __restrict__ FLGD = (unsigned int*)(ws + WS_FLAGS);

    if (bid < NBATCH) {
        // ========================= STATE block =========================
        const int b = bid;
        float* lk = S+O_LK;
        float* mem = S+O_MEM;
        float* rwS = S+O_RW;   float* rwN = S+O_RWN;
        float* wwO = S+O_WWO;  float* wwN = S+O_WWN;
        float* usg = S+O_USG;  float* prc = S+O_PRC; float* xiS = S+O_XI;
        float* keys = S+O_KEY; float* wkey = S+O_WK; float* ers = S+O_ER;
        float* wvec = S+O_WV;  float* rstr = S+O_RS; float* fgte = S+O_FG;
        float* modes = S+O_MD; float* nkey = S+O_NK; float* sc = S+O_SC;
        float* nrm = S+O_NRM;  float* wcw = S+O_WCW;
        float* uu = S+O_UU;    float* su = S+O_SU;   float* cum = S+O_CUM;
        int*   rnk = (int*)(S+O_RNK);
        float* ccw = S+O_CCW;  float* fwdT = S+O_FWD; float* rv = S+O_RV;
        float* red = S+O_RED;

        for (int e = tid; e < NM*LKS; e += TPB) lk[e] = 0.0f;
        for (int e = tid; e < NM*NW; e += TPB) mem[(e>>6)*MS + (e&63)] = EPSF;
        for (int e = tid; e < NR*NM; e += TPB) rwS[e]=0.0f;
        for (int e = tid; e < NM; e += TPB){ wwO[e]=0.0f; usg[e]=0.0f; prc[e]=0.0f; }
        for (int e = tid; e < 2*NM; e += TPB) nrm[e] = 8.0f*EPSF; // ||EPS row||
        __syncthreads();

        for (int t = 0; t < NT; ++t) {
            const int par = t & 1;
            float* nmo = nrm + 128*(t & 1);        // old norms = prev step's new
            float* nmn = nrm + 128*((t+1) & 1);

            // P1: xi(t) ready; load (nmo phase deleted: double-buffered norms)
            multi_wait_d(&FLGD[D_X], NXB, (unsigned)(t+1), tid);
            if (tid < 120)
                *(f4*)&xiS[tid*4] =
                    cload4(&pubXI[(size_t)par*NBATCH*480 + b*480 + tid*4]);
            __syncthreads();

            // P2: E1 unpack interface
            if (tid < 256)       keys[tid] = tanhf(xiS[tid]);
            else if (tid < 260)  rstr[tid-256] = sftp(xiS[tid]);
            else if (tid < 324)  wkey[tid-260] = tanhf(xiS[tid]);
            else if (tid == 324) sc[0] = sftp(xiS[324]);
            else if (tid < 389)  ers[tid-325] = sigm(xiS[tid]);
            else if (tid < 453)  wvec[tid-389] = tanhf(xiS[tid]);
            else if (tid < 457)  fgte[tid-453] = sigm(xiS[tid]);
            else if (tid == 457) sc[1] = sigm(xiS[457]);
            else if (tid == 458) sc[2] = sigm(xiS[458]);
            else if (tid < 463) {
                int r = tid - 459;
                float a0=xiS[459+3*r], a1=xiS[460+3*r], a2=xiS[461+3*r];
                float mx = fmaxf(a0, fmaxf(a1, a2));
                float e0=expf(a0-mx), e1=expf(a1-mx), e2=expf(a2-mx);
                float si = 1.0f/(e0+e1+e2);
                modes[3*r]=e0*si; modes[3*r+1]=e1*si; modes[3*r+2]=e2*si;
            }
            __syncthreads();

            // P3: key norms (waves 0-4) ∥ usage+uu (waves 6-7)
            if (wv < 4) {
                float v = keys[wv*NW + l];
                float s2 = wave_red(v*v);
                if (l == 0) nkey[wv] = sqrtf(s2);
            } else if (wv == 4) {
                float v = wkey[l];
                float s2 = wave_red(v*v);
                if (l == 0) sc[3] = sqrtf(s2);
            } else if (wv == 6 || wv == 7) {
                int m = tid - 384;
                float u = usg[m];
                u = u + (1.0f - u)*wwO[m];
                float psi = 1.0f;
                #pragma unroll
                for (int r = 0; r < NR; ++r) psi *= (1.0f - fgte[r]*rwS[r*NM+m]);
                u *= psi;
                usg[m] = u;
                uu[m] = 5e-6f + (1.0f - 5e-6f)*u;
            }
            __syncthreads();

            // P4: F1 write-content logits — 8 threads per row
            {
                const int m = tid >> 3, s = tid & 7;
                const int w0 = s*8;
                float d = 0.0f;
                #pragma unroll
                for (int k = 0; k < 8; ++k) d += wkey[w0+k]*mem[m*MS+w0+k];
                d += __shfl_down(d, 4); d += __shfl_down(d, 2); d += __shfl_down(d, 1);
                if (s == 0) wcw[m] = d/(sc[3]*nmo[m] + EPSF) * sc[0];
            }
            __syncthreads();

            // P5: wcw softmax (wave 0, single phase) ∥ G2 rank (waves 8-15)
            if (tid < 64) {
                float w0 = wcw[l], w1 = wcw[l+64];
                float mx = fmaxf(w0, w1);
                #pragma unroll
                for (int o = 32; o > 0; o >>= 1) mx = fmaxf(mx, __shfl_down(mx, o));
                float M = __shfl(mx, 0);
                float e0 = expf(w0 - M), e1 = expf(w1 - M);
                float s = wave_red(e0 + e1);
                float inv = 1.0f/__shfl(s, 0);
                wcw[l] = e0*inv; wcw[l+64] = e1*inv;
            } else if (tid >= 512) {
                // 4 threads/row, stride-4 interleave (broadcast reads, no conflict)
                const int q = tid - 512, m = q >> 2, s = q & 3;
                const float um = uu[m];
                int rk = 0;
                #pragma unroll 8
                for (int k = 0; k < 32; ++k) {
                    int j = 4*k + s;
                    float uj = uu[j];
                    rk += (uj < um) || (uj == um && j < m);
                }
                rk += __shfl_down(rk, 1); rk += __shfl_down(rk, 2);
                if (s == 0) { rnk[m] = rk; su[rk] = um; }
            }
            __syncthreads();

            // P6: product scan (wave 0)
            if (tid < 64) {
                float a = su[tid], bb = su[64+tid];
                #pragma unroll
                for (int o = 1; o < 64; o <<= 1) {
                    float ta = __shfl_up(a, o);
                    float tb = __shfl_up(bb, o);
                    if (tid >= o) { a *= ta; bb *= tb; }
                }
                float P0 = __shfl(a, 63);
                cum[tid] = a;
                cum[64+tid] = P0*bb;
            }
            __syncthreads();

            // P7: alloc + wwN + per-wave alloc-sum partials (G5 analytic)
            if (tid < NM) {
                int rk = rnk[tid];
                float excl = (rk == 0) ? 1.0f : cum[rk-1];
                float al = (1.0f - uu[tid])*excl;
                wwN[tid] = sc[2]*(sc[1]*al + (1.0f - sc[1])*wcw[tid]);
                float sal = wave_red(al);
                if (l == 0) red[2 + wv] = sal;     // wave0->red[2], wave1->red[3]
            }
            __syncthreads();

            // P8: H fused: sc[4] analytic + mem erase/write + nmn + link update
            if (tid == 1023)
                sc[4] = sc[2]*(sc[1]*(red[2]+red[3]) + (1.0f - sc[1]));
            #pragma unroll
            for (int ri = 0; ri < 8; ++ri) {
                int row = wv*8 + ri;
                float wm = wwN[row];
                float v = mem[row*MS + l];
                float nv = v*(1.0f - wm*ers[l]) + wm*wvec[l];
                mem[row*MS + l] = nv;
                float s2 = wave_red(nv*nv);
                if (l == 0) nmn[row] = sqrtf(s2);
            }
            #pragma unroll
            for (int k = 0; k < 16; ++k) {
                int e = tid + k*TPB;
                int i = e >> 7, j = e & 127;
                int a = i*LKS + j;
                float nl = (i == j) ? 0.0f
                         : (1.0f - wwN[i] - wwN[j])*lk[a] + wwN[i]*prc[j];
                lk[a] = nl;
            }
            __syncthreads();

            // P9: I read-content logits — 2 threads per dot
            {
                const int p = tid >> 1, s = tid & 1;
                const int r = p >> 7, m = p & 127, w0 = s*32;
                float d = 0.0f;
                #pragma unroll 8
                for (int k = 0; k < 32; ++k)
                    d += keys[r*NW + w0 + k]*mem[m*MS + w0 + k];
                d += __shfl_down(d, 1);
                if (s == 0) ccw[p] = d/(nkey[r]*nmn[m] + EPSF) * rstr[r];
            }
            __syncthreads();

            // P10: ccw softmax (waves 0-3, one r each) ∥ J1 r∈{1,2,3} (waves 4-15)
            if (tid < 256) {
                float v0 = ccw[wv*NM + l], v1 = ccw[wv*NM + 64 + l];
                float mx = fmaxf(v0, v1);
                #pragma unroll
                for (int o = 32; o > 0; o >>= 1) mx = fmaxf(mx, __shfl_down(mx, o));
                float M = __shfl(mx, 0);
                float e0 = expf(v0 - M), e1 = expf(v1 - M);
                float s = wave_red(e0 + e1);
                float inv = 1.0f/__shfl(s, 0);
                ccw[wv*NM + l] = e0*inv; ccw[wv*NM + 64 + l] = e1*inv;
            } else {
                const int q = tid - 256, p = 128 + (q >> 1), s = q & 1;
                const int m = p & 127, i0 = s*64;
                const int r = p >> 7;
                float d = 0.0f;
                #pragma unroll 8
                for (int k = 0; k < 64; ++k)
                    d += lk[m*LKS + i0 + k]*rwS[r*NM + i0 + k];
                d += __shfl_down(d, 1);
                if (s == 0) fwdT[p] = d;
            }
            __syncthreads();

            // P11: J1 r=0 (tid<256) ∥ J2 r∈{1,2,3} (tid>=256)
            if (tid < 256) {
                const int p = tid >> 1, s = tid & 1;
                const int m = p & 127, i0 = s*64;
                float d = 0.0f;
                #pragma unroll 8
                for (int k = 0; k < 64; ++k)
                    d += lk[m*LKS + i0 + k]*rwS[i0 + k];
                d += __shfl_down(d, 1);
                if (s == 0) fwdT[p] = d;
            } else {
                const int q = tid - 256, p = 128 + (q >> 1), s = q & 1;
                const int r = p >> 7, m = p & 127, i0 = s*64;
                float bw = 0.0f;
                #pragma unroll 8
                for (int k = 0; k < 64; ++k)
                    bw += lk[(i0+k)*LKS + m]*rwS[r*NM + i0 + k];
                bw += __shfl_down(bw, 1);
                if (s == 0)
                    rwN[p] = modes[3*r]*bw + modes[3*r+1]*fwdT[p]
                           + modes[3*r+2]*ccw[p];
            }
            __syncthreads();

            // P12: J2 r=0 (tid<256) ∥ K r∈{1,2,3} (tid>=256)
            if (tid < 256) {
                const int p = tid >> 1, s = tid & 1;
                const int m = p & 127, i0 = s*64;
                float bw = 0.0f;
                #pragma unroll 8
                for (int k = 0; k < 64; ++k)
                    bw += lk[(i0+k)*LKS + m]*rwS[i0 + k];
                bw += __shfl_down(bw, 1);
                if (s == 0)
                    rwN[p] = modes[0]*bw + modes[1]*fwdT[p] + modes[2]*ccw[p];
            } else {
                const int q = tid - 256, r = 1 + (q >> 8);
                const int q2 = q & 255, w = q2 >> 2, mg = q2 & 3;
                const int m0 = mg*32;
                float ssum = 0.0f;
                #pragma unroll 8
                for (int k = 0; k < 32; ++k)
                    ssum += rwN[r*NM + m0 + k]*mem[(m0+k)*MS + w];
                ssum += __shfl_down(ssum, 1); ssum += __shfl_down(ssum, 2);
                if (mg == 0) rv[r*NW + w] = ssum;
            }
            __syncthreads();

            // P13: K r=0 (tid<256) ∥ rwS writeback r∈{1,2,3} (tid 256..639)
            if (tid < 256) {
                const int w = tid >> 2, mg = tid & 3;
                const int m0 = mg*32;
                float ssum = 0.0f;
                #pragma unroll 8
                for (int k = 0; k < 32; ++k)
                    ssum += rwN[m0 + k]*mem[(m0+k)*MS + w];
                ssum += __shfl_down(ssum, 1); ssum += __shfl_down(ssum, 2);
                if (mg == 0) rv[w] = ssum;
            } else if (tid < 640) {
                rwS[128 + (tid - 256)] = rwN[128 + (tid - 256)];
            }
            __syncthreads();

            // P14: publish rv ∥ rwS r=0 wb ∥ precedence ∥ wwO copy
            if (tid < 64)
                cstore4(&pubRV[(size_t)par*NBATCH*NR*NW + b*NR*NW + tid*4],
                        *(const f4*)&rv[tid*4]);
            else if (tid < 192)
                rwS[tid - 64] = rwN[tid - 64];
            else if (tid < 320) {
                int m = tid - 192;
                prc[m] = (1.0f - sc[4])*prc[m] + wwN[m];
            } else if (tid < 448)
                wwO[tid - 320] = wwN[tid - 320];
            flag_set_d(&FLGD[D_R + b], (unsigned)(t+1), tid);
        }
    } else {
        // ===== GATES block: 4 units (16 gate rows) + LSTM + 4 xi + 4 out ====
        const int g = bid - 32;            // owns units u = 4g .. 4g+3
        const int gate = wv >> 2, j = wv & 3;
        const int r = gate*NH + 4*g + j;   // weight row: gate, unit 4g+j
        const f4* WA = (const f4*)(W_ih + (size_t)r*NI);
        f4 wx0 = WA[l], wx1 = WA[l+64], wrv = WA[128+l];
        const f4* WB = (const f4*)(W_hh + (size_t)r*NH);
        f4 wh0 = WB[l], wh1 = WB[l+64];
        const float bias = b_ih[r] + b_hh[r];
        float* accS = S + G_ACC;   // [32][17] (stride 17: conflict-free)
        float* cSg  = S + G_C;     // [32][5]  (stride 5: conflict-free)
        float* hStg = S + G_H;     // [32][512] h(t-1) staging
        const int sbi = tid >> 7, sk4 = (tid & 127) << 2;

        if (tid < 160) cSg[tid] = 0.0f;
        for (int e = tid; e < NBATCH*NH; e += TPB) hStg[e] = 0.0f;  // h(-1)=0
        __syncthreads();

        for (int t = 0; t <= NT; ++t) {          // NT+1 iters (epilogue at NT)
            const int par = t & 1, parp = (t+1) & 1;   // parp = parity of t-1

            // A: stage ALL h(t-1); then xi(t-1) from our 8KB W_xi slice
            if (t >= 1) {
                multi_wait_d(&FLGD[D_G], 128, (unsigned)t, tid);   // h(t-1) all
                const float* hIn = pubH + (size_t)parp*NBATCH*NH;
                f4 a0, a1, a2, a3;
                cload4x4(hIn + tid*4, hIn + (tid+1024)*4,
                         hIn + (tid+2048)*4, hIn + (tid+3072)*4,
                         a0, a1, a2, a3);
                *(f4*)&hStg[tid*4]          = a0;
                *(f4*)&hStg[(tid+1024)*4]   = a1;
                *(f4*)&hStg[(tid+2048)*4]   = a2;
                *(f4*)&hStg[(tid+3072)*4]   = a3;
                __syncthreads();
                if (g < NXB) {
                    float* xOut = pubXI + (size_t)parp*NBATCH*480;
                    #pragma unroll
                    for (int bb = 0; bb < 2; ++bb) {
                        const int bi = 2*wv + bb;
                        const f4* H4 = (const f4*)(hStg + bi*512);
                        f4 res = {0.0f, 0.0f, 0.0f, 0.0f};
                        #pragma unroll
                        for (int jj = 0; jj < 4; ++jj) {
                            const int row = 4*g + jj;
                            if (row < NXI) {
                                const f4* WX = (const f4*)(W_xi + (size_t)row*NH);
                                float a = dot4(WX[l], H4[l])
                                        + dot4(WX[l+64], H4[l+64]);
                                a = wave_red(a);
                                res[jj] = a + b_xi[row];
                            }
                        }
                        if (l == 0) cstore4(&xOut[(size_t)bi*480 + 4*g], res);
                    }
                    flag_set_d(&FLGD[D_X + g], (unsigned)t, tid);
                }
            }

            // B: heavy phase x(t)·W_ih + h(t-1)·W_hh (off critical path)
            if (t < NT) {
                for (int p = 0; p < 4; ++p) {
                    const int b0 = p*8;
                    *(f4*)&S[sbi*512 + sk4] =
                        *(const f4*)&x[((size_t)(b0+sbi)*NT + t)*NH + sk4];
                    __syncthreads();
                    #pragma unroll
                    for (int bi = 0; bi < 8; ++bi) {
                        const f4* X4 = (const f4*)(S + bi*512);
                        const f4* H4 = (const f4*)(hStg + (b0+bi)*512);
                        float a = dot4(wx0, X4[l]) + dot4(wx1, X4[l+64])
                                + dot4(wh0, H4[l]) + dot4(wh1, H4[l+64]);
                        a = wave_red(a);
                        if (l == 0) accS[(b0+bi)*17 + wv] = a + bias;
                    }
                    __syncthreads();
                }
            }

            // C: rv(t-1) — the critical-path input
            {
                const int bi0 = tid >> 6, k40 = (tid & 63) << 2;
                if (t >= 1) {
                    multi_wait_d(&FLGD[D_R], 32, (unsigned)t, tid);
                    const float* rIn = pubRV + (size_t)parp*NBATCH*NR*NW;
                    f4 a0, a1;
                    cload4x2(&rIn[bi0*256 + k40], &rIn[(bi0+16)*256 + k40], a0, a1);
                    *(f4*)&S[bi0*256 + k40] = a0;
                    *(f4*)&S[(bi0+16)*256 + k40] = a1;
                } else {
                    f4 z = {0.0f, 0.0f, 0.0f, 0.0f};
                    *(f4*)&S[bi0*256 + k40] = z;
                    *(f4*)&S[(bi0+16)*256 + k40] = z;
                }
            }
            __syncthreads();

            // D: rv dot + LSTM + publish h(t)
            if (t < NT) {
                #pragma unroll
                for (int bi = 0; bi < 32; ++bi) {
                    const f4* RV4 = (const f4*)(S + bi*256);
                    float d = dot4(wrv, RV4[l]);
                    d = wave_red(d);
                    if (l == 0) accS[bi*17 + wv] += d;
                }
                __syncthreads();
                if (tid < 32) {
                    const int bi = tid;
                    const float* acc = accS + bi*17;
                    f4 hq;
                    #pragma unroll
                    for (int jj = 0; jj < 4; ++jj) {
                        float i_ = sigm(acc[0*4 + jj]);
                        float f_ = sigm(acc[1*4 + jj]);
                        float g_ = tanhf(acc[2*4 + jj]);
                        float o_ = sigm(acc[3*4 + jj]);
                        float c  = f_*cSg[bi*5 + jj] + i_*g_;
                        cSg[bi*5 + jj] = c;
                        hq[jj] = o_*tanhf(c);
                    }
                    cstore4(&pubH[(size_t)par*NBATCH*NH + (size_t)bi*NH + 4*g], hq);
                }
                flag_set_d(&FLGD[D_G + g], (unsigned)(t+1), tid);
            }

            // E: out(t-1) from hStg (h(t-1)) + staged rv(t-1) — idle shadow
            if (t >= 1) {
                #pragma unroll
                for (int bb = 0; bb < 2; ++bb) {
                    const int bi = 2*wv + bb;
                    const f4* H4 = (const f4*)(hStg + bi*512);
                    const f4* RV4 = (const f4*)(S + bi*256);
                    f4 res;
                    #pragma unroll
                    for (int jj = 0; jj < 4; ++jj) {
                        const int row = 4*g + jj;
                        const f4* WO = (const f4*)(W_o + (size_t)row*NI);
                        float a = dot4(WO[l], H4[l]) + dot4(WO[l+64], H4[l+64])
                                + dot4(WO[128+l], RV4[l]);
                        a = wave_red(a);
                        res[jj] = a + b_o[row];
                    }
                    if (l == 0)
                        *(f4*)&out[((size_t)bi*NT + (t-1))*NH + 4*g] = res;
                }
            }
            // next iter's D_G multi_wait barrier orders these reads vs restaging
        }
    }
}

extern "C" void kernel_launch(void* const* d_in, const int* in_sizes, int n_in,
                              void* d_out, int out_size, void* d_ws, size_t ws_size,
                              hipStream_t stream) {
    (void)in_sizes; (void)n_in; (void)out_size; (void)ws_size;
    const float* x    = (const float*)d_in[0];
    const float* W_ih = (const float*)d_in[1];
    const float* W_hh = (const float*)d_in[2];
    const float* b_ih = (const float*)d_in[3];
    const float* b_hh = (const float*)d_in[4];
    const float* W_xi = (const float*)d_in[5];
    const float* b_xi = (const float*)d_in[6];
    const float* W_o  = (const float*)d_in[7];
    const float* b_o  = (const float*)d_in[8];
    float* out = (float*)d_out;
    float* ws  = (float*)d_ws;

    dnc_zero<<<1, 512, 0, stream>>>(ws);

    void* args[] = { (void*)&x, (void*)&W_ih, (void*)&W_hh, (void*)&b_ih,
                     (void*)&b_hh, (void*)&W_xi, (void*)&b_xi, (void*)&W_o,
                     (void*)&b_o, (void*)&out, (void*)&ws };
    hipLaunchCooperativeKernel((void*)dnc_pipe2, dim3(NBLK), dim3(TPB),
                               args, 0, stream);
}

// Round 8
// 2870.359 us; speedup vs baseline: 2.0413x; 1.0533x over previous
//
#include <hip/hip_runtime.h>
#include <math.h>

#define TPB 1024
#define NBLK 160
#define NBATCH 32
#define NT 64
#define NH 512
#define NM 128
#define NR 4
#define NW 64
#define NI 768          // controller input size (H + R*W)
#define NXI 471         // interface vector size
#define EPSF 1e-6f
#define MS 68           // mem row stride (f4-aligned, bank-audited)
#define MS4 17          // MS/4
#define LKS 129         // link row stride (odd: row+col b32 scans conflict-free)

// roles: [0,32) state (DNC machinery only) |
//        [32,160) gates blocks: 4 hidden units (16 gate rows) + LSTM cell
//                 + 4 xi rows + 4 out rows (distributed W_xi / W_o streams)

typedef float f4 __attribute__((ext_vector_type(4)));

// ws layout (float offsets). pub* parity double-buffered.
#define WS_PUBH  0                                 // [2][32][512] (gates)
#define WS_PUBRV (WS_PUBH + 2*NBATCH*NH)           // [2][32][256] (state)
#define WS_PUBXI (WS_PUBRV + 2*NBATCH*NR*NW)       // [2][32][480] (gates)
#define WS_FLAGS (WS_PUBXI + 2*NBATCH*480)
// packed flag dwords
#define D_G 0        // 128 gate blocks: h(t) published -> t+1
#define D_R 128      // 32 state blocks: rv(t) published -> t+1
#define D_X 160      // 118 gate blocks: xi(t-1) published -> t
#define D_TOTAL 288
#define NXB 118      // gate blocks that own xi rows (4*118 >= 471)

__device__ __forceinline__ float sigm(float x){ return 1.0f/(1.0f+expf(-x)); }
__device__ __forceinline__ float sftp(float x){ return fmaxf(x,0.0f)+log1pf(expf(-fabsf(x))); }
__device__ __forceinline__ float dot4(f4 a, f4 b){
    return a.x*b.x + a.y*b.y + a.z*b.z + a.w*b.w;
}
__device__ __forceinline__ float wave_red(float v){
    #pragma unroll
    for (int o = 32; o > 0; o >>= 1) v += __shfl_down(v, o);
    return v;
}

// ---- coherent (LLC write-through, device-visible) accessors: sc0 sc1 ----
__device__ __forceinline__ f4 cload4(const float* p){
    f4 v;
    asm volatile("global_load_dwordx4 %0, %1, off sc0 sc1\n\t"
                 "s_waitcnt vmcnt(0)"
                 : "=&v"(v) : "v"(p) : "memory");
    return v;
}
__device__ __forceinline__ void cload4x2(const float* p0, const float* p1,
                                         f4& a, f4& b){
    asm volatile("global_load_dwordx4 %0, %2, off sc0 sc1\n\t"
                 "global_load_dwordx4 %1, %3, off sc0 sc1\n\t"
                 "s_waitcnt vmcnt(0)"
                 : "=&v"(a), "=&v"(b) : "v"(p0), "v"(p1) : "memory");
}
__device__ __forceinline__ void cload4x4(const float* p0, const float* p1,
                                         const float* p2, const float* p3,
                                         f4& a, f4& b, f4& c, f4& d){
    asm volatile("global_load_dwordx4 %0, %4, off sc0 sc1\n\t"
                 "global_load_dwordx4 %1, %5, off sc0 sc1\n\t"
                 "global_load_dwordx4 %2, %6, off sc0 sc1\n\t"
                 "global_load_dwordx4 %3, %7, off sc0 sc1\n\t"
                 "s_waitcnt vmcnt(0)"
                 : "=&v"(a), "=&v"(b), "=&v"(c), "=&v"(d)
                 : "v"(p0), "v"(p1), "v"(p2), "v"(p3) : "memory");
}
__device__ __forceinline__ void cstore4(float* p, f4 v){
    asm volatile("global_store_dwordx4 %0, %1, off sc0 sc1"
                 :: "v"(p), "v"(v) : "memory");
}

// ---- packed-flag protocol ----
__device__ __forceinline__ void multi_wait_d(const unsigned int* f, int n,
                                             unsigned int tgt, int tid){
    if (tid < n) {
        const unsigned int* p = f + tid;
        while (__hip_atomic_load(p, __ATOMIC_RELAXED,
                                 __HIP_MEMORY_SCOPE_AGENT) < tgt)
            __builtin_amdgcn_s_sleep(2);
    }
    __syncthreads();
}
__device__ __forceinline__ void flag_set_d(unsigned int* f, unsigned int v, int tid){
    asm volatile("s_waitcnt vmcnt(0)" ::: "memory");
    __syncthreads();
    if (tid == 0)
        __hip_atomic_store(f, v, __ATOMIC_RELAXED, __HIP_MEMORY_SCOPE_AGENT);
}

__global__ void dnc_zero(float* ws){
    unsigned int* z = (unsigned int*)(ws + WS_FLAGS);
    for (int e = threadIdx.x; e < D_TOTAL; e += blockDim.x) z[e] = 0u;
}

// ---- pooled LDS (floats) ----
#define O_MEM 0         // 8704 (128 x 68)
#define O_RW  8704      // 512
#define O_WWO 9216      // 128
#define O_WWN 9344      // 128
#define O_USG 9472      // 128
#define O_PRC 9600      // 128
#define O_XI  9728      // 480
#define O_KEY 10208     // 256
#define O_WK  10464     // 64
#define O_ER  10528     // 64
#define O_WV  10592     // 64
#define O_RS  10656     // 4
#define O_FG  10660     // 4
#define O_MD  10664     // 12
#define O_NK  10676     // 4
#define O_SC  10680     // 8
#define O_NRM 10688     // 2 x 128 double-buffered row norms
#define O_WCW 10944     // 128
#define O_UU  11072     // 128
#define O_SU  11200     // 128
#define O_CUM 11328     // 128
#define O_RNK 11456     // 128 (int)
#define O_CCW 11584     // 512
#define O_JP  12096     // 512 (mode-mixed fwd/bwd)
#define O_RV  12608     // 256
#define O_RED 12864     // 16
#define O_PF  12880     // 4096: J fwd partials [8][4][128]
#define O_PB  16976     // 4096: J bwd partials [8][4][128]
#define O_PK  12880     // 2048: K partials [8][4][64] (aliases PF, disjoint phases)
#define O_LK  21072     // 128*129 link matrix
#define S_SZ  (21072 + NM*LKS)     // 37584 floats = 150,336 B; 1 block/CU
// gates role (disjoint): x/rv staging S[0..8191]
#define G_ACC 8192      // [32][17]
#define G_C   8736      // [32][5]
#define G_H   8896      // [32][512] h(t-1) staging

__global__ __launch_bounds__(TPB) void dnc_pipe2(
    const float* __restrict__ x, const float* __restrict__ W_ih,
    const float* __restrict__ W_hh, const float* __restrict__ b_ih,
    const float* __restrict__ b_hh, const float* __restrict__ W_xi,
    const float* __restrict__ b_xi, const float* __restrict__ W_o,
    const float* __restrict__ b_o, float* __restrict__ out,
    float* __restrict__ ws)
{
    __shared__ __align__(16) float S[S_SZ];

    const int tid = threadIdx.x;
    const int wv  = tid >> 6;
    const int l   = tid & 63;
    const int bid = blockIdx.x;

    float* __restrict__ pubH  = ws + WS_PUBH;
    float* __restrict__ pubRV = ws + WS_PUBRV;
    float* __restrict__ pubXI = ws + WS_PUBXI;
    unsigned int* __restrict__ FLGD = (unsigned int*)(ws + WS_FLAGS);

    if (bid < NBATCH) {
        // ========================= STATE block =========================
        const int b = bid;
        float* lk = S+O_LK;
        float* mem = S+O_MEM;
        float* rwS = S+O_RW;
        float* wwO = S+O_WWO;  float* wwN = S+O_WWN;
        float* usg = S+O_USG;  float* prc = S+O_PRC; float* xiS = S+O_XI;
        float* keys = S+O_KEY; float* wkey = S+O_WK; float* ers = S+O_ER;
        float* wvec = S+O_WV;  float* rstr = S+O_RS; float* fgte = S+O_FG;
        float* modes = S+O_MD; float* nkey = S+O_NK; float* sc = S+O_SC;
        float* nrm = S+O_NRM;  float* wcw = S+O_WCW;
        float* uu = S+O_UU;    float* su = S+O_SU;   float* cum = S+O_CUM;
        int*   rnk = (int*)(S+O_RNK);
        float* ccw = S+O_CCW;  float* jp = S+O_JP;   float* rv = S+O_RV;
        float* red = S+O_RED;

        for (int e = tid; e < NM*LKS; e += TPB) lk[e] = 0.0f;
        for (int e = tid; e < NM*NW; e += TPB) mem[(e>>6)*MS + (e&63)] = EPSF;
        for (int e = tid; e < NR*NM; e += TPB) rwS[e]=0.0f;
        for (int e = tid; e < NM; e += TPB){ wwO[e]=0.0f; usg[e]=0.0f; prc[e]=0.0f; }
        for (int e = tid; e < 2*NM; e += TPB) nrm[e] = 8.0f*EPSF; // ||EPS row||
        __syncthreads();

        for (int t = 0; t < NT; ++t) {
            const int par = t & 1;
            float* nmo = nrm + 128*(t & 1);        // old norms = prev step's new
            float* nmn = nrm + 128*((t+1) & 1);

            // P1: xi(t) ready; load
            multi_wait_d(&FLGD[D_X], NXB, (unsigned)(t+1), tid);
            if (tid < 120)
                *(f4*)&xiS[tid*4] =
                    cload4(&pubXI[(size_t)par*NBATCH*480 + b*480 + tid*4]);
            __syncthreads();

            // P2: E1 unpack interface
            if (tid < 256)       keys[tid] = tanhf(xiS[tid]);
            else if (tid < 260)  rstr[tid-256] = sftp(xiS[tid]);
            else if (tid < 324)  wkey[tid-260] = tanhf(xiS[tid]);
            else if (tid == 324) sc[0] = sftp(xiS[324]);
            else if (tid < 389)  ers[tid-325] = sigm(xiS[tid]);
            else if (tid < 453)  wvec[tid-389] = tanhf(xiS[tid]);
            else if (tid < 457)  fgte[tid-453] = sigm(xiS[tid]);
            else if (tid == 457) sc[1] = sigm(xiS[457]);
            else if (tid == 458) sc[2] = sigm(xiS[458]);
            else if (tid < 463) {
                int r = tid - 459;
                float a0=xiS[459+3*r], a1=xiS[460+3*r], a2=xiS[461+3*r];
                float mx = fmaxf(a0, fmaxf(a1, a2));
                float e0=expf(a0-mx), e1=expf(a1-mx), e2=expf(a2-mx);
                float si = 1.0f/(e0+e1+e2);
                modes[3*r]=e0*si; modes[3*r+1]=e1*si; modes[3*r+2]=e2*si;
            }
            __syncthreads();

            // P3: key norms (waves 0-4) ∥ usage+uu (waves 6-7)
            if (wv < 4) {
                float v = keys[wv*NW + l];
                float s2 = wave_red(v*v);
                if (l == 0) nkey[wv] = sqrtf(s2);
            } else if (wv == 4) {
                float v = wkey[l];
                float s2 = wave_red(v*v);
                if (l == 0) sc[3] = sqrtf(s2);
            } else if (wv == 6 || wv == 7) {
                int m = tid - 384;
                float u = usg[m];
                u = u + (1.0f - u)*wwO[m];
                float psi = 1.0f;
                #pragma unroll
                for (int r = 0; r < NR; ++r) psi *= (1.0f - fgte[r]*rwS[r*NM+m]);
                u *= psi;
                usg[m] = u;
                uu[m] = 5e-6f + (1.0f - 5e-6f)*u;
            }
            __syncthreads();

            // P4: F1 write-content logits — f4 reads, 8 thr/row
            {
                const int m = tid >> 3, s = tid & 7;
                const f4* mem4 = (const f4*)(S + O_MEM);
                const f4* wk4  = (const f4*)(S + O_WK);
                f4 m0 = mem4[m*MS4 + s*2], m1 = mem4[m*MS4 + s*2 + 1];
                f4 k0 = wk4[s*2], k1 = wk4[s*2 + 1];
                float d = dot4(m0, k0) + dot4(m1, k1);
                d += __shfl_down(d, 4); d += __shfl_down(d, 2); d += __shfl_down(d, 1);
                if (s == 0) wcw[m] = d/(sc[3]*nmo[m] + EPSF) * sc[0];
            }
            __syncthreads();

            // P5: wcw softmax (wave 0) ∥ G2 rank (waves 8-15)
            if (tid < 64) {
                float w0 = wcw[l], w1 = wcw[l+64];
                float mx = fmaxf(w0, w1);
                #pragma unroll
                for (int o = 32; o > 0; o >>= 1) mx = fmaxf(mx, __shfl_down(mx, o));
                float M = __shfl(mx, 0);
                float e0 = expf(w0 - M), e1 = expf(w1 - M);
                float s = wave_red(e0 + e1);
                float inv = 1.0f/__shfl(s, 0);
                wcw[l] = e0*inv; wcw[l+64] = e1*inv;
            } else if (tid >= 512) {
                const int q = tid - 512, m = q >> 2, s = q & 3;
                const float um = uu[m];
                int rk = 0;
                #pragma unroll 8
                for (int k = 0; k < 32; ++k) {
                    int j = 4*k + s;
                    float uj = uu[j];
                    rk += (uj < um) || (uj == um && j < m);
                }
                rk += __shfl_down(rk, 1); rk += __shfl_down(rk, 2);
                if (s == 0) { rnk[m] = rk; su[rk] = um; }
            }
            __syncthreads();

            // P6: product scan (wave 0)
            if (tid < 64) {
                float a = su[tid], bb = su[64+tid];
                #pragma unroll
                for (int o = 1; o < 64; o <<= 1) {
                    float ta = __shfl_up(a, o);
                    float tb = __shfl_up(bb, o);
                    if (tid >= o) { a *= ta; bb *= tb; }
                }
                float P0 = __shfl(a, 63);
                cum[tid] = a;
                cum[64+tid] = P0*bb;
            }
            __syncthreads();

            // P7: alloc + wwN + per-wave alloc-sum partials
            if (tid < NM) {
                int rk = rnk[tid];
                float excl = (rk == 0) ? 1.0f : cum[rk-1];
                float al = (1.0f - uu[tid])*excl;
                wwN[tid] = sc[2]*(sc[1]*al + (1.0f - sc[1])*wcw[tid]);
                float sal = wave_red(al);
                if (l == 0) red[2 + wv] = sal;
            }
            __syncthreads();

            // P8: H fused: sc[4] analytic + mem erase/write + nmn + link update
            if (tid == 1023)
                sc[4] = sc[2]*(sc[1]*(red[2]+red[3]) + (1.0f - sc[1]));
            #pragma unroll
            for (int ri = 0; ri < 8; ++ri) {
                int row = wv*8 + ri;
                float wm = wwN[row];
                float v = mem[row*MS + l];
                float nv = v*(1.0f - wm*ers[l]) + wm*wvec[l];
                mem[row*MS + l] = nv;
                float s2 = wave_red(nv*nv);
                if (l == 0) nmn[row] = sqrtf(s2);
            }
            #pragma unroll
            for (int k = 0; k < 16; ++k) {
                int e = tid + k*TPB;
                int i = e >> 7, j = e & 127;
                int a = i*LKS + j;
                float nl = (i == j) ? 0.0f
                         : (1.0f - wwN[i] - wwN[j])*lk[a] + wwN[i]*prc[j];
                lk[a] = nl;
            }
            __syncthreads();

            // P9: I logits (waves 0-7, f4 mem + shfl-keys, r-in-register)
            //     ∥ J1+J2 fused (waves 8-15, lk read once per orientation)
            if (tid < 512) {
                const int m = tid >> 2, s = tid & 3;
                const f4* mem4 = (const f4*)(S + O_MEM);
                const f4* key4 = (const f4*)(S + O_KEY);
                f4 kv = key4[l];                // lane-local keys[4l..4l+3]
                float a0=0.f, a1=0.f, a2=0.f, a3=0.f;
                #pragma unroll
                for (int c = 0; c < 4; ++c) {
                    f4 mv = mem4[m*MS4 + s*4 + c];
                    const int sl = s*4 + c;
                    a0 += mv.x*__shfl(kv.x, sl)    + mv.y*__shfl(kv.y, sl)
                        + mv.z*__shfl(kv.z, sl)    + mv.w*__shfl(kv.w, sl);
                    a1 += mv.x*__shfl(kv.x, 16+sl) + mv.y*__shfl(kv.y, 16+sl)
                        + mv.z*__shfl(kv.z, 16+sl) + mv.w*__shfl(kv.w, 16+sl);
                    a2 += mv.x*__shfl(kv.x, 32+sl) + mv.y*__shfl(kv.y, 32+sl)
                        + mv.z*__shfl(kv.z, 32+sl) + mv.w*__shfl(kv.w, 32+sl);
                    a3 += mv.x*__shfl(kv.x, 48+sl) + mv.y*__shfl(kv.y, 48+sl)
                        + mv.z*__shfl(kv.z, 48+sl) + mv.w*__shfl(kv.w, 48+sl);
                }
                a0 += __shfl_down(a0,1); a0 += __shfl_down(a0,2);
                a1 += __shfl_down(a1,1); a1 += __shfl_down(a1,2);
                a2 += __shfl_down(a2,1); a2 += __shfl_down(a2,2);
                a3 += __shfl_down(a3,1); a3 += __shfl_down(a3,2);
                if (s == 0) {
                    float nm = nmn[m];
                    ccw[0*NM+m] = a0/(nkey[0]*nm + EPSF)*rstr[0];
                    ccw[1*NM+m] = a1/(nkey[1]*nm + EPSF)*rstr[1];
                    ccw[2*NM+m] = a2/(nkey[2]*nm + EPSF)*rstr[2];
                    ccw[3*NM+m] = a3/(nkey[3]*nm + EPSF)*rstr[3];
                }
            } else {
                const int wj = wv - 8;          // 0..7, i-chunk of 16
                const int i0 = wj*16;
                float srw = rwS[(l>>4)*NM + i0 + (l&15)];
                float fA0=0,fA1=0,fA2=0,fA3=0, fB0=0,fB1=0,fB2=0,fB3=0;
                float bA0=0,bA1=0,bA2=0,bA3=0, bB0=0,bB1=0,bB2=0,bB3=0;
                #pragma unroll 4
                for (int ii = 0; ii < 16; ++ii) {
                    const int i = i0 + ii;
                    float r0 = __shfl(srw, ii);
                    float r1 = __shfl(srw, 16+ii);
                    float r2 = __shfl(srw, 32+ii);
                    float r3 = __shfl(srw, 48+ii);
                    float lrA = lk[l*LKS + i];          // row m=l
                    float lrB = lk[(l+64)*LKS + i];     // row m=l+64
                    float lcA = lk[i*LKS + l];          // col j=l
                    float lcB = lk[i*LKS + 64 + l];     // col j=l+64
                    fA0 += lrA*r0; fA1 += lrA*r1; fA2 += lrA*r2; fA3 += lrA*r3;
                    fB0 += lrB*r0; fB1 += lrB*r1; fB2 += lrB*r2; fB3 += lrB*r3;
                    bA0 += lcA*r0; bA1 += lcA*r1; bA2 += lcA*r2; bA3 += lcA*r3;
                    bB0 += lcB*r0; bB1 += lcB*r1; bB2 += lcB*r2; bB3 += lcB*r3;
                }
                float* Pf = S + O_PF + wj*512;
                float* Pb = S + O_PB + wj*512;
                Pf[0*NM+l]=fA0; Pf[1*NM+l]=fA1; Pf[2*NM+l]=fA2; Pf[3*NM+l]=fA3;
                Pf[0*NM+64+l]=fB0; Pf[1*NM+64+l]=fB1;
                Pf[2*NM+64+l]=fB2; Pf[3*NM+64+l]=fB3;
                Pb[0*NM+l]=bA0; Pb[1*NM+l]=bA1; Pb[2*NM+l]=bA2; Pb[3*NM+l]=bA3;
                Pb[0*NM+64+l]=bB0; Pb[1*NM+64+l]=bB1;
                Pb[2*NM+64+l]=bB2; Pb[3*NM+64+l]=bB3;
            }
            __syncthreads();

            // P10: ccw softmax (waves 0-3) ∥ J-combine -> jp (waves 4-11)
            //      ∥ precedence (waves 12-13 lo) ∥ wwO copy (waves 14-15 lo)
            if (tid < 256) {
                float v0 = ccw[wv*NM + l], v1 = ccw[wv*NM + 64 + l];
                float mx = fmaxf(v0, v1);
                #pragma unroll
                for (int o = 32; o > 0; o >>= 1) mx = fmaxf(mx, __shfl_down(mx, o));
                float M = __shfl(mx, 0);
                float e0 = expf(v0 - M), e1 = expf(v1 - M);
                float s = wave_red(e0 + e1);
                float inv = 1.0f/__shfl(s, 0);
                ccw[wv*NM + l] = e0*inv; ccw[wv*NM + 64 + l] = e1*inv;
            } else if (tid < 768) {
                const int q = tid - 256, r = q >> 7, m = q & 127;
                float fs = 0.0f, bs = 0.0f;
                #pragma unroll
                for (int c = 0; c < 8; ++c) {
                    fs += S[O_PF + c*512 + r*NM + m];
                    bs += S[O_PB + c*512 + r*NM + m];
                }
                jp[r*NM + m] = modes[3*r]*bs + modes[3*r+1]*fs;
            } else if (tid < 896) {
                int m = tid - 768;
                prc[m] = (1.0f - sc[4])*prc[m] + wwN[m];
            } else {
                int m = tid - 896;
                wwO[m] = wwN[m];
            }
            __syncthreads();

            // P11: K main (waves 0-7): lane=w, rwn on the fly via shfl
            if (wv < 8) {
                const int m0 = wv*16;
                float jpv = jp[(l>>4)*NM + m0 + (l&15)];
                float ccv = ccw[(l>>4)*NM + m0 + (l&15)];
                float m30 = modes[2], m31 = modes[5], m32 = modes[8], m33 = modes[11];
                float a0=0.f, a1=0.f, a2=0.f, a3=0.f;
                #pragma unroll 4
                for (int mm = 0; mm < 16; ++mm) {
                    const int m = m0 + mm;
                    float rn0 = __shfl(jpv, mm)    + m30*__shfl(ccv, mm);
                    float rn1 = __shfl(jpv, 16+mm) + m31*__shfl(ccv, 16+mm);
                    float rn2 = __shfl(jpv, 32+mm) + m32*__shfl(ccv, 32+mm);
                    float rn3 = __shfl(jpv, 48+mm) + m33*__shfl(ccv, 48+mm);
                    float mv = mem[m*MS + l];
                    a0 += rn0*mv; a1 += rn1*mv; a2 += rn2*mv; a3 += rn3*mv;
                }
                float* Pk = S + O_PK + wv*256;
                Pk[0*64+l]=a0; Pk[1*64+l]=a1; Pk[2*64+l]=a2; Pk[3*64+l]=a3;
            }
            __syncthreads();

            // P12: K reduce -> rv (tid<256) ∥ rwS <- jp + m2*ccw (tid 256..767)
            if (tid < 256) {
                const int r = tid >> 6, w = tid & 63;
                float s = 0.0f;
                #pragma unroll
                for (int c = 0; c < 8; ++c) s += S[O_PK + c*256 + r*64 + w];
                rv[r*NW + w] = s;
            } else if (tid < 768) {
                const int q = tid - 256, r = q >> 7;
                rwS[q] = jp[q] + modes[3*r+2]*ccw[q];
            }
            __syncthreads();

            // P13: publish rv
            if (tid < 64)
                cstore4(&pubRV[(size_t)par*NBATCH*NR*NW + b*NR*NW + tid*4],
                        *(const f4*)&rv[tid*4]);
            flag_set_d(&FLGD[D_R + b], (unsigned)(t+1), tid);
        }
    } else {
        // ===== GATES block: 4 units (16 gate rows) + LSTM + 4 xi + 4 out ====
        const int g = bid - 32;            // owns units u = 4g .. 4g+3
        const int gate = wv >> 2, j = wv & 3;
        const int r = gate*NH + 4*g + j;   // weight row: gate, unit 4g+j
        const f4* WA = (const f4*)(W_ih + (size_t)r*NI);
        f4 wx0 = WA[l], wx1 = WA[l+64], wrv = WA[128+l];
        const f4* WB = (const f4*)(W_hh + (size_t)r*NH);
        f4 wh0 = WB[l], wh1 = WB[l+64];
        const float bias = b_ih[r] + b_hh[r];
        float* accS = S + G_ACC;   // [32][17]
        float* cSg  = S + G_C;     // [32][5]
        float* hStg = S + G_H;     // [32][512] h(t-1) staging
        const int sbi = tid >> 7, sk4 = (tid & 127) << 2;

        if (tid < 160) cSg[tid] = 0.0f;
        for (int e = tid; e < NBATCH*NH; e += TPB) hStg[e] = 0.0f;  // h(-1)=0
        __syncthreads();

        for (int t = 0; t <= NT; ++t) {          // NT+1 iters (epilogue at NT)
            const int par = t & 1, parp = (t+1) & 1;   // parp = parity of t-1

            // A: stage ALL h(t-1); then xi(t-1) from our 8KB W_xi slice
            if (t >= 1) {
                multi_wait_d(&FLGD[D_G], 128, (unsigned)t, tid);   // h(t-1) all
                const float* hIn = pubH + (size_t)parp*NBATCH*NH;
                f4 a0, a1, a2, a3;
                cload4x4(hIn + tid*4, hIn + (tid+1024)*4,
                         hIn + (tid+2048)*4, hIn + (tid+3072)*4,
                         a0, a1, a2, a3);
                *(f4*)&hStg[tid*4]          = a0;
                *(f4*)&hStg[(tid+1024)*4]   = a1;
                *(f4*)&hStg[(tid+2048)*4]   = a2;
                *(f4*)&hStg[(tid+3072)*4]   = a3;
                __syncthreads();
                if (g < NXB) {
                    float* xOut = pubXI + (size_t)parp*NBATCH*480;
                    #pragma unroll
                    for (int bb = 0; bb < 2; ++bb) {
                        const int bi = 2*wv + bb;
                        const f4* H4 = (const f4*)(hStg + bi*512);
                        f4 res = {0.0f, 0.0f, 0.0f, 0.0f};
                        #pragma unroll
                        for (int jj = 0; jj < 4; ++jj) {
                            const int row = 4*g + jj;
                            if (row < NXI) {
                                const f4* WX = (const f4*)(W_xi + (size_t)row*NH);
                                float a = dot4(WX[l], H4[l])
                                        + dot4(WX[l+64], H4[l+64]);
                                a = wave_red(a);
                                res[jj] = a + b_xi[row];
                            }
                        }
                        if (l == 0) cstore4(&xOut[(size_t)bi*480 + 4*g], res);
                    }
                    flag_set_d(&FLGD[D_X + g], (unsigned)t, tid);
                }
            }

            // B: heavy phase x(t)·W_ih + h(t-1)·W_hh (off critical path)
            if (t < NT) {
                for (int p = 0; p < 4; ++p) {
                    const int b0 = p*8;
                    *(f4*)&S[sbi*512 + sk4] =
                        *(const f4*)&x[((size_t)(b0+sbi)*NT + t)*NH + sk4];
                    __syncthreads();
                    #pragma unroll
                    for (int bi = 0; bi < 8; ++bi) {
                        const f4* X4 = (const f4*)(S + bi*512);
                        const f4* H4 = (const f4*)(hStg + (b0+bi)*512);
                        float a = dot4(wx0, X4[l]) + dot4(wx1, X4[l+64])
                                + dot4(wh0, H4[l]) + dot4(wh1, H4[l+64]);
                        a = wave_red(a);
                        if (l == 0) accS[(b0+bi)*17 + wv] = a + bias;
                    }
                    __syncthreads();
                }
            }

            // C: rv(t-1) — the critical-path input
            {
                const int bi0 = tid >> 6, k40 = (tid & 63) << 2;
                if (t >= 1) {
                    multi_wait_d(&FLGD[D_R], 32, (unsigned)t, tid);
                    const float* rIn = pubRV + (size_t)parp*NBATCH*NR*NW;
                    f4 a0, a1;
                    cload4x2(&rIn[bi0*256 + k40], &rIn[(bi0+16)*256 + k40], a0, a1);
                    *(f4*)&S[bi0*256 + k40] = a0;
                    *(f4*)&S[(bi0+16)*256 + k40] = a1;
                } else {
                    f4 z = {0.0f, 0.0f, 0.0f, 0.0f};
                    *(f4*)&S[bi0*256 + k40] = z;
                    *(f4*)&S[(bi0+16)*256 + k40] = z;
                }
            }
            __syncthreads();

            // D: rv dot + LSTM + publish h(t)
            if (t < NT) {
                #pragma unroll
                for (int bi = 0; bi < 32; ++bi) {
                    const f4* RV4 = (const f4*)(S + bi*256);
                    float d = dot4(wrv, RV4[l]);
                    d = wave_red(d);
                    if (l == 0) accS[bi*17 + wv] += d;
                }
                __syncthreads();
                if (tid < 32) {
                    const int bi = tid;
                    const float* acc = accS + bi*17;
                    f4 hq;
                    #pragma unroll
                    for (int jj = 0; jj < 4; ++jj) {
                        float i_ = sigm(acc[0*4 + jj]);
                        float f_ = sigm(acc[1*4 + jj]);
                        float g_ = tanhf(acc[2*4 + jj]);
                        float o_ = sigm(acc[3*4 + jj]);
                        float c  = f_*cSg[bi*5 + jj] + i_*g_;
                        cSg[bi*5 + jj] = c;
                        hq[jj] = o_*tanhf(c);
                    }
                    cstore4(&pubH[(size_t)par*NBATCH*NH + (size_t)bi*NH + 4*g], hq);
                }
                flag_set_d(&FLGD[D_G + g], (unsigned)(t+1), tid);
            }

            // E: out(t-1) from hStg (h(t-1)) + staged rv(t-1) — idle shadow
            if (t >= 1) {
                #pragma unroll
                for (int bb = 0; bb < 2; ++bb) {
                    const int bi = 2*wv + bb;
                    const f4* H4 = (const f4*)(hStg + bi*512);
                    const f4* RV4 = (const f4*)(S + bi*256);
                    f4 res;
                    #pragma unroll
                    for (int jj = 0; jj < 4; ++jj) {
                        const int row = 4*g + jj;
                        const f4* WO = (const f4*)(W_o + (size_t)row*NI);
                        float a = dot4(WO[l], H4[l]) + dot4(WO[l+64], H4[l+64])
                                + dot4(WO[128+l], RV4[l]);
                        a = wave_red(a);
                        res[jj] = a + b_o[row];
                    }
                    if (l == 0)
                        *(f4*)&out[((size_t)bi*NT + (t-1))*NH + 4*g] = res;
                }
            }
        }
    }
}

extern "C" void kernel_launch(void* const* d_in, const int* in_sizes, int n_in,
                              void* d_out, int out_size, void* d_ws, size_t ws_size,
                              hipStream_t stream) {
    (void)in_sizes; (void)n_in; (void)out_size; (void)ws_size;
    const float* x    = (const float*)d_in[0];
    const float* W_ih = (const float*)d_in[1];
    const float* W_hh = (const float*)d_in[2];
    const float* b_ih = (const float*)d_in[3];
    const float* b_hh = (const float*)d_in[4];
    const float* W_xi = (const float*)d_in[5];
    const float* b_xi = (const float*)d_in[6];
    const float* W_o  = (const float*)d_in[7];
    const float* b_o  = (const float*)d_in[8];
    float* out = (float*)d_out;
    float* ws  = (float*)d_ws;

    dnc_zero<<<1, 512, 0, stream>>>(ws);

    void* args[] = { (void*)&x, (void*)&W_ih, (void*)&W_hh, (void*)&b_ih,
                     (void*)&b_hh, (void*)&W_xi, (void*)&b_xi, (void*)&W_o,
                     (void*)&b_o, (void*)&out, (void*)&ws };
    hipLaunchCooperativeKernel((void*)dnc_pipe2, dim3(NBLK), dim3(TPB),
                               args, 0, stream);
}

// Round 9
// 2624.751 us; speedup vs baseline: 2.2324x; 1.0936x over previous
//
#include <hip/hip_runtime.h>
#include <math.h>

#define TPB 1024
#define NBLK 160
#define NBATCH 32
#define NT 64
#define NH 512
#define NM 128
#define NR 4
#define NW 64
#define NI 768          // controller input size (H + R*W)
#define NXI 471         // interface vector size
#define EPSF 1e-6f
#define MS 68           // mem row stride (f4-aligned, bank-audited)
#define MS4 17          // MS/4
#define LKS 129         // link row stride (odd: row+col b32 scans conflict-free)

// roles: [0,32) state (DNC machinery only) |
//        [32,160) gates blocks: 4 hidden units (16 gate rows) + LSTM cell
//                 + 4 xi rows + 4 out rows (distributed W_xi / W_o streams)

typedef float f4 __attribute__((ext_vector_type(4)));

// ws layout (float offsets). pub* parity double-buffered.
#define WS_PUBH  0                                 // [2][32][512] (gates)
#define WS_PUBRV (WS_PUBH + 2*NBATCH*NH)           // [2][32][256] (state)
#define WS_PUBXI (WS_PUBRV + 2*NBATCH*NR*NW)       // [2][32][480] (gates)
#define WS_FLAGS (WS_PUBXI + 2*NBATCH*480)
// packed flag dwords
#define D_G 0        // 128 gate blocks: h(t) published -> t+1
#define D_R 128      // 32 state blocks: rv(t) published -> t+1
#define D_X 160      // 118 gate blocks: xi(t-1) published -> t
#define D_TOTAL 288
#define NXB 118      // gate blocks that own xi rows (4*118 >= 471)

__device__ __forceinline__ float sigm(float x){ return 1.0f/(1.0f+expf(-x)); }
__device__ __forceinline__ float sftp(float x){ return fmaxf(x,0.0f)+log1pf(expf(-fabsf(x))); }
__device__ __forceinline__ float dot4(f4 a, f4 b){
    return a.x*b.x + a.y*b.y + a.z*b.z + a.w*b.w;
}
__device__ __forceinline__ float wave_red(float v){
    #pragma unroll
    for (int o = 32; o > 0; o >>= 1) v += __shfl_down(v, o);
    return v;
}

// ---- coherent (LLC write-through, device-visible) accessors: sc0 sc1 ----
__device__ __forceinline__ f4 cload4(const float* p){
    f4 v;
    asm volatile("global_load_dwordx4 %0, %1, off sc0 sc1\n\t"
                 "s_waitcnt vmcnt(0)"
                 : "=&v"(v) : "v"(p) : "memory");
    return v;
}
__device__ __forceinline__ void cload4x2(const float* p0, const float* p1,
                                         f4& a, f4& b){
    asm volatile("global_load_dwordx4 %0, %2, off sc0 sc1\n\t"
                 "global_load_dwordx4 %1, %3, off sc0 sc1\n\t"
                 "s_waitcnt vmcnt(0)"
                 : "=&v"(a), "=&v"(b) : "v"(p0), "v"(p1) : "memory");
}
__device__ __forceinline__ void cload4x4(const float* p0, const float* p1,
                                         const float* p2, const float* p3,
                                         f4& a, f4& b, f4& c, f4& d){
    asm volatile("global_load_dwordx4 %0, %4, off sc0 sc1\n\t"
                 "global_load_dwordx4 %1, %5, off sc0 sc1\n\t"
                 "global_load_dwordx4 %2, %6, off sc0 sc1\n\t"
                 "global_load_dwordx4 %3, %7, off sc0 sc1\n\t"
                 "s_waitcnt vmcnt(0)"
                 : "=&v"(a), "=&v"(b), "=&v"(c), "=&v"(d)
                 : "v"(p0), "v"(p1), "v"(p2), "v"(p3) : "memory");
}
__device__ __forceinline__ void cstore4(float* p, f4 v){
    asm volatile("global_store_dwordx4 %0, %1, off sc0 sc1"
                 :: "v"(p), "v"(v) : "memory");
}
__device__ __forceinline__ void cstore1(float* p, float v){
    asm volatile("global_store_dword %0, %1, off sc0 sc1"
                 :: "v"(p), "v"(v) : "memory");
}

// ---- packed-flag protocol ----
__device__ __forceinline__ void multi_wait_d(const unsigned int* f, int n,
                                             unsigned int tgt, int tid){
    if (tid < n) {
        const unsigned int* p = f + tid;
        while (__hip_atomic_load(p, __ATOMIC_RELAXED,
                                 __HIP_MEMORY_SCOPE_AGENT) < tgt)
            __builtin_amdgcn_s_sleep(2);
    }
    __syncthreads();
}
__device__ __forceinline__ void flag_set_d(unsigned int* f, unsigned int v, int tid){
    asm volatile("s_waitcnt vmcnt(0)" ::: "memory");
    __syncthreads();
    if (tid == 0)
        __hip_atomic_store(f, v, __ATOMIC_RELAXED, __HIP_MEMORY_SCOPE_AGENT);
}

__global__ void dnc_zero(float* ws){
    unsigned int* z = (unsigned int*)(ws + WS_FLAGS);
    for (int e = threadIdx.x; e < D_TOTAL; e += blockDim.x) z[e] = 0u;
}

// ---- pooled LDS (floats) ----
#define O_MEM 0         // 8704 (128 x 68)
#define O_RW2 8704      // 1024: rw double-buffered [2][4][128]
#define O_WW2 9728      // 256: ww double-buffered [2][128]
#define O_USG 9984      // 128
#define O_PRC 10112     // 128
#define O_XI  10240     // 480
#define O_KEY 10720     // 256
#define O_WK  10976     // 64
#define O_ER  11040     // 64
#define O_WV  11104     // 64
#define O_RS  11168     // 4
#define O_FG  11172     // 4
#define O_MD  11176     // 12
#define O_NK  11188     // 4
#define O_SC  11192     // 8
#define O_NRM 11200     // 2 x 128 double-buffered row norms
#define O_WCW 11456     // 128
#define O_UU  11584     // 128
#define O_SU  11712     // 128
#define O_CUM 11840     // 128
#define O_RNK 11968     // 128 (int)
#define O_CCW 12096     // 512
#define O_RED 12608     // 16
#define O_PF  12624     // 4096: J fwd partials [8][4][128]
#define O_PB  16720     // 4096: J bwd partials [8][4][128]
#define O_PK  12624     // 2048: K partials [8][4][64] (aliases PF; disjoint phases)
#define O_LK  20816     // 128*129 link matrix
#define S_SZ  (20816 + NM*LKS)     // 37328 floats = 149,312 B; 1 block/CU
// gates role (disjoint): x/rv staging S[0..8191]
#define G_ACC 8192      // [32][17]
#define G_C   8736      // [32][5]
#define G_H   8896      // [32][512] h(t-1) staging

__global__ __launch_bounds__(TPB) void dnc_pipe2(
    const float* __restrict__ x, const float* __restrict__ W_ih,
    const float* __restrict__ W_hh, const float* __restrict__ b_ih,
    const float* __restrict__ b_hh, const float* __restrict__ W_xi,
    const float* __restrict__ b_xi, const float* __restrict__ W_o,
    const float* __restrict__ b_o, float* __restrict__ out,
    float* __restrict__ ws)
{
    __shared__ __align__(16) float S[S_SZ];

    const int tid = threadIdx.x;
    const int wv  = tid >> 6;
    const int l   = tid & 63;
    const int bid = blockIdx.x;

    float* __restrict__ pubH  = ws + WS_PUBH;
    float* __restrict__ pubRV = ws + WS_PUBRV;
    float* __restrict__ pubXI = ws + WS_PUBXI;
    unsigned int* __restrict__ FLGD = (unsigned int*)(ws + WS_FLAGS);

    if (bid < NBATCH) {
        // ========================= STATE block =========================
        const int b = bid;
        float* lk = S+O_LK;
        float* mem = S+O_MEM;
        float* usg = S+O_USG;  float* prc = S+O_PRC; float* xiS = S+O_XI;
        float* keys = S+O_KEY; float* wkey = S+O_WK; float* ers = S+O_ER;
        float* wvec = S+O_WV;  float* rstr = S+O_RS; float* fgte = S+O_FG;
        float* modes = S+O_MD; float* nkey = S+O_NK; float* sc = S+O_SC;
        float* nrm = S+O_NRM;  float* wcw = S+O_WCW;
        float* uu = S+O_UU;    float* su = S+O_SU;   float* cum = S+O_CUM;
        int*   rnk = (int*)(S+O_RNK);
        float* ccw = S+O_CCW;  float* red = S+O_RED;

        for (int e = tid; e < NM*LKS; e += TPB) lk[e] = 0.0f;
        for (int e = tid; e < NM*NW; e += TPB) mem[(e>>6)*MS + (e&63)] = EPSF;
        for (int e = tid; e < 2*NR*NM; e += TPB) S[O_RW2+e]=0.0f;
        for (int e = tid; e < 2*NM; e += TPB) S[O_WW2+e]=0.0f;
        for (int e = tid; e < NM; e += TPB){ usg[e]=0.0f; prc[e]=0.0f; }
        for (int e = tid; e < 2*NM; e += TPB) nrm[e] = 8.0f*EPSF; // ||EPS row||
        __syncthreads();

        for (int t = 0; t < NT; ++t) {
            const int par = t & 1;
            float* nmo = nrm + 128*par;            // old norms = prev step's new
            float* nmn = nrm + 128*(par^1);
            float* rwC = S + O_RW2 + 512*par;      // rw(t-1)
            float* rwN = S + O_RW2 + 512*(par^1);  // rw(t) written this step
            float* wwP = S + O_WW2 + 128*(par^1);  // ww(t-1)
            float* wwC = S + O_WW2 + 128*par;      // ww(t) written this step

            // P1: xi(t) ready; load
            multi_wait_d(&FLGD[D_X], NXB, (unsigned)(t+1), tid);
            if (tid < 120)
                *(f4*)&xiS[tid*4] =
                    cload4(&pubXI[(size_t)par*NBATCH*480 + b*480 + tid*4]);
            __syncthreads();

            // P2: E1 unpack interface
            if (tid < 256)       keys[tid] = tanhf(xiS[tid]);
            else if (tid < 260)  rstr[tid-256] = sftp(xiS[tid]);
            else if (tid < 324)  wkey[tid-260] = tanhf(xiS[tid]);
            else if (tid == 324) sc[0] = sftp(xiS[324]);
            else if (tid < 389)  ers[tid-325] = sigm(xiS[tid]);
            else if (tid < 453)  wvec[tid-389] = tanhf(xiS[tid]);
            else if (tid < 457)  fgte[tid-453] = sigm(xiS[tid]);
            else if (tid == 457) sc[1] = sigm(xiS[457]);
            else if (tid == 458) sc[2] = sigm(xiS[458]);
            else if (tid < 463) {
                int r = tid - 459;
                float a0=xiS[459+3*r], a1=xiS[460+3*r], a2=xiS[461+3*r];
                float mx = fmaxf(a0, fmaxf(a1, a2));
                float e0=expf(a0-mx), e1=expf(a1-mx), e2=expf(a2-mx);
                float si = 1.0f/(e0+e1+e2);
                modes[3*r]=e0*si; modes[3*r+1]=e1*si; modes[3*r+2]=e2*si;
            }
            __syncthreads();

            // P3: key norms (waves 0-4) ∥ usage+uu (waves 6-7)
            if (wv < 4) {
                float v = keys[wv*NW + l];
                float s2 = wave_red(v*v);
                if (l == 0) nkey[wv] = sqrtf(s2);
            } else if (wv == 4) {
                float v = wkey[l];
                float s2 = wave_red(v*v);
                if (l == 0) sc[3] = sqrtf(s2);
            } else if (wv == 6 || wv == 7) {
                int m = tid - 384;
                float u = usg[m];
                u = u + (1.0f - u)*wwP[m];
                float psi = 1.0f;
                #pragma unroll
                for (int r = 0; r < NR; ++r) psi *= (1.0f - fgte[r]*rwC[r*NM+m]);
                u *= psi;
                usg[m] = u;
                uu[m] = 5e-6f + (1.0f - 5e-6f)*u;
            }
            __syncthreads();

            // P4: F1 write-content logits — f4 reads, 8 thr/row
            {
                const int m = tid >> 3, s = tid & 7;
                const f4* mem4 = (const f4*)(S + O_MEM);
                const f4* wk4  = (const f4*)(S + O_WK);
                f4 m0 = mem4[m*MS4 + s*2], m1 = mem4[m*MS4 + s*2 + 1];
                f4 k0 = wk4[s*2], k1 = wk4[s*2 + 1];
                float d = dot4(m0, k0) + dot4(m1, k1);
                d += __shfl_down(d, 4); d += __shfl_down(d, 2); d += __shfl_down(d, 1);
                if (s == 0) wcw[m] = d/(sc[3]*nmo[m] + EPSF) * sc[0];
            }
            __syncthreads();

            // P5: wcw softmax (wave 0) ∥ G2 rank (waves 8-15)
            if (tid < 64) {
                float w0 = wcw[l], w1 = wcw[l+64];
                float mx = fmaxf(w0, w1);
                #pragma unroll
                for (int o = 32; o > 0; o >>= 1) mx = fmaxf(mx, __shfl_down(mx, o));
                float M = __shfl(mx, 0);
                float e0 = expf(w0 - M), e1 = expf(w1 - M);
                float s = wave_red(e0 + e1);
                float inv = 1.0f/__shfl(s, 0);
                wcw[l] = e0*inv; wcw[l+64] = e1*inv;
            } else if (tid >= 512) {
                const int q = tid - 512, m = q >> 2, s = q & 3;
                const float um = uu[m];
                int rk = 0;
                #pragma unroll 8
                for (int k = 0; k < 32; ++k) {
                    int j = 4*k + s;
                    float uj = uu[j];
                    rk += (uj < um) || (uj == um && j < m);
                }
                rk += __shfl_down(rk, 1); rk += __shfl_down(rk, 2);
                if (s == 0) { rnk[m] = rk; su[rk] = um; }
            }
            __syncthreads();

            // P6: product scan (wave 0)
            if (tid < 64) {
                float a = su[tid], bb = su[64+tid];
                #pragma unroll
                for (int o = 1; o < 64; o <<= 1) {
                    float ta = __shfl_up(a, o);
                    float tb = __shfl_up(bb, o);
                    if (tid >= o) { a *= ta; bb *= tb; }
                }
                float P0 = __shfl(a, 63);
                cum[tid] = a;
                cum[64+tid] = P0*bb;
            }
            __syncthreads();

            // P7: alloc + wwC + per-wave alloc-sum partials
            if (tid < NM) {
                int rk = rnk[tid];
                float excl = (rk == 0) ? 1.0f : cum[rk-1];
                float al = (1.0f - uu[tid])*excl;
                wwC[tid] = sc[2]*(sc[1]*al + (1.0f - sc[1])*wcw[tid]);
                float sal = wave_red(al);
                if (l == 0) red[2 + wv] = sal;
            }
            __syncthreads();

            // P8: sc[4] analytic + mem erase/write + nmn (link update moved to P9)
            if (tid == 1023)
                sc[4] = sc[2]*(sc[1]*(red[2]+red[3]) + (1.0f - sc[1]));
            #pragma unroll
            for (int ri = 0; ri < 8; ++ri) {
                int row = wv*8 + ri;
                float wm = wwC[row];
                float v = mem[row*MS + l];
                float nv = v*(1.0f - wm*ers[l]) + wm*wvec[l];
                mem[row*MS + l] = nv;
                float s2 = wave_red(nv*nv);
                if (l == 0) nmn[row] = sqrtf(s2);
            }
            __syncthreads();

            // P9: I logits (waves 0-7, keys via broadcast b128)
            //     ∥ J row-scan + FUSED link update (waves 8-15)
            if (tid < 512) {
                const int m = tid >> 2, s = tid & 3;
                const f4* mem4 = (const f4*)(S + O_MEM);
                const f4* key4 = (const f4*)(S + O_KEY);
                float a0=0.f, a1=0.f, a2=0.f, a3=0.f;
                #pragma unroll
                for (int c = 0; c < 4; ++c) {
                    f4 mv = mem4[m*MS4 + s*4 + c];
                    f4 k0 = key4[0*16 + s*4 + c];   // broadcast (4 addrs/wave)
                    f4 k1 = key4[1*16 + s*4 + c];
                    f4 k2 = key4[2*16 + s*4 + c];
                    f4 k3 = key4[3*16 + s*4 + c];
                    a0 += dot4(mv, k0); a1 += dot4(mv, k1);
                    a2 += dot4(mv, k2); a3 += dot4(mv, k3);
                }
                a0 += __shfl_down(a0,1); a0 += __shfl_down(a0,2);
                a1 += __shfl_down(a1,1); a1 += __shfl_down(a1,2);
                a2 += __shfl_down(a2,1); a2 += __shfl_down(a2,2);
                a3 += __shfl_down(a3,1); a3 += __shfl_down(a3,2);
                if (s == 0) {
                    float nm = nmn[m];
                    ccw[0*NM+m] = a0/(nkey[0]*nm + EPSF)*rstr[0];
                    ccw[1*NM+m] = a1/(nkey[1]*nm + EPSF)*rstr[1];
                    ccw[2*NM+m] = a2/(nkey[2]*nm + EPSF)*rstr[2];
                    ccw[3*NM+m] = a3/(nkey[3]*nm + EPSF)*rstr[3];
                }
            } else {
                const int wj = wv - 8;          // 0..7: i-chunk of 16
                const int i0 = wj*16;
                const float wmA = wwC[l], wmB = wwC[64+l];   // row ww (lane-local)
                float fA0=0,fA1=0,fA2=0,fA3=0, fB0=0,fB1=0,fB2=0,fB3=0;
                #pragma unroll 4
                for (int ii = 0; ii < 16; ++ii) {
                    const int i = i0 + ii;
                    float pri = prc[i];          // broadcast
                    float wwi = wwC[i];          // broadcast
                    float r0 = rwC[0*NM+i];      // broadcast
                    float r1 = rwC[1*NM+i];
                    float r2 = rwC[2*NM+i];
                    float r3 = rwC[3*NM+i];
                    // row A: element (l, i) — update + use
                    float lrA = lk[l*LKS + i];
                    float nA = (i == l) ? 0.0f
                             : (1.0f - wmA - wwi)*lrA + wmA*pri;
                    lk[l*LKS + i] = nA;
                    // row B: element (l+64, i)
                    float lrB = lk[(l+64)*LKS + i];
                    float nB = (i == l+64) ? 0.0f
                             : (1.0f - wmB - wwi)*lrB + wmB*pri;
                    lk[(l+64)*LKS + i] = nB;
                    fA0 += nA*r0; fA1 += nA*r1; fA2 += nA*r2; fA3 += nA*r3;
                    fB0 += nB*r0; fB1 += nB*r1; fB2 += nB*r2; fB3 += nB*r3;
                }
                float* Pf = S + O_PF + wj*512;
                Pf[0*NM+l]=fA0; Pf[1*NM+l]=fA1; Pf[2*NM+l]=fA2; Pf[3*NM+l]=fA3;
                Pf[0*NM+64+l]=fB0; Pf[1*NM+64+l]=fB1;
                Pf[2*NM+64+l]=fB2; Pf[3*NM+64+l]=fB3;
            }
            __syncthreads();

            // P10: ccw softmax (waves 0-3) ∥ precedence (tid 256-383)
            //      ∥ J col-scan on NEW lk (waves 8-15)
            if (tid < 256) {
                float v0 = ccw[wv*NM + l], v1 = ccw[wv*NM + 64 + l];
                float mx = fmaxf(v0, v1);
                #pragma unroll
                for (int o = 32; o > 0; o >>= 1) mx = fmaxf(mx, __shfl_down(mx, o));
                float M = __shfl(mx, 0);
                float e0 = expf(v0 - M), e1 = expf(v1 - M);
                float s = wave_red(e0 + e1);
                float inv = 1.0f/__shfl(s, 0);
                ccw[wv*NM + l] = e0*inv; ccw[wv*NM + 64 + l] = e1*inv;
            } else if (tid < 384) {
                int m = tid - 256;
                prc[m] = (1.0f - sc[4])*prc[m] + wwC[m];
            } else if (wv >= 8) {
                const int wj = wv - 8;
                const int i0 = wj*16;
                float bA0=0,bA1=0,bA2=0,bA3=0, bB0=0,bB1=0,bB2=0,bB3=0;
                #pragma unroll 4
                for (int ii = 0; ii < 16; ++ii) {
                    const int i = i0 + ii;
                    float r0 = rwC[0*NM+i];      // broadcast
                    float r1 = rwC[1*NM+i];
                    float r2 = rwC[2*NM+i];
                    float r3 = rwC[3*NM+i];
                    float lcA = lk[i*LKS + l];       // col j=l (new lk)
                    float lcB = lk[i*LKS + 64 + l];  // col j=l+64
                    bA0 += lcA*r0; bA1 += lcA*r1; bA2 += lcA*r2; bA3 += lcA*r3;
                    bB0 += lcB*r0; bB1 += lcB*r1; bB2 += lcB*r2; bB3 += lcB*r3;
                }
                float* Pb = S + O_PB + wj*512;
                Pb[0*NM+l]=bA0; Pb[1*NM+l]=bA1; Pb[2*NM+l]=bA2; Pb[3*NM+l]=bA3;
                Pb[0*NM+64+l]=bB0; Pb[1*NM+64+l]=bB1;
                Pb[2*NM+64+l]=bB2; Pb[3*NM+64+l]=bB3;
            }
            __syncthreads();

            // P11: J-combine + mode mix -> rwN (new read weights, double-buffered)
            if (tid < 512) {
                const int r = tid >> 7, m = tid & 127;
                float fs = 0.0f, bs = 0.0f;
                #pragma unroll
                for (int c = 0; c < 8; ++c) {
                    fs += S[O_PF + c*512 + r*NM + m];
                    bs += S[O_PB + c*512 + r*NM + m];
                }
                rwN[r*NM + m] = modes[3*r]*bs + modes[3*r+1]*fs
                              + modes[3*r+2]*ccw[r*NM + m];
            }
            __syncthreads();

            // P12: K main (waves 0-7): lane=w, rwN via broadcast reads
            if (wv < 8) {
                const int m0 = wv*16;
                float a0=0.f, a1=0.f, a2=0.f, a3=0.f;
                #pragma unroll 4
                for (int mm = 0; mm < 16; ++mm) {
                    const int m = m0 + mm;
                    float rn0 = rwN[0*NM + m];   // broadcast
                    float rn1 = rwN[1*NM + m];
                    float rn2 = rwN[2*NM + m];
                    float rn3 = rwN[3*NM + m];
                    float mv = mem[m*MS + l];
                    a0 += rn0*mv; a1 += rn1*mv; a2 += rn2*mv; a3 += rn3*mv;
                }
                float* Pk = S + O_PK + wv*256;
                Pk[0*64+l]=a0; Pk[1*64+l]=a1; Pk[2*64+l]=a2; Pk[3*64+l]=a3;
            }
            __syncthreads();

            // P13: K reduce -> publish rv DIRECT to LLC (coalesced scalar stores)
            if (tid < 256) {
                const int r = tid >> 6, w = tid & 63;
                float s = 0.0f;
                #pragma unroll
                for (int c = 0; c < 8; ++c) s += S[O_PK + c*256 + r*64 + w];
                cstore1(&pubRV[(size_t)par*NBATCH*NR*NW + b*NR*NW + r*NW + w], s);
            }
            flag_set_d(&FLGD[D_R + b], (unsigned)(t+1), tid);
        }
    } else {
        // ===== GATES block: 4 units (16 gate rows) + LSTM + 4 xi + 4 out ====
        const int g = bid - 32;            // owns units u = 4g .. 4g+3
        const int gate = wv >> 2, j = wv & 3;
        const int r = gate*NH + 4*g + j;   // weight row: gate, unit 4g+j
        const f4* WA = (const f4*)(W_ih + (size_t)r*NI);
        f4 wx0 = WA[l], wx1 = WA[l+64], wrv = WA[128+l];
        const f4* WB = (const f4*)(W_hh + (size_t)r*NH);
        f4 wh0 = WB[l], wh1 = WB[l+64];
        const float bias = b_ih[r] + b_hh[r];
        float* accS = S + G_ACC;   // [32][17]
        float* cSg  = S + G_C;     // [32][5]
        float* hStg = S + G_H;     // [32][512] h(t-1) staging
        const int sbi = tid >> 7, sk4 = (tid & 127) << 2;

        if (tid < 160) cSg[tid] = 0.0f;
        for (int e = tid; e < NBATCH*NH; e += TPB) hStg[e] = 0.0f;  // h(-1)=0
        __syncthreads();

        for (int t = 0; t <= NT; ++t) {          // NT+1 iters (epilogue at NT)
            const int par = t & 1, parp = (t+1) & 1;   // parp = parity of t-1

            // A: stage ALL h(t-1); then xi(t-1) from our 8KB W_xi slice
            if (t >= 1) {
                multi_wait_d(&FLGD[D_G], 128, (unsigned)t, tid);   // h(t-1) all
                const float* hIn = pubH + (size_t)parp*NBATCH*NH;
                f4 a0, a1, a2, a3;
                cload4x4(hIn + tid*4, hIn + (tid+1024)*4,
                         hIn + (tid+2048)*4, hIn + (tid+3072)*4,
                         a0, a1, a2, a3);
                *(f4*)&hStg[tid*4]          = a0;
                *(f4*)&hStg[(tid+1024)*4]   = a1;
                *(f4*)&hStg[(tid+2048)*4]   = a2;
                *(f4*)&hStg[(tid+3072)*4]   = a3;
                __syncthreads();
                if (g < NXB) {
                    float* xOut = pubXI + (size_t)parp*NBATCH*480;
                    #pragma unroll
                    for (int bb = 0; bb < 2; ++bb) {
                        const int bi = 2*wv + bb;
                        const f4* H4 = (const f4*)(hStg + bi*512);
                        f4 res = {0.0f, 0.0f, 0.0f, 0.0f};
                        #pragma unroll
                        for (int jj = 0; jj < 4; ++jj) {
                            const int row = 4*g + jj;
                            if (row < NXI) {
                                const f4* WX = (const f4*)(W_xi + (size_t)row*NH);
                                float a = dot4(WX[l], H4[l])
                                        + dot4(WX[l+64], H4[l+64]);
                                a = wave_red(a);
                                res[jj] = a + b_xi[row];
                            }
                        }
                        if (l == 0) cstore4(&xOut[(size_t)bi*480 + 4*g], res);
                    }
                    flag_set_d(&FLGD[D_X + g], (unsigned)t, tid);
                }
            }

            // B: heavy phase x(t)·W_ih + h(t-1)·W_hh (off critical path)
            if (t < NT) {
                for (int p = 0; p < 4; ++p) {
                    const int b0 = p*8;
                    *(f4*)&S[sbi*512 + sk4] =
                        *(const f4*)&x[((size_t)(b0+sbi)*NT + t)*NH + sk4];
                    __syncthreads();
                    #pragma unroll
                    for (int bi = 0; bi < 8; ++bi) {
                        const f4* X4 = (const f4*)(S + bi*512);
                        const f4* H4 = (const f4*)(hStg + (b0+bi)*512);
                        float a = dot4(wx0, X4[l]) + dot4(wx1, X4[l+64])
                                + dot4(wh0, H4[l]) + dot4(wh1, H4[l+64]);
                        a = wave_red(a);
                        if (l == 0) accS[(b0+bi)*17 + wv] = a + bias;
                    }
                    __syncthreads();
                }
            }

            // C: rv(t-1) — the critical-path input
            {
                const int bi0 = tid >> 6, k40 = (tid & 63) << 2;
                if (t >= 1) {
                    multi_wait_d(&FLGD[D_R], 32, (unsigned)t, tid);
                    const float* rIn = pubRV + (size_t)parp*NBATCH*NR*NW;
                    f4 a0, a1;
                    cload4x2(&rIn[bi0*256 + k40], &rIn[(bi0+16)*256 + k40], a0, a1);
                    *(f4*)&S[bi0*256 + k40] = a0;
                    *(f4*)&S[(bi0+16)*256 + k40] = a1;
                } else {
                    f4 z = {0.0f, 0.0f, 0.0f, 0.0f};
                    *(f4*)&S[bi0*256 + k40] = z;
                    *(f4*)&S[(bi0+16)*256 + k40] = z;
                }
            }
            __syncthreads();

            // D: rv dot + LSTM + publish h(t)
            if (t < NT) {
                #pragma unroll
                for (int bi = 0; bi < 32; ++bi) {
                    const f4* RV4 = (const f4*)(S + bi*256);
                    float d = dot4(wrv, RV4[l]);
                    d = wave_red(d);
                    if (l == 0) accS[bi*17 + wv] += d;
                }
                __syncthreads();
                if (tid < 32) {
                    const int bi = tid;
                    const float* acc = accS + bi*17;
                    f4 hq;
                    #pragma unroll
                    for (int jj = 0; jj < 4; ++jj) {
                        float i_ = sigm(acc[0*4 + jj]);
                        float f_ = sigm(acc[1*4 + jj]);
                        float g_ = tanhf(acc[2*4 + jj]);
                        float o_ = sigm(acc[3*4 + jj]);
                        float c  = f_*cSg[bi*5 + jj] + i_*g_;
                        cSg[bi*5 + jj] = c;
                        hq[jj] = o_*tanhf(c);
                    }
                    cstore4(&pubH[(size_t)par*NBATCH*NH + (size_t)bi*NH + 4*g], hq);
                }
                flag_set_d(&FLGD[D_G + g], (unsigned)(t+1), tid);
            }

            // E: out(t-1) from hStg (h(t-1)) + staged rv(t-1) — idle shadow
            if (t >= 1) {
                #pragma unroll
                for (int bb = 0; bb < 2; ++bb) {
                    const int bi = 2*wv + bb;
                    const f4* H4 = (const f4*)(hStg + bi*512);
                    const f4* RV4 = (const f4*)(S + bi*256);
                    f4 res;
                    #pragma unroll
                    for (int jj = 0; jj < 4; ++jj) {
                        const int row = 4*g + jj;
                        const f4* WO = (const f4*)(W_o + (size_t)row*NI);
                        float a = dot4(WO[l], H4[l]) + dot4(WO[l+64], H4[l+64])
                                + dot4(WO[128+l], RV4[l]);
                        a = wave_red(a);
                        res[jj] = a + b_o[row];
                    }
                    if (l == 0)
                        *(f4*)&out[((size_t)bi*NT + (t-1))*NH + 4*g] = res;
                }
            }
        }
    }
}

extern "C" void kernel_launch(void* const* d_in, const int* in_sizes, int n_in,
                              void* d_out, int out_size, void* d_ws, size_t ws_size,
                              hipStream_t stream) {
    (void)in_sizes; (void)n_in; (void)out_size; (void)ws_size;
    const float* x    = (const float*)d_in[0];
    const float* W_ih = (const float*)d_in[1];
    const float* W_hh = (const float*)d_in[2];
    const float* b_ih = (const float*)d_in[3];
    const float* b_hh = (const float*)d_in[4];
    const float* W_xi = (const float*)d_in[5];
    const float* b_xi = (const float*)d_in[6];
    const float* W_o  = (const float*)d_in[7];
    const float* b_o  = (const float*)d_in[8];
    float* out = (float*)d_out;
    float* ws  = (float*)d_ws;

    dnc_zero<<<1, 512, 0, stream>>>(ws);

    void* args[] = { (void*)&x, (void*)&W_ih, (void*)&W_hh, (void*)&b_ih,
                     (void*)&b_hh, (void*)&W_xi, (void*)&b_xi, (void*)&W_o,
                     (void*)&b_o, (void*)&out, (void*)&ws };
    hipLaunchCooperativeKernel((void*)dnc_pipe2, dim3(NBLK), dim3(TPB),
                               args, 0, stream);
}

// Round 10
// 2564.965 us; speedup vs baseline: 2.2844x; 1.0233x over previous
//
#include <hip/hip_runtime.h>
#include <math.h>

#define TPB 1024
#define NBLK 160
#define NBATCH 32
#define NT 64
#define NH 512
#define NM 128
#define NR 4
#define NW 64
#define NI 768          // controller input size (H + R*W)
#define NXI 471         // interface vector size
#define EPSF 1e-6f
#define MS 68           // mem row stride (f4-aligned, bank-audited)
#define MS4 17          // MS/4
#define LKS 129         // link row stride (odd: row+col b32 scans conflict-free)

// roles: [0,32) state (DNC machinery only) |
//        [32,160) gates blocks: 4 hidden units (16 gate rows) + LSTM cell
//                 + 4 xi rows + 4 out rows (distributed W_xi / W_o streams)

typedef float f4 __attribute__((ext_vector_type(4)));

// ws layout (float offsets). pub* parity double-buffered.
#define WS_PUBH  0                                 // [2][32][512] (gates)
#define WS_PUBRV (WS_PUBH + 2*NBATCH*NH)           // [2][32][256] (state)
#define WS_PUBXI (WS_PUBRV + 2*NBATCH*NR*NW)       // [2][32][480] (gates)
#define WS_FLAGS (WS_PUBXI + 2*NBATCH*480)
// packed flag dwords
#define D_G 0        // 128 gate blocks: h(t) published -> t+1
#define D_R 128      // 32 state blocks: rv(t) published -> t+1
#define D_X 160      // 118 gate blocks: xi(t-1) published -> t
#define D_TOTAL 288
#define NXB 118      // gate blocks that own xi rows (4*118 >= 471)

__device__ __forceinline__ float sigm(float x){ return 1.0f/(1.0f+expf(-x)); }
__device__ __forceinline__ float sftp(float x){ return fmaxf(x,0.0f)+log1pf(expf(-fabsf(x))); }
__device__ __forceinline__ float dot4(f4 a, f4 b){
    return a.x*b.x + a.y*b.y + a.z*b.z + a.w*b.w;
}
__device__ __forceinline__ float wave_red(float v){
    #pragma unroll
    for (int o = 32; o > 0; o >>= 1) v += __shfl_down(v, o);
    return v;
}

// ---- coherent (LLC write-through, device-visible) accessors: sc0 sc1 ----
__device__ __forceinline__ f4 cload4(const float* p){
    f4 v;
    asm volatile("global_load_dwordx4 %0, %1, off sc0 sc1\n\t"
                 "s_waitcnt vmcnt(0)"
                 : "=&v"(v) : "v"(p) : "memory");
    return v;
}
__device__ __forceinline__ float cload1f(const float* p){
    float v;
    asm volatile("global_load_dword %0, %1, off sc0 sc1\n\t"
                 "s_waitcnt vmcnt(0)"
                 : "=&v"(v) : "v"(p) : "memory");
    return v;
}
__device__ __forceinline__ void cload4x2(const float* p0, const float* p1,
                                         f4& a, f4& b){
    asm volatile("global_load_dwordx4 %0, %2, off sc0 sc1\n\t"
                 "global_load_dwordx4 %1, %3, off sc0 sc1\n\t"
                 "s_waitcnt vmcnt(0)"
                 : "=&v"(a), "=&v"(b) : "v"(p0), "v"(p1) : "memory");
}
__device__ __forceinline__ void cload4x4(const float* p0, const float* p1,
                                         const float* p2, const float* p3,
                                         f4& a, f4& b, f4& c, f4& d){
    asm volatile("global_load_dwordx4 %0, %4, off sc0 sc1\n\t"
                 "global_load_dwordx4 %1, %5, off sc0 sc1\n\t"
                 "global_load_dwordx4 %2, %6, off sc0 sc1\n\t"
                 "global_load_dwordx4 %3, %7, off sc0 sc1\n\t"
                 "s_waitcnt vmcnt(0)"
                 : "=&v"(a), "=&v"(b), "=&v"(c), "=&v"(d)
                 : "v"(p0), "v"(p1), "v"(p2), "v"(p3) : "memory");
}
__device__ __forceinline__ void cstore4(float* p, f4 v){
    asm volatile("global_store_dwordx4 %0, %1, off sc0 sc1"
                 :: "v"(p), "v"(v) : "memory");
}
__device__ __forceinline__ void cstore1(float* p, float v){
    asm volatile("global_store_dword %0, %1, off sc0 sc1"
                 :: "v"(p), "v"(v) : "memory");
}

// ---- packed-flag protocol ----
__device__ __forceinline__ void multi_wait_d(const unsigned int* f, int n,
                                             unsigned int tgt, int tid){
    if (tid < n) {
        const unsigned int* p = f + tid;
        while (__hip_atomic_load(p, __ATOMIC_RELAXED,
                                 __HIP_MEMORY_SCOPE_AGENT) < tgt)
            __builtin_amdgcn_s_sleep(2);
    }
    __syncthreads();
}
__device__ __forceinline__ void flag_set_d(unsigned int* f, unsigned int v, int tid){
    asm volatile("s_waitcnt vmcnt(0)" ::: "memory");
    __syncthreads();
    if (tid == 0)
        __hip_atomic_store(f, v, __ATOMIC_RELAXED, __HIP_MEMORY_SCOPE_AGENT);
}

__global__ void dnc_zero(float* ws){
    unsigned int* z = (unsigned int*)(ws + WS_FLAGS);
    for (int e = threadIdx.x; e < D_TOTAL; e += blockDim.x) z[e] = 0u;
}

// ---- pooled LDS (floats) ----
#define O_MEM 0         // 8704 (128 x 68)
#define O_RW2 8704      // 1024: rw double-buffered [2][4][128]
#define O_WW2 9728      // 256: ww double-buffered [2][128]
#define O_USG 9984      // 128
#define O_PRC 10112     // 128
#define O_KEY 10720     // 256
#define O_WK  10976     // 64
#define O_ER  11040     // 64
#define O_WV  11104     // 64
#define O_RS  11168     // 4
#define O_FG  11172     // 4
#define O_MD  11176     // 12
#define O_NK  11188     // 4
#define O_SC  11192     // 8
#define O_NRM 11200     // 2 x 128 double-buffered row norms
#define O_WCW 11456     // 128
#define O_UU  11584     // 128
#define O_SU  11712     // 128
#define O_CUM 11840     // 128
#define O_RNK 11968     // 128 (int)
#define O_CCW 12096     // 512
#define O_RED 12608     // 16
#define O_PF  12624     // 4096: J fwd partials [8][4][128]
#define O_PB  16720     // 4096: J bwd partials [8][4][128]
#define O_PK  12624     // 2048: K partials [8][4][64] (aliases PF; disjoint phases)
#define O_LK  20816     // 128*129 link matrix
#define S_SZ  (20816 + NM*LKS)     // 37328 floats = 149,312 B; 1 block/CU
// gates role (disjoint): x/rv staging S[0..8191]
#define G_ACC 8192      // [32][17]
#define G_C   8736      // [32][5]
#define G_H   8896      // [32][512] h(t-1) staging
#define G_OH  25280     // [32][5] out H-part partials (hoisted into B slack)

__global__ __launch_bounds__(TPB) void dnc_pipe2(
    const float* __restrict__ x, const float* __restrict__ W_ih,
    const float* __restrict__ W_hh, const float* __restrict__ b_ih,
    const float* __restrict__ b_hh, const float* __restrict__ W_xi,
    const float* __restrict__ b_xi, const float* __restrict__ W_o,
    const float* __restrict__ b_o, float* __restrict__ out,
    float* __restrict__ ws)
{
    __shared__ __align__(16) float S[S_SZ];

    const int tid = threadIdx.x;
    const int wv  = tid >> 6;
    const int l   = tid & 63;
    const int bid = blockIdx.x;

    float* __restrict__ pubH  = ws + WS_PUBH;
    float* __restrict__ pubRV = ws + WS_PUBRV;
    float* __restrict__ pubXI = ws + WS_PUBXI;
    unsigned int* __restrict__ FLGD = (unsigned int*)(ws + WS_FLAGS);

    if (bid < NBATCH) {
        // ========================= STATE block =========================
        const int b = bid;
        float* lk = S+O_LK;
        float* mem = S+O_MEM;
        float* usg = S+O_USG;  float* prc = S+O_PRC;
        float* keys = S+O_KEY; float* wkey = S+O_WK; float* ers = S+O_ER;
        float* wvec = S+O_WV;  float* rstr = S+O_RS; float* fgte = S+O_FG;
        float* modes = S+O_MD; float* nkey = S+O_NK; float* sc = S+O_SC;
        float* nrm = S+O_NRM;  float* wcw = S+O_WCW;
        float* uu = S+O_UU;    float* su = S+O_SU;   float* cum = S+O_CUM;
        int*   rnk = (int*)(S+O_RNK);
        float* ccw = S+O_CCW;  float* red = S+O_RED;

        for (int e = tid; e < NM*LKS; e += TPB) lk[e] = 0.0f;
        for (int e = tid; e < NM*NW; e += TPB) mem[(e>>6)*MS + (e&63)] = EPSF;
        for (int e = tid; e < 2*NR*NM; e += TPB) S[O_RW2+e]=0.0f;
        for (int e = tid; e < 2*NM; e += TPB) S[O_WW2+e]=0.0f;
        for (int e = tid; e < NM; e += TPB){ usg[e]=0.0f; prc[e]=0.0f; }
        for (int e = tid; e < 2*NM; e += TPB) nrm[e] = 8.0f*EPSF; // ||EPS row||
        __syncthreads();

        for (int t = 0; t < NT; ++t) {
            const int par = t & 1;
            float* nmo = nrm + 128*par;            // old norms = prev step's new
            float* nmn = nrm + 128*(par^1);
            float* rwC = S + O_RW2 + 512*par;      // rw(t-1)
            float* rwN = S + O_RW2 + 512*(par^1);  // rw(t) written this step
            float* wwP = S + O_WW2 + 128*(par^1);  // ww(t-1)
            float* wwC = S + O_WW2 + 128*par;      // ww(t) written this step

            // P1+P2 fused: xi(t) ready; DIRECT coherent loads into unpack
            // (xiS LDS round-trip + one barrier deleted)
            multi_wait_d(&FLGD[D_X], NXB, (unsigned)(t+1), tid);
            {
                const float* xb = pubXI + (size_t)par*NBATCH*480 + b*480;
                if (tid < 256)       keys[tid] = tanhf(cload1f(xb+tid));
                else if (tid < 260)  rstr[tid-256] = sftp(cload1f(xb+tid));
                else if (tid < 324)  wkey[tid-260] = tanhf(cload1f(xb+tid));
                else if (tid == 324) sc[0] = sftp(cload1f(xb+324));
                else if (tid < 389)  ers[tid-325] = sigm(cload1f(xb+tid));
                else if (tid < 453)  wvec[tid-389] = tanhf(cload1f(xb+tid));
                else if (tid < 457)  fgte[tid-453] = sigm(cload1f(xb+tid));
                else if (tid == 457) sc[1] = sigm(cload1f(xb+457));
                else if (tid == 458) sc[2] = sigm(cload1f(xb+458));
                else if (tid < 471) {
                    // tid 459..470 = wave 7 lanes 11..22 (all active here)
                    float xv = cload1f(xb + tid);
                    int r = tid - 459;             // 0..11
                    float a0 = __shfl(xv, 11 + 3*r);
                    float a1 = __shfl(xv, 12 + 3*r);
                    float a2 = __shfl(xv, 13 + 3*r);
                    if (r < 4) {
                        float mx = fmaxf(a0, fmaxf(a1, a2));
                        float e0=expf(a0-mx), e1=expf(a1-mx), e2=expf(a2-mx);
                        float si = 1.0f/(e0+e1+e2);
                        modes[3*r]=e0*si; modes[3*r+1]=e1*si; modes[3*r+2]=e2*si;
                    }
                }
            }
            __syncthreads();

            // P3: key norms (waves 0-4) ∥ usage+uu (waves 6-7)
            if (wv < 4) {
                float v = keys[wv*NW + l];
                float s2 = wave_red(v*v);
                if (l == 0) nkey[wv] = sqrtf(s2);
            } else if (wv == 4) {
                float v = wkey[l];
                float s2 = wave_red(v*v);
                if (l == 0) sc[3] = sqrtf(s2);
            } else if (wv == 6 || wv == 7) {
                int m = tid - 384;
                float u = usg[m];
                u = u + (1.0f - u)*wwP[m];
                float psi = 1.0f;
                #pragma unroll
                for (int r = 0; r < NR; ++r) psi *= (1.0f - fgte[r]*rwC[r*NM+m]);
                u *= psi;
                usg[m] = u;
                uu[m] = 5e-6f + (1.0f - 5e-6f)*u;
            }
            __syncthreads();

            // P4: F1 write-content logits — f4 reads, 8 thr/row
            {
                const int m = tid >> 3, s = tid & 7;
                const f4* mem4 = (const f4*)(S + O_MEM);
                const f4* wk4  = (const f4*)(S + O_WK);
                f4 m0 = mem4[m*MS4 + s*2], m1 = mem4[m*MS4 + s*2 + 1];
                f4 k0 = wk4[s*2], k1 = wk4[s*2 + 1];
                float d = dot4(m0, k0) + dot4(m1, k1);
                d += __shfl_down(d, 4); d += __shfl_down(d, 2); d += __shfl_down(d, 1);
                if (s == 0) wcw[m] = d/(sc[3]*nmo[m] + EPSF) * sc[0];
            }
            __syncthreads();

            // P5: wcw softmax (wave 0) ∥ G2 rank (waves 8-15)
            if (tid < 64) {
                float w0 = wcw[l], w1 = wcw[l+64];
                float mx = fmaxf(w0, w1);
                #pragma unroll
                for (int o = 32; o > 0; o >>= 1) mx = fmaxf(mx, __shfl_down(mx, o));
                float M = __shfl(mx, 0);
                float e0 = expf(w0 - M), e1 = expf(w1 - M);
                float s = wave_red(e0 + e1);
                float inv = 1.0f/__shfl(s, 0);
                wcw[l] = e0*inv; wcw[l+64] = e1*inv;
            } else if (tid >= 512) {
                const int q = tid - 512, m = q >> 2, s = q & 3;
                const float um = uu[m];
                int rk = 0;
                #pragma unroll 8
                for (int k = 0; k < 32; ++k) {
                    int j = 4*k + s;
                    float uj = uu[j];
                    rk += (uj < um) || (uj == um && j < m);
                }
                rk += __shfl_down(rk, 1); rk += __shfl_down(rk, 2);
                if (s == 0) { rnk[m] = rk; su[rk] = um; }
            }
            __syncthreads();

            // P6: product scan (wave 0)
            if (tid < 64) {
                float a = su[tid], bb = su[64+tid];
                #pragma unroll
                for (int o = 1; o < 64; o <<= 1) {
                    float ta = __shfl_up(a, o);
                    float tb = __shfl_up(bb, o);
                    if (tid >= o) { a *= ta; bb *= tb; }
                }
                float P0 = __shfl(a, 63);
                cum[tid] = a;
                cum[64+tid] = P0*bb;
            }
            __syncthreads();

            // P7: alloc + wwC + per-wave alloc-sum partials
            if (tid < NM) {
                int rk = rnk[tid];
                float excl = (rk == 0) ? 1.0f : cum[rk-1];
                float al = (1.0f - uu[tid])*excl;
                wwC[tid] = sc[2]*(sc[1]*al + (1.0f - sc[1])*wcw[tid]);
                float sal = wave_red(al);
                if (l == 0) red[2 + wv] = sal;
            }
            __syncthreads();

            // P8: sc[4] analytic + mem erase/write + nmn via 8-thread f4 groups
            // (replaces 8 serial wave_reds with one 3-shfl reduce)
            if (tid == 1023)
                sc[4] = sc[2]*(sc[1]*(red[2]+red[3]) + (1.0f - sc[1]));
            #pragma unroll
            for (int ri = 0; ri < 8; ++ri) {
                int row = wv*8 + ri;
                float wm = wwC[row];
                float v = mem[row*MS + l];
                mem[row*MS + l] = v*(1.0f - wm*ers[l]) + wm*wvec[l];
            }
            {
                // same-wave norm: rows wv*8..wv*8+7 just written by THIS wave
                const int row = wv*8 + (l>>3);
                const f4* mem4 = (const f4*)(S + O_MEM);
                f4 m0 = mem4[row*MS4 + (l&7)*2];
                f4 m1 = mem4[row*MS4 + (l&7)*2 + 1];
                float s2 = dot4(m0,m0) + dot4(m1,m1);
                s2 += __shfl_down(s2, 4); s2 += __shfl_down(s2, 2);
                s2 += __shfl_down(s2, 1);
                if ((l & 7) == 0) nmn[row] = sqrtf(s2);
            }
            __syncthreads();

            // P9: I logits (waves 0-7, keys via broadcast b128)
            //     ∥ J row-scan + FUSED link update (waves 8-15)
            if (tid < 512) {
                const int m = tid >> 2, s = tid & 3;
                const f4* mem4 = (const f4*)(S + O_MEM);
                const f4* key4 = (const f4*)(S + O_KEY);
                float a0=0.f, a1=0.f, a2=0.f, a3=0.f;
                #pragma unroll
                for (int c = 0; c < 4; ++c) {
                    f4 mv = mem4[m*MS4 + s*4 + c];
                    f4 k0 = key4[0*16 + s*4 + c];   // broadcast (4 addrs/wave)
                    f4 k1 = key4[1*16 + s*4 + c];
                    f4 k2 = key4[2*16 + s*4 + c];
                    f4 k3 = key4[3*16 + s*4 + c];
                    a0 += dot4(mv, k0); a1 += dot4(mv, k1);
                    a2 += dot4(mv, k2); a3 += dot4(mv, k3);
                }
                a0 += __shfl_down(a0,1); a0 += __shfl_down(a0,2);
                a1 += __shfl_down(a1,1); a1 += __shfl_down(a1,2);
                a2 += __shfl_down(a2,1); a2 += __shfl_down(a2,2);
                a3 += __shfl_down(a3,1); a3 += __shfl_down(a3,2);
                if (s == 0) {
                    float nm = nmn[m];
                    ccw[0*NM+m] = a0/(nkey[0]*nm + EPSF)*rstr[0];
                    ccw[1*NM+m] = a1/(nkey[1]*nm + EPSF)*rstr[1];
                    ccw[2*NM+m] = a2/(nkey[2]*nm + EPSF)*rstr[2];
                    ccw[3*NM+m] = a3/(nkey[3]*nm + EPSF)*rstr[3];
                }
            } else {
                const int wj = wv - 8;          // 0..7: i-chunk of 16
                const int i0 = wj*16;
                const float wmA = wwC[l], wmB = wwC[64+l];   // row ww (lane-local)
                float fA0=0,fA1=0,fA2=0,fA3=0, fB0=0,fB1=0,fB2=0,fB3=0;
                #pragma unroll 4
                for (int ii = 0; ii < 16; ++ii) {
                    const int i = i0 + ii;
                    float pri = prc[i];          // broadcast
                    float wwi = wwC[i];          // broadcast
                    float r0 = rwC[0*NM+i];      // broadcast
                    float r1 = rwC[1*NM+i];
                    float r2 = rwC[2*NM+i];
                    float r3 = rwC[3*NM+i];
                    // row A: element (l, i) — update + use
                    float lrA = lk[l*LKS + i];
                    float nA = (i == l) ? 0.0f
                             : (1.0f - wmA - wwi)*lrA + wmA*pri;
                    lk[l*LKS + i] = nA;
                    // row B: element (l+64, i)
                    float lrB = lk[(l+64)*LKS + i];
                    float nB = (i == l+64) ? 0.0f
                             : (1.0f - wmB - wwi)*lrB + wmB*pri;
                    lk[(l+64)*LKS + i] = nB;
                    fA0 += nA*r0; fA1 += nA*r1; fA2 += nA*r2; fA3 += nA*r3;
                    fB0 += nB*r0; fB1 += nB*r1; fB2 += nB*r2; fB3 += nB*r3;
                }
                float* Pf = S + O_PF + wj*512;
                Pf[0*NM+l]=fA0; Pf[1*NM+l]=fA1; Pf[2*NM+l]=fA2; Pf[3*NM+l]=fA3;
                Pf[0*NM+64+l]=fB0; Pf[1*NM+64+l]=fB1;
                Pf[2*NM+64+l]=fB2; Pf[3*NM+64+l]=fB3;
            }
            __syncthreads();

            // P10: ccw softmax (waves 0-3) ∥ precedence (tid 256-383)
            //      ∥ J col-scan on NEW lk (waves 8-15)
            if (tid < 256) {
                float v0 = ccw[wv*NM + l], v1 = ccw[wv*NM + 64 + l];
                float mx = fmaxf(v0, v1);
                #pragma unroll
                for (int o = 32; o > 0; o >>= 1) mx = fmaxf(mx, __shfl_down(mx, o));
                float M = __shfl(mx, 0);
                float e0 = expf(v0 - M), e1 = expf(v1 - M);
                float s = wave_red(e0 + e1);
                float inv = 1.0f/__shfl(s, 0);
                ccw[wv*NM + l] = e0*inv; ccw[wv*NM + 64 + l] = e1*inv;
            } else if (tid < 384) {
                int m = tid - 256;
                prc[m] = (1.0f - sc[4])*prc[m] + wwC[m];
            } else if (wv >= 8) {
                const int wj = wv - 8;
                const int i0 = wj*16;
                float bA0=0,bA1=0,bA2=0,bA3=0, bB0=0,bB1=0,bB2=0,bB3=0;
                #pragma unroll 4
                for (int ii = 0; ii < 16; ++ii) {
                    const int i = i0 + ii;
                    float r0 = rwC[0*NM+i];      // broadcast
                    float r1 = rwC[1*NM+i];
                    float r2 = rwC[2*NM+i];
                    float r3 = rwC[3*NM+i];
                    float lcA = lk[i*LKS + l];       // col j=l (new lk)
                    float lcB = lk[i*LKS + 64 + l];  // col j=l+64
                    bA0 += lcA*r0; bA1 += lcA*r1; bA2 += lcA*r2; bA3 += lcA*r3;
                    bB0 += lcB*r0; bB1 += lcB*r1; bB2 += lcB*r2; bB3 += lcB*r3;
                }
                float* Pb = S + O_PB + wj*512;
                Pb[0*NM+l]=bA0; Pb[1*NM+l]=bA1; Pb[2*NM+l]=bA2; Pb[3*NM+l]=bA3;
                Pb[0*NM+64+l]=bB0; Pb[1*NM+64+l]=bB1;
                Pb[2*NM+64+l]=bB2; Pb[3*NM+64+l]=bB3;
            }
            __syncthreads();

            // P11: J-combine + mode mix -> rwN (new read weights, double-buffered)
            if (tid < 512) {
                const int r = tid >> 7, m = tid & 127;
                float fs = 0.0f, bs = 0.0f;
                #pragma unroll
                for (int c = 0; c < 8; ++c) {
                    fs += S[O_PF + c*512 + r*NM + m];
                    bs += S[O_PB + c*512 + r*NM + m];
                }
                rwN[r*NM + m] = modes[3*r]*bs + modes[3*r+1]*fs
                              + modes[3*r+2]*ccw[r*NM + m];
            }
            __syncthreads();

            // P12: K main (waves 0-7): lane=w, rwN via broadcast reads
            if (wv < 8) {
                const int m0 = wv*16;
                float a0=0.f, a1=0.f, a2=0.f, a3=0.f;
                #pragma unroll 4
                for (int mm = 0; mm < 16; ++mm) {
                    const int m = m0 + mm;
                    float rn0 = rwN[0*NM + m];   // broadcast
                    float rn1 = rwN[1*NM + m];
                    float rn2 = rwN[2*NM + m];
                    float rn3 = rwN[3*NM + m];
                    float mv = mem[m*MS + l];
                    a0 += rn0*mv; a1 += rn1*mv; a2 += rn2*mv; a3 += rn3*mv;
                }
                float* Pk = S + O_PK + wv*256;
                Pk[0*64+l]=a0; Pk[1*64+l]=a1; Pk[2*64+l]=a2; Pk[3*64+l]=a3;
            }
            __syncthreads();

            // P13: K reduce -> publish rv DIRECT to LLC (coalesced scalar stores)
            if (tid < 256) {
                const int r = tid >> 6, w = tid & 63;
                float s = 0.0f;
                #pragma unroll
                for (int c = 0; c < 8; ++c) s += S[O_PK + c*256 + r*64 + w];
                cstore1(&pubRV[(size_t)par*NBATCH*NR*NW + b*NR*NW + r*NW + w], s);
            }
            flag_set_d(&FLGD[D_R + b], (unsigned)(t+1), tid);
        }
    } else {
        // ===== GATES block: 4 units (16 gate rows) + LSTM + 4 xi + 4 out ====
        const int g = bid - 32;            // owns units u = 4g .. 4g+3
        const int gate = wv >> 2, j = wv & 3;
        const int r = gate*NH + 4*g + j;   // weight row: gate, unit 4g+j
        const f4* WA = (const f4*)(W_ih + (size_t)r*NI);
        f4 wx0 = WA[l], wx1 = WA[l+64], wrv = WA[128+l];
        const f4* WB = (const f4*)(W_hh + (size_t)r*NH);
        f4 wh0 = WB[l], wh1 = WB[l+64];
        const float bias = b_ih[r] + b_hh[r];
        float* accS = S + G_ACC;   // [32][17]
        float* cSg  = S + G_C;     // [32][5]
        float* hStg = S + G_H;     // [32][512] h(t-1) staging
        float* oH   = S + G_OH;    // [32][5] out H-part (hoisted into B slack)
        const int sbi = tid >> 7, sk4 = (tid & 127) << 2;

        if (tid < 160) cSg[tid] = 0.0f;
        for (int e = tid; e < NBATCH*NH; e += TPB) hStg[e] = 0.0f;  // h(-1)=0
        __syncthreads();

        for (int t = 0; t <= NT; ++t) {          // NT+1 iters (epilogue at NT)
            const int par = t & 1, parp = (t+1) & 1;   // parp = parity of t-1

            // A: stage ALL h(t-1); then xi(t-1) from our 8KB W_xi slice
            if (t >= 1) {
                multi_wait_d(&FLGD[D_G], 128, (unsigned)t, tid);   // h(t-1) all
                const float* hIn = pubH + (size_t)parp*NBATCH*NH;
                f4 a0, a1, a2, a3;
                cload4x4(hIn + tid*4, hIn + (tid+1024)*4,
                         hIn + (tid+2048)*4, hIn + (tid+3072)*4,
                         a0, a1, a2, a3);
                *(f4*)&hStg[tid*4]          = a0;
                *(f4*)&hStg[(tid+1024)*4]   = a1;
                *(f4*)&hStg[(tid+2048)*4]   = a2;
                *(f4*)&hStg[(tid+3072)*4]   = a3;
                __syncthreads();
                if (g < NXB) {
                    float* xOut = pubXI + (size_t)parp*NBATCH*480;
                    #pragma unroll
                    for (int bb = 0; bb < 2; ++bb) {
                        const int bi = 2*wv + bb;
                        const f4* H4 = (const f4*)(hStg + bi*512);
                        f4 res = {0.0f, 0.0f, 0.0f, 0.0f};
                        #pragma unroll
                        for (int jj = 0; jj < 4; ++jj) {
                            const int row = 4*g + jj;
                            if (row < NXI) {
                                const f4* WX = (const f4*)(W_xi + (size_t)row*NH);
                                float a = dot4(WX[l], H4[l])
                                        + dot4(WX[l+64], H4[l+64]);
                                a = wave_red(a);
                                res[jj] = a + b_xi[row];
                            }
                        }
                        if (l == 0) cstore4(&xOut[(size_t)bi*480 + 4*g], res);
                    }
                    flag_set_d(&FLGD[D_X + g], (unsigned)t, tid);
                }
            }

            // B: heavy phase x(t)·W_ih + h(t-1)·W_hh + out-H hoist (all in
            //    the slack under the state machinery)
            if (t < NT) {
                for (int p = 0; p < 4; ++p) {
                    const int b0 = p*8;
                    *(f4*)&S[sbi*512 + sk4] =
                        *(const f4*)&x[((size_t)(b0+sbi)*NT + t)*NH + sk4];
                    __syncthreads();
                    #pragma unroll
                    for (int bi = 0; bi < 8; ++bi) {
                        const f4* X4 = (const f4*)(S + bi*512);
                        const f4* H4 = (const f4*)(hStg + (b0+bi)*512);
                        float a = dot4(wx0, X4[l]) + dot4(wx1, X4[l+64])
                                + dot4(wh0, H4[l]) + dot4(wh1, H4[l+64]);
                        a = wave_red(a);
                        if (l == 0) accS[(b0+bi)*17 + wv] = a + bias;
                    }
                    __syncthreads();
                }
                // B-tail: out(t-1) H-part from hStg (= h(t-1)) — off-chain
                #pragma unroll
                for (int bb = 0; bb < 2; ++bb) {
                    const int bi = 2*wv + bb;
                    const f4* H4 = (const f4*)(hStg + bi*512);
                    #pragma unroll
                    for (int jj = 0; jj < 4; ++jj) {
                        const int row = 4*g + jj;
                        const f4* WO = (const f4*)(W_o + (size_t)row*NI);
                        float a = dot4(WO[l], H4[l]) + dot4(WO[l+64], H4[l+64]);
                        a = wave_red(a);
                        if (l == 0) oH[bi*5 + jj] = a;
                    }
                }
            }

            // C: rv(t-1) — the critical-path input
            {
                const int bi0 = tid >> 6, k40 = (tid & 63) << 2;
                if (t >= 1) {
                    multi_wait_d(&FLGD[D_R], 32, (unsigned)t, tid);
                    const float* rIn = pubRV + (size_t)parp*NBATCH*NR*NW;
                    f4 a0, a1;
                    cload4x2(&rIn[bi0*256 + k40], &rIn[(bi0+16)*256 + k40], a0, a1);
                    *(f4*)&S[bi0*256 + k40] = a0;
                    *(f4*)&S[(bi0+16)*256 + k40] = a1;
                } else {
                    f4 z = {0.0f, 0.0f, 0.0f, 0.0f};
                    *(f4*)&S[bi0*256 + k40] = z;
                    *(f4*)&S[(bi0+16)*256 + k40] = z;
                }
            }
            __syncthreads();

            // D: rv dot + LSTM + publish h(t)
            if (t < NT) {
                #pragma unroll
                for (int bi = 0; bi < 32; ++bi) {
                    const f4* RV4 = (const f4*)(S + bi*256);
                    float d = dot4(wrv, RV4[l]);
                    d = wave_red(d);
                    if (l == 0) accS[bi*17 + wv] += d;
                }
                __syncthreads();
                if (tid < 32) {
                    const int bi = tid;
                    const float* acc = accS + bi*17;
                    f4 hq;
                    #pragma unroll
                    for (int jj = 0; jj < 4; ++jj) {
                        float i_ = sigm(acc[0*4 + jj]);
                        float f_ = sigm(acc[1*4 + jj]);
                        float g_ = tanhf(acc[2*4 + jj]);
                        float o_ = sigm(acc[3*4 + jj]);
                        float c  = f_*cSg[bi*5 + jj] + i_*g_;
                        cSg[bi*5 + jj] = c;
                        hq[jj] = o_*tanhf(c);
                    }
                    cstore4(&pubH[(size_t)par*NBATCH*NH + (size_t)bi*NH + 4*g], hq);
                }
                flag_set_d(&FLGD[D_G + g], (unsigned)(t+1), tid);
            }

            // E: out(t-1) = hoisted H-part + rv-part (short on-chain segment)
            if (t >= 1) {
                #pragma unroll
                for (int bb = 0; bb < 2; ++bb) {
                    const int bi = 2*wv + bb;
                    const f4* H4 = (const f4*)(hStg + bi*512);
                    const f4* RV4 = (const f4*)(S + bi*256);
                    f4 res;
                    #pragma unroll
                    for (int jj = 0; jj < 4; ++jj) {
                        const int row = 4*g + jj;
                        const f4* WO = (const f4*)(W_o + (size_t)row*NI);
                        float a = dot4(WO[128+l], RV4[l]);
                        if (t == NT) {
                            // epilogue: B didn't run; hStg = h(NT-1), compute
                            a += dot4(WO[l], H4[l]) + dot4(WO[l+64], H4[l+64]);
                        }
                        a = wave_red(a);
                        if (l == 0) {
                            float hp = (t < NT) ? oH[bi*5 + jj] : 0.0f;
                            res[jj] = a + hp + b_o[row];
                        }
                    }
                    if (l == 0)
                        *(f4*)&out[((size_t)bi*NT + (t-1))*NH + 4*g] = res;
                }
            }
        }
    }
}

extern "C" void kernel_launch(void* const* d_in, const int* in_sizes, int n_in,
                              void* d_out, int out_size, void* d_ws, size_t ws_size,
                              hipStream_t stream) {
    (void)in_sizes; (void)n_in; (void)out_size; (void)ws_size;
    const float* x    = (const float*)d_in[0];
    const float* W_ih = (const float*)d_in[1];
    const float* W_hh = (const float*)d_in[2];
    const float* b_ih = (const float*)d_in[3];
    const float* b_hh = (const float*)d_in[4];
    const float* W_xi = (const float*)d_in[5];
    const float* b_xi = (const float*)d_in[6];
    const float* W_o  = (const float*)d_in[7];
    const float* b_o  = (const float*)d_in[8];
    float* out = (float*)d_out;
    float* ws  = (float*)d_ws;

    dnc_zero<<<1, 512, 0, stream>>>(ws);

    void* args[] = { (void*)&x, (void*)&W_ih, (void*)&W_hh, (void*)&b_ih,
                     (void*)&b_hh, (void*)&W_xi, (void*)&b_xi, (void*)&W_o,
                     (void*)&b_o, (void*)&out, (void*)&ws };
    hipLaunchCooperativeKernel((void*)dnc_pipe2, dim3(NBLK), dim3(TPB),
                               args, 0, stream);
}

// Round 11
// 2400.005 us; speedup vs baseline: 2.4414x; 1.0687x over previous
//
#include <hip/hip_runtime.h>
#include <math.h>

#define TPB 1024
#define NBLK 160
#define NBATCH 32
#define NT 64
#define NH 512
#define NM 128
#define NR 4
#define NW 64
#define NI 768          // controller input size (H + R*W)
#define NXI 471         // interface vector size
#define EPSF 1e-6f
#define MS 68           // mem row stride (f4-aligned, bank-audited)
#define MS4 17          // MS/4
#define LKS 129         // link row stride (odd: row+col b32 scans conflict-free)

// roles: [0,32) state (DNC machinery only) |
//        [32,160) gates blocks: 4 hidden units (16 gate rows) + LSTM cell
//                 + 4 xi rows + 4 out rows (distributed W_xi / W_o streams)

typedef float f4 __attribute__((ext_vector_type(4)));

// ws layout (float offsets). pub* parity double-buffered.
#define WS_PUBH  0                                 // [2][32][512] (gates)
#define WS_PUBRV (WS_PUBH + 2*NBATCH*NH)           // [2][32][256] (state)
#define WS_PUBXI (WS_PUBRV + 2*NBATCH*NR*NW)       // [2][32][480] (gates)
#define WS_FLAGS (WS_PUBXI + 2*NBATCH*480)
// packed flag dwords
#define D_G 0        // 128 gate blocks: h(t) published -> t+1
#define D_R 128      // 32 state blocks: rv(t) published -> t+1
#define D_X 160      // 118 gate blocks: xi(t-1) published -> t
#define D_TOTAL 288
#define NXB 118      // gate blocks that own xi rows (4*118 >= 471)

__device__ __forceinline__ float sigm(float x){ return 1.0f/(1.0f+expf(-x)); }
__device__ __forceinline__ float sftp(float x){ return fmaxf(x,0.0f)+log1pf(expf(-fabsf(x))); }
__device__ __forceinline__ float dot4(f4 a, f4 b){
    return a.x*b.x + a.y*b.y + a.z*b.z + a.w*b.w;
}
__device__ __forceinline__ float wave_red(float v){
    #pragma unroll
    for (int o = 32; o > 0; o >>= 1) v += __shfl_down(v, o);
    return v;
}
// wave-uniform extract on the VALU pipe (not LDS): v_readlane_b32
__device__ __forceinline__ float rdlane(float v, int lane){
    return __uint_as_float(__builtin_amdgcn_readlane(__float_as_uint(v), lane));
}

// ---- coherent (LLC write-through, device-visible) accessors: sc0 sc1 ----
__device__ __forceinline__ f4 cload4(const float* p){
    f4 v;
    asm volatile("global_load_dwordx4 %0, %1, off sc0 sc1\n\t"
                 "s_waitcnt vmcnt(0)"
                 : "=&v"(v) : "v"(p) : "memory");
    return v;
}
__device__ __forceinline__ float cload1f(const float* p){
    float v;
    asm volatile("global_load_dword %0, %1, off sc0 sc1\n\t"
                 "s_waitcnt vmcnt(0)"
                 : "=&v"(v) : "v"(p) : "memory");
    return v;
}
__device__ __forceinline__ void cload4x2(const float* p0, const float* p1,
                                         f4& a, f4& b){
    asm volatile("global_load_dwordx4 %0, %2, off sc0 sc1\n\t"
                 "global_load_dwordx4 %1, %3, off sc0 sc1\n\t"
                 "s_waitcnt vmcnt(0)"
                 : "=&v"(a), "=&v"(b) : "v"(p0), "v"(p1) : "memory");
}
__device__ __forceinline__ void cload4x4(const float* p0, const float* p1,
                                         const float* p2, const float* p3,
                                         f4& a, f4& b, f4& c, f4& d){
    asm volatile("global_load_dwordx4 %0, %4, off sc0 sc1\n\t"
                 "global_load_dwordx4 %1, %5, off sc0 sc1\n\t"
                 "global_load_dwordx4 %2, %6, off sc0 sc1\n\t"
                 "global_load_dwordx4 %3, %7, off sc0 sc1\n\t"
                 "s_waitcnt vmcnt(0)"
                 : "=&v"(a), "=&v"(b), "=&v"(c), "=&v"(d)
                 : "v"(p0), "v"(p1), "v"(p2), "v"(p3) : "memory");
}
__device__ __forceinline__ void cstore4(float* p, f4 v){
    asm volatile("global_store_dwordx4 %0, %1, off sc0 sc1"
                 :: "v"(p), "v"(v) : "memory");
}
__device__ __forceinline__ void cstore1(float* p, float v){
    asm volatile("global_store_dword %0, %1, off sc0 sc1"
                 :: "v"(p), "v"(v) : "memory");
}

// ---- packed-flag protocol ----
__device__ __forceinline__ void multi_wait_d(const unsigned int* f, int n,
                                             unsigned int tgt, int tid){
    if (tid < n) {
        const unsigned int* p = f + tid;
        while (__hip_atomic_load(p, __ATOMIC_RELAXED,
                                 __HIP_MEMORY_SCOPE_AGENT) < tgt)
            __builtin_amdgcn_s_sleep(2);
    }
    __syncthreads();
}
__device__ __forceinline__ void flag_set_d(unsigned int* f, unsigned int v, int tid){
    asm volatile("s_waitcnt vmcnt(0)" ::: "memory");
    __syncthreads();
    if (tid == 0)
        __hip_atomic_store(f, v, __ATOMIC_RELAXED, __HIP_MEMORY_SCOPE_AGENT);
}

__global__ void dnc_zero(float* ws){
    unsigned int* z = (unsigned int*)(ws + WS_FLAGS);
    for (int e = threadIdx.x; e < D_TOTAL; e += blockDim.x) z[e] = 0u;
}

// ---- pooled LDS (floats) ----
#define O_MEM 0         // 8704 (128 x 68)
#define O_RW2 8704      // 1024: rw double-buffered [2][4][128]
#define O_WW2 9728      // 256: ww double-buffered [2][128]
#define O_USG 9984      // 128
#define O_PRC 10112     // 128
#define O_KEY 10720     // 256
#define O_WK  10976     // 64
#define O_ER  11040     // 64
#define O_WV  11104     // 64
#define O_RS  11168     // 4
#define O_FG  11172     // 4
#define O_MD  11176     // 12
#define O_NK  11188     // 4
#define O_SC  11192     // 8
#define O_NRM 11200     // 2 x 128 double-buffered row norms
#define O_WCW 11456     // 128
#define O_UU  11584     // 128
#define O_SU  11712     // 128
#define O_CUM 11840     // 128
#define O_RNK 11968     // 128 (int)
#define O_CCW 12096     // 512
#define O_RED 12608     // 16
#define O_PF  12624     // 4096: J fwd partials [8][4][128]
#define O_PB  16720     // 4096: J bwd partials [8][4][128]
#define O_PK  12624     // 2048: K partials [8][4][64] (aliases PF; disjoint phases)
#define O_LK  20816     // 128*129 link matrix
#define S_SZ  (20816 + NM*LKS)     // 37328 floats = 149,312 B; 1 block/CU
// gates role (disjoint): rv staging stride 272 (2-way-max banks for D groups)
#define G_RVS 272       // rv staging stride in floats (17 f4)
#define G_ACC 8704      // [32][17]
#define G_C   9248      // [32][5]
#define G_H   9472      // [32][512] h(t-1) staging
#define G_OH  25856     // [32][5] out H-part partials (hoisted into B slack)

__global__ __launch_bounds__(TPB) void dnc_pipe2(
    const float* __restrict__ x, const float* __restrict__ W_ih,
    const float* __restrict__ W_hh, const float* __restrict__ b_ih,
    const float* __restrict__ b_hh, const float* __restrict__ W_xi,
    const float* __restrict__ b_xi, const float* __restrict__ W_o,
    const float* __restrict__ b_o, float* __restrict__ out,
    float* __restrict__ ws)
{
    __shared__ __align__(16) float S[S_SZ];

    const int tid = threadIdx.x;
    const int wv  = tid >> 6;
    const int l   = tid & 63;
    const int bid = blockIdx.x;

    float* __restrict__ pubH  = ws + WS_PUBH;
    float* __restrict__ pubRV = ws + WS_PUBRV;
    float* __restrict__ pubXI = ws + WS_PUBXI;
    unsigned int* __restrict__ FLGD = (unsigned int*)(ws + WS_FLAGS);

    if (bid < NBATCH) {
        // ========================= STATE block =========================
        const int b = bid;
        float* lk = S+O_LK;
        float* mem = S+O_MEM;
        float* usg = S+O_USG;  float* prc = S+O_PRC;
        float* keys = S+O_KEY; float* wkey = S+O_WK; float* ers = S+O_ER;
        float* wvec = S+O_WV;  float* rstr = S+O_RS; float* fgte = S+O_FG;
        float* modes = S+O_MD; float* nkey = S+O_NK; float* sc = S+O_SC;
        float* nrm = S+O_NRM;  float* wcw = S+O_WCW;
        float* uu = S+O_UU;    float* su = S+O_SU;   float* cum = S+O_CUM;
        int*   rnk = (int*)(S+O_RNK);
        float* ccw = S+O_CCW;  float* red = S+O_RED;

        for (int e = tid; e < NM*LKS; e += TPB) lk[e] = 0.0f;
        for (int e = tid; e < NM*NW; e += TPB) mem[(e>>6)*MS + (e&63)] = EPSF;
        for (int e = tid; e < 2*NR*NM; e += TPB) S[O_RW2+e]=0.0f;
        for (int e = tid; e < 2*NM; e += TPB) S[O_WW2+e]=0.0f;
        for (int e = tid; e < NM; e += TPB){ usg[e]=0.0f; prc[e]=0.0f; }
        for (int e = tid; e < 2*NM; e += TPB) nrm[e] = 8.0f*EPSF; // ||EPS row||
        __syncthreads();

        for (int t = 0; t < NT; ++t) {
            const int par = t & 1;
            float* nmo = nrm + 128*par;            // old norms = prev step's new
            float* nmn = nrm + 128*(par^1);
            float* rwC = S + O_RW2 + 512*par;      // rw(t-1)
            float* rwN = S + O_RW2 + 512*(par^1);  // rw(t) written this step
            float* wwP = S + O_WW2 + 128*(par^1);  // ww(t-1)
            float* wwC = S + O_WW2 + 128*par;      // ww(t) written this step

            // P1+P2 fused: xi(t) ready; DIRECT coherent loads into unpack
            multi_wait_d(&FLGD[D_X], NXB, (unsigned)(t+1), tid);
            {
                const float* xb = pubXI + (size_t)par*NBATCH*480 + b*480;
                if (tid < 256)       keys[tid] = tanhf(cload1f(xb+tid));
                else if (tid < 260)  rstr[tid-256] = sftp(cload1f(xb+tid));
                else if (tid < 324)  wkey[tid-260] = tanhf(cload1f(xb+tid));
                else if (tid == 324) sc[0] = sftp(cload1f(xb+324));
                else if (tid < 389)  ers[tid-325] = sigm(cload1f(xb+tid));
                else if (tid < 453)  wvec[tid-389] = tanhf(cload1f(xb+tid));
                else if (tid < 457)  fgte[tid-453] = sigm(cload1f(xb+tid));
                else if (tid == 457) sc[1] = sigm(cload1f(xb+457));
                else if (tid == 458) sc[2] = sigm(cload1f(xb+458));
                else if (tid < 471) {
                    // tid 459..470 = wave 7 lanes 11..22 (all active here)
                    float xv = cload1f(xb + tid);
                    int r = tid - 459;             // 0..11
                    float a0 = __shfl(xv, 11 + 3*r);
                    float a1 = __shfl(xv, 12 + 3*r);
                    float a2 = __shfl(xv, 13 + 3*r);
                    if (r < 4) {
                        float mx = fmaxf(a0, fmaxf(a1, a2));
                        float e0=expf(a0-mx), e1=expf(a1-mx), e2=expf(a2-mx);
                        float si = 1.0f/(e0+e1+e2);
                        modes[3*r]=e0*si; modes[3*r+1]=e1*si; modes[3*r+2]=e2*si;
                    }
                }
            }
            __syncthreads();

            // P3: key norms (waves 0-4) ∥ usage+uu (waves 6-7)
            if (wv < 4) {
                float v = keys[wv*NW + l];
                float s2 = wave_red(v*v);
                if (l == 0) nkey[wv] = sqrtf(s2);
            } else if (wv == 4) {
                float v = wkey[l];
                float s2 = wave_red(v*v);
                if (l == 0) sc[3] = sqrtf(s2);
            } else if (wv == 6 || wv == 7) {
                int m = tid - 384;
                float u = usg[m];
                u = u + (1.0f - u)*wwP[m];
                float psi = 1.0f;
                #pragma unroll
                for (int r = 0; r < NR; ++r) psi *= (1.0f - fgte[r]*rwC[r*NM+m]);
                u *= psi;
                usg[m] = u;
                uu[m] = 5e-6f + (1.0f - 5e-6f)*u;
            }
            __syncthreads();

            // P4: F1 write-content logits — f4 reads, 8 thr/row
            {
                const int m = tid >> 3, s = tid & 7;
                const f4* mem4 = (const f4*)(S + O_MEM);
                const f4* wk4  = (const f4*)(S + O_WK);
                f4 m0 = mem4[m*MS4 + s*2], m1 = mem4[m*MS4 + s*2 + 1];
                f4 k0 = wk4[s*2], k1 = wk4[s*2 + 1];
                float d = dot4(m0, k0) + dot4(m1, k1);
                d += __shfl_down(d, 4); d += __shfl_down(d, 2); d += __shfl_down(d, 1);
                if (s == 0) wcw[m] = d/(sc[3]*nmo[m] + EPSF) * sc[0];
            }
            __syncthreads();

            // P5: wcw softmax (wave 0) ∥ G2 rank (waves 8-15)
            if (tid < 64) {
                float w0 = wcw[l], w1 = wcw[l+64];
                float mx = fmaxf(w0, w1);
                #pragma unroll
                for (int o = 32; o > 0; o >>= 1) mx = fmaxf(mx, __shfl_down(mx, o));
                float M = __shfl(mx, 0);
                float e0 = expf(w0 - M), e1 = expf(w1 - M);
                float s = wave_red(e0 + e1);
                float inv = 1.0f/__shfl(s, 0);
                wcw[l] = e0*inv; wcw[l+64] = e1*inv;
            } else if (tid >= 512) {
                const int q = tid - 512, m = q >> 2, s = q & 3;
                const float um = uu[m];
                int rk = 0;
                #pragma unroll 8
                for (int k = 0; k < 32; ++k) {
                    int j = 4*k + s;
                    float uj = uu[j];
                    rk += (uj < um) || (uj == um && j < m);
                }
                rk += __shfl_down(rk, 1); rk += __shfl_down(rk, 2);
                if (s == 0) { rnk[m] = rk; su[rk] = um; }
            }
            __syncthreads();

            // P6: product scan (wave 0)
            if (tid < 64) {
                float a = su[tid], bb = su[64+tid];
                #pragma unroll
                for (int o = 1; o < 64; o <<= 1) {
                    float ta = __shfl_up(a, o);
                    float tb = __shfl_up(bb, o);
                    if (tid >= o) { a *= ta; bb *= tb; }
                }
                float P0 = __shfl(a, 63);
                cum[tid] = a;
                cum[64+tid] = P0*bb;
            }
            __syncthreads();

            // P7: alloc + wwC + per-wave alloc-sum partials
            if (tid < NM) {
                int rk = rnk[tid];
                float excl = (rk == 0) ? 1.0f : cum[rk-1];
                float al = (1.0f - uu[tid])*excl;
                wwC[tid] = sc[2]*(sc[1]*al + (1.0f - sc[1])*wcw[tid]);
                float sal = wave_red(al);
                if (l == 0) red[2 + wv] = sal;
            }
            __syncthreads();

            // P8: sc[4] analytic + mem erase/write + nmn via 8-thread f4 groups
            if (tid == 1023)
                sc[4] = sc[2]*(sc[1]*(red[2]+red[3]) + (1.0f - sc[1]));
            #pragma unroll
            for (int ri = 0; ri < 8; ++ri) {
                int row = wv*8 + ri;
                float wm = wwC[row];
                float v = mem[row*MS + l];
                mem[row*MS + l] = v*(1.0f - wm*ers[l]) + wm*wvec[l];
            }
            {
                // same-wave norm: rows wv*8..wv*8+7 just written by THIS wave
                const int row = wv*8 + (l>>3);
                const f4* mem4 = (const f4*)(S + O_MEM);
                f4 m0 = mem4[row*MS4 + (l&7)*2];
                f4 m1 = mem4[row*MS4 + (l&7)*2 + 1];
                float s2 = dot4(m0,m0) + dot4(m1,m1);
                s2 += __shfl_down(s2, 4); s2 += __shfl_down(s2, 2);
                s2 += __shfl_down(s2, 1);
                if ((l & 7) == 0) nmn[row] = sqrtf(s2);
            }
            __syncthreads();

            // P9: I logits (waves 0-7, keys via broadcast b128)
            //     ∥ J row-scan + FUSED link update (waves 8-15, readlane-fed)
            if (tid < 512) {
                const int m = tid >> 2, s = tid & 3;
                const f4* mem4 = (const f4*)(S + O_MEM);
                const f4* key4 = (const f4*)(S + O_KEY);
                float a0=0.f, a1=0.f, a2=0.f, a3=0.f;
                #pragma unroll
                for (int c = 0; c < 4; ++c) {
                    f4 mv = mem4[m*MS4 + s*4 + c];
                    f4 k0 = key4[0*16 + s*4 + c];   // broadcast (4 addrs/wave)
                    f4 k1 = key4[1*16 + s*4 + c];
                    f4 k2 = key4[2*16 + s*4 + c];
                    f4 k3 = key4[3*16 + s*4 + c];
                    a0 += dot4(mv, k0); a1 += dot4(mv, k1);
                    a2 += dot4(mv, k2); a3 += dot4(mv, k3);
                }
                a0 += __shfl_down(a0,1); a0 += __shfl_down(a0,2);
                a1 += __shfl_down(a1,1); a1 += __shfl_down(a1,2);
                a2 += __shfl_down(a2,1); a2 += __shfl_down(a2,2);
                a3 += __shfl_down(a3,1); a3 += __shfl_down(a3,2);
                if (s == 0) {
                    float nm = nmn[m];
                    ccw[0*NM+m] = a0/(nkey[0]*nm + EPSF)*rstr[0];
                    ccw[1*NM+m] = a1/(nkey[1]*nm + EPSF)*rstr[1];
                    ccw[2*NM+m] = a2/(nkey[2]*nm + EPSF)*rstr[2];
                    ccw[3*NM+m] = a3/(nkey[3]*nm + EPSF)*rstr[3];
                }
            } else {
                const int wj = wv - 8;          // 0..7: i-chunk of 16
                const int i0 = wj*16;
                const float wmA = wwC[l], wmB = wwC[64+l];   // lane-local
                // per-wave preloads: lanes hold the 16-chunk of rw/prc/ww
                float srw  = rwC[(l>>4)*NM + i0 + (l&15)];
                float sprc = prc[i0 + (l&15)];
                float swwc = wwC[i0 + (l&15)];
                float fA0=0,fA1=0,fA2=0,fA3=0, fB0=0,fB1=0,fB2=0,fB3=0;
                #pragma unroll
                for (int ii = 0; ii < 16; ++ii) {
                    const int i = i0 + ii;
                    float pri = rdlane(sprc, ii);
                    float wwi = rdlane(swwc, ii);
                    float r0 = rdlane(srw, ii);
                    float r1 = rdlane(srw, 16+ii);
                    float r2 = rdlane(srw, 32+ii);
                    float r3 = rdlane(srw, 48+ii);
                    // row A: element (l, i) — update + use
                    float lrA = lk[l*LKS + i];
                    float nA = (i == l) ? 0.0f
                             : (1.0f - wmA - wwi)*lrA + wmA*pri;
                    lk[l*LKS + i] = nA;
                    // row B: element (l+64, i)
                    float lrB = lk[(l+64)*LKS + i];
                    float nB = (i == l+64) ? 0.0f
                             : (1.0f - wmB - wwi)*lrB + wmB*pri;
                    lk[(l+64)*LKS + i] = nB;
                    fA0 += nA*r0; fA1 += nA*r1; fA2 += nA*r2; fA3 += nA*r3;
                    fB0 += nB*r0; fB1 += nB*r1; fB2 += nB*r2; fB3 += nB*r3;
                }
                float* Pf = S + O_PF + wj*512;
                Pf[0*NM+l]=fA0; Pf[1*NM+l]=fA1; Pf[2*NM+l]=fA2; Pf[3*NM+l]=fA3;
                Pf[0*NM+64+l]=fB0; Pf[1*NM+64+l]=fB1;
                Pf[2*NM+64+l]=fB2; Pf[3*NM+64+l]=fB3;
            }
            __syncthreads();

            // P10: ccw softmax (waves 0-3) ∥ precedence (tid 256-383)
            //      ∥ J col-scan on NEW lk (waves 8-15, readlane-fed)
            if (tid < 256) {
                float v0 = ccw[wv*NM + l], v1 = ccw[wv*NM + 64 + l];
                float mx = fmaxf(v0, v1);
                #pragma unroll
                for (int o = 32; o > 0; o >>= 1) mx = fmaxf(mx, __shfl_down(mx, o));
                float M = __shfl(mx, 0);
                float e0 = expf(v0 - M), e1 = expf(v1 - M);
                float s = wave_red(e0 + e1);
                float inv = 1.0f/__shfl(s, 0);
                ccw[wv*NM + l] = e0*inv; ccw[wv*NM + 64 + l] = e1*inv;
            } else if (tid < 384) {
                int m = tid - 256;
                prc[m] = (1.0f - sc[4])*prc[m] + wwC[m];
            } else if (wv >= 8) {
                const int wj = wv - 8;
                const int i0 = wj*16;
                float srw = rwC[(l>>4)*NM + i0 + (l&15)];
                float bA0=0,bA1=0,bA2=0,bA3=0, bB0=0,bB1=0,bB2=0,bB3=0;
                #pragma unroll
                for (int ii = 0; ii < 16; ++ii) {
                    const int i = i0 + ii;
                    float r0 = rdlane(srw, ii);
                    float r1 = rdlane(srw, 16+ii);
                    float r2 = rdlane(srw, 32+ii);
                    float r3 = rdlane(srw, 48+ii);
                    float lcA = lk[i*LKS + l];       // col j=l (new lk)
                    float lcB = lk[i*LKS + 64 + l];  // col j=l+64
                    bA0 += lcA*r0; bA1 += lcA*r1; bA2 += lcA*r2; bA3 += lcA*r3;
                    bB0 += lcB*r0; bB1 += lcB*r1; bB2 += lcB*r2; bB3 += lcB*r3;
                }
                float* Pb = S + O_PB + wj*512;
                Pb[0*NM+l]=bA0; Pb[1*NM+l]=bA1; Pb[2*NM+l]=bA2; Pb[3*NM+l]=bA3;
                Pb[0*NM+64+l]=bB0; Pb[1*NM+64+l]=bB1;
                Pb[2*NM+64+l]=bB2; Pb[3*NM+64+l]=bB3;
            }
            __syncthreads();

            // P11: J-combine + mode mix -> rwN (new read weights, double-buffered)
            if (tid < 512) {
                const int r = tid >> 7, m = tid & 127;
                float fs = 0.0f, bs = 0.0f;
                #pragma unroll
                for (int c = 0; c < 8; ++c) {
                    fs += S[O_PF + c*512 + r*NM + m];
                    bs += S[O_PB + c*512 + r*NM + m];
                }
                rwN[r*NM + m] = modes[3*r]*bs + modes[3*r+1]*fs
                              + modes[3*r+2]*ccw[r*NM + m];
            }
            __syncthreads();

            // P12: K main (waves 0-7): lane=w, rwN via readlane
            if (wv < 8) {
                const int m0 = wv*16;
                float srn = rwN[(l>>4)*NM + m0 + (l&15)];
                float a0=0.f, a1=0.f, a2=0.f, a3=0.f;
                #pragma unroll
                for (int mm = 0; mm < 16; ++mm) {
                    const int m = m0 + mm;
                    float rn0 = rdlane(srn, mm);
                    float rn1 = rdlane(srn, 16+mm);
                    float rn2 = rdlane(srn, 32+mm);
                    float rn3 = rdlane(srn, 48+mm);
                    float mv = mem[m*MS + l];
                    a0 += rn0*mv; a1 += rn1*mv; a2 += rn2*mv; a3 += rn3*mv;
                }
                float* Pk = S + O_PK + wv*256;
                Pk[0*64+l]=a0; Pk[1*64+l]=a1; Pk[2*64+l]=a2; Pk[3*64+l]=a3;
            }
            __syncthreads();

            // P13: K reduce -> publish rv DIRECT to LLC (coalesced scalar stores)
            if (tid < 256) {
                const int r = tid >> 6, w = tid & 63;
                float s = 0.0f;
                #pragma unroll
                for (int c = 0; c < 8; ++c) s += S[O_PK + c*256 + r*64 + w];
                cstore1(&pubRV[(size_t)par*NBATCH*NR*NW + b*NR*NW + r*NW + w], s);
            }
            flag_set_d(&FLGD[D_R + b], (unsigned)(t+1), tid);
        }
    } else {
        // ===== GATES block: 4 units (16 gate rows) + LSTM + 4 xi + 4 out ====
        const int g = bid - 32;            // owns units u = 4g .. 4g+3
        const int gate = wv >> 2, j = wv & 3;
        const int r = gate*NH + 4*g + j;   // weight row: gate, unit 4g+j
        const f4* WA = (const f4*)(W_ih + (size_t)r*NI);
        f4 wx0 = WA[l], wx1 = WA[l+64];
        const int qv = l & 15;             // lane-in-group for D's 16-lane dots
        f4 wrv0 = WA[128 + qv*4],     wrv1 = WA[128 + qv*4 + 1],
           wrv2 = WA[128 + qv*4 + 2], wrv3 = WA[128 + qv*4 + 3];
        const f4* WB = (const f4*)(W_hh + (size_t)r*NH);
        f4 wh0 = WB[l], wh1 = WB[l+64];
        const float bias = b_ih[r] + b_hh[r];
        float* accS = S + G_ACC;   // [32][17]
        float* cSg  = S + G_C;     // [32][5]
        float* hStg = S + G_H;     // [32][512] h(t-1) staging
        float* oH   = S + G_OH;    // [32][5] out H-part (hoisted into B slack)
        const int sbi = tid >> 7, sk4 = (tid & 127) << 2;

        if (tid < 160) cSg[tid] = 0.0f;
        for (int e = tid; e < NBATCH*NH; e += TPB) hStg[e] = 0.0f;  // h(-1)=0
        __syncthreads();

        for (int t = 0; t <= NT; ++t) {          // NT+1 iters (epilogue at NT)
            const int par = t & 1, parp = (t+1) & 1;   // parp = parity of t-1

            // A: stage ALL h(t-1); then xi(t-1) from our 8KB W_xi slice
            if (t >= 1) {
                multi_wait_d(&FLGD[D_G], 128, (unsigned)t, tid);   // h(t-1) all
                const float* hIn = pubH + (size_t)parp*NBATCH*NH;
                f4 a0, a1, a2, a3;
                cload4x4(hIn + tid*4, hIn + (tid+1024)*4,
                         hIn + (tid+2048)*4, hIn + (tid+3072)*4,
                         a0, a1, a2, a3);
                *(f4*)&hStg[tid*4]          = a0;
                *(f4*)&hStg[(tid+1024)*4]   = a1;
                *(f4*)&hStg[(tid+2048)*4]   = a2;
                *(f4*)&hStg[(tid+3072)*4]   = a3;
                __syncthreads();
                if (g < NXB) {
                    float* xOut = pubXI + (size_t)parp*NBATCH*480;
                    #pragma unroll
                    for (int bb = 0; bb < 2; ++bb) {
                        const int bi = 2*wv + bb;
                        const f4* H4 = (const f4*)(hStg + bi*512);
                        f4 res = {0.0f, 0.0f, 0.0f, 0.0f};
                        #pragma unroll
                        for (int jj = 0; jj < 4; ++jj) {
                            const int row = 4*g + jj;
                            if (row < NXI) {
                                const f4* WX = (const f4*)(W_xi + (size_t)row*NH);
                                float a = dot4(WX[l], H4[l])
                                        + dot4(WX[l+64], H4[l+64]);
                                a = wave_red(a);
                                res[jj] = a + b_xi[row];
                            }
                        }
                        if (l == 0) cstore4(&xOut[(size_t)bi*480 + 4*g], res);
                    }
                    flag_set_d(&FLGD[D_X + g], (unsigned)t, tid);
                }
            }

            // B: heavy phase x(t)·W_ih + h(t-1)·W_hh + out-H hoist (slack)
            if (t < NT) {
                for (int p = 0; p < 4; ++p) {
                    const int b0 = p*8;
                    *(f4*)&S[sbi*512 + sk4] =
                        *(const f4*)&x[((size_t)(b0+sbi)*NT + t)*NH + sk4];
                    __syncthreads();
                    #pragma unroll
                    for (int bi = 0; bi < 8; ++bi) {
                        const f4* X4 = (const f4*)(S + bi*512);
                        const f4* H4 = (const f4*)(hStg + (b0+bi)*512);
                        float a = dot4(wx0, X4[l]) + dot4(wx1, X4[l+64])
                                + dot4(wh0, H4[l]) + dot4(wh1, H4[l+64]);
                        a = wave_red(a);
                        if (l == 0) accS[(b0+bi)*17 + wv] = a + bias;
                    }
                    __syncthreads();
                }
                // B-tail: out(t-1) H-part from hStg (= h(t-1)) — off-chain
                #pragma unroll
                for (int bb = 0; bb < 2; ++bb) {
                    const int bi = 2*wv + bb;
                    const f4* H4 = (const f4*)(hStg + bi*512);
                    #pragma unroll
                    for (int jj = 0; jj < 4; ++jj) {
                        const int row = 4*g + jj;
                        const f4* WO = (const f4*)(W_o + (size_t)row*NI);
                        float a = dot4(WO[l], H4[l]) + dot4(WO[l+64], H4[l+64]);
                        a = wave_red(a);
                        if (l == 0) oH[bi*5 + jj] = a;
                    }
                }
            }

            // C: rv(t-1) — the critical-path input (staged at stride 272)
            {
                const int bi0 = tid >> 6, k40 = (tid & 63) << 2;
                if (t >= 1) {
                    multi_wait_d(&FLGD[D_R], 32, (unsigned)t, tid);
                    const float* rIn = pubRV + (size_t)parp*NBATCH*NR*NW;
                    f4 a0, a1;
                    cload4x2(&rIn[bi0*256 + k40], &rIn[(bi0+16)*256 + k40], a0, a1);
                    *(f4*)&S[bi0*G_RVS + k40] = a0;
                    *(f4*)&S[(bi0+16)*G_RVS + k40] = a1;
                } else {
                    f4 z = {0.0f, 0.0f, 0.0f, 0.0f};
                    *(f4*)&S[bi0*G_RVS + k40] = z;
                    *(f4*)&S[(bi0+16)*G_RVS + k40] = z;
                }
            }
            __syncthreads();

            // D: rv dot in 16-lane groups (4 batches/pass) + LSTM + publish h(t)
            if (t < NT) {
                const int grp = l >> 4;
                #pragma unroll
                for (int p = 0; p < 8; ++p) {
                    const int bi = p*4 + grp;
                    const f4* RV4 = (const f4*)(S + bi*G_RVS);
                    float d = dot4(wrv0, RV4[qv*4])   + dot4(wrv1, RV4[qv*4+1])
                            + dot4(wrv2, RV4[qv*4+2]) + dot4(wrv3, RV4[qv*4+3]);
                    d += __shfl_down(d, 8); d += __shfl_down(d, 4);
                    d += __shfl_down(d, 2); d += __shfl_down(d, 1);
                    if (qv == 0) accS[bi*17 + wv] += d;
                }
                __syncthreads();
                if (tid < 32) {
                    const int bi = tid;
                    const float* acc = accS + bi*17;
                    f4 hq;
                    #pragma unroll
                    for (int jj = 0; jj < 4; ++jj) {
                        float i_ = sigm(acc[0*4 + jj]);
                        float f_ = sigm(acc[1*4 + jj]);
                        float g_ = tanhf(acc[2*4 + jj]);
                        float o_ = sigm(acc[3*4 + jj]);
                        float c  = f_*cSg[bi*5 + jj] + i_*g_;
                        cSg[bi*5 + jj] = c;
                        hq[jj] = o_*tanhf(c);
                    }
                    cstore4(&pubH[(size_t)par*NBATCH*NH + (size_t)bi*NH + 4*g], hq);
                }
                flag_set_d(&FLGD[D_G + g], (unsigned)(t+1), tid);
            }

            // E: out(t-1) = hoisted H-part + rv-part (short on-chain segment)
            if (t >= 1) {
                #pragma unroll
                for (int bb = 0; bb < 2; ++bb) {
                    const int bi = 2*wv + bb;
                    const f4* H4 = (const f4*)(hStg + bi*512);
                    const f4* RV4 = (const f4*)(S + bi*G_RVS);
                    f4 res;
                    #pragma unroll
                    for (int jj = 0; jj < 4; ++jj) {
                        const int row = 4*g + jj;
                        const f4* WO = (const f4*)(W_o + (size_t)row*NI);
                        float a = dot4(WO[128+l], RV4[l]);
                        if (t == NT) {
                            // epilogue: B didn't run; hStg = h(NT-1), compute
                            a += dot4(WO[l], H4[l]) + dot4(WO[l+64], H4[l+64]);
                        }
                        a = wave_red(a);
                        if (l == 0) {
                            float hp = (t < NT) ? oH[bi*5 + jj] : 0.0f;
                            res[jj] = a + hp + b_o[row];
                        }
                    }
                    if (l == 0)
                        *(f4*)&out[((size_t)bi*NT + (t-1))*NH + 4*g] = res;
                }
            }
        }
    }
}

extern "C" void kernel_launch(void* const* d_in, const int* in_sizes, int n_in,
                              void* d_out, int out_size, void* d_ws, size_t ws_size,
                              hipStream_t stream) {
    (void)in_sizes; (void)n_in; (void)out_size; (void)ws_size;
    const float* x    = (const float*)d_in[0];
    const float* W_ih = (const float*)d_in[1];
    const float* W_hh = (const float*)d_in[2];
    const float* b_ih = (const float*)d_in[3];
    const float* b_hh = (const float*)d_in[4];
    const float* W_xi = (const float*)d_in[5];
    const float* b_xi = (const float*)d_in[6];
    const float* W_o  = (const float*)d_in[7];
    const float* b_o  = (const float*)d_in[8];
    float* out = (float*)d_out;
    float* ws  = (float*)d_ws;

    dnc_zero<<<1, 512, 0, stream>>>(ws);

    void* args[] = { (void*)&x, (void*)&W_ih, (void*)&W_hh, (void*)&b_ih,
                     (void*)&b_hh, (void*)&W_xi, (void*)&b_xi, (void*)&W_o,
                     (void*)&b_o, (void*)&out, (void*)&ws };
    hipLaunchCooperativeKernel((void*)dnc_pipe2, dim3(NBLK), dim3(TPB),
                               args, 0, stream);
}

// Round 12
// 2167.749 us; speedup vs baseline: 2.7030x; 1.1071x over previous
//
#include <hip/hip_runtime.h>
#include <math.h>

#define TPB 1024
#define NBLK 160
#define NBATCH 32
#define NT 64
#define NH 512
#define NM 128
#define NR 4
#define NW 64
#define NI 768          // controller input size (H + R*W)
#define NXI 471         // interface vector size
#define EPSF 1e-6f
#define MS 68           // mem row stride (f4-aligned, bank-audited)
#define MS4 17          // MS/4
#define LKS 129         // link row stride (odd: row+col b32 scans conflict-free)

// roles: [0,32) state (DNC machinery only) |
//        [32,160) gates blocks: 4 hidden units (16 gate rows) + LSTM cell
//                 + 4 xi rows + 4 out rows (distributed W_xi / W_o streams)

typedef float f4 __attribute__((ext_vector_type(4)));

// ws layout (float offsets). pub* parity double-buffered.
#define WS_PUBH  0                                 // [2][32][512] (gates)
#define WS_PUBRV (WS_PUBH + 2*NBATCH*NH)           // [2][32][256] (state)
#define WS_PUBXI (WS_PUBRV + 2*NBATCH*NR*NW)       // [2][32][480] (gates)
#define WS_FLAGS (WS_PUBXI + 2*NBATCH*480)
// packed flag dwords
#define D_G 0        // 128 gate blocks: h(t) published -> t+1
#define D_R 128      // 32 state blocks: rv(t) published -> t+1
#define D_X 160      // 118 gate blocks: xi(t-1) published -> t
#define D_TOTAL 288
#define NXB 118      // gate blocks that own xi rows (4*118 >= 471)

__device__ __forceinline__ float sigm(float x){ return 1.0f/(1.0f+expf(-x)); }
__device__ __forceinline__ float sftp(float x){ return fmaxf(x,0.0f)+log1pf(expf(-fabsf(x))); }
__device__ __forceinline__ float dot4(f4 a, f4 b){
    return a.x*b.x + a.y*b.y + a.z*b.z + a.w*b.w;
}
__device__ __forceinline__ float wave_red(float v){
    #pragma unroll
    for (int o = 32; o > 0; o >>= 1) v += __shfl_down(v, o);
    return v;
}
// wave-uniform extract on the VALU pipe (not LDS): v_readlane_b32
__device__ __forceinline__ float rdlane(float v, int lane){
    return __uint_as_float(__builtin_amdgcn_readlane(__float_as_uint(v), lane));
}

// ---- coherent (LLC write-through, device-visible) accessors: sc0 sc1 ----
__device__ __forceinline__ f4 cload4(const float* p){
    f4 v;
    asm volatile("global_load_dwordx4 %0, %1, off sc0 sc1\n\t"
                 "s_waitcnt vmcnt(0)"
                 : "=&v"(v) : "v"(p) : "memory");
    return v;
}
__device__ __forceinline__ float cload1f(const float* p){
    float v;
    asm volatile("global_load_dword %0, %1, off sc0 sc1\n\t"
                 "s_waitcnt vmcnt(0)"
                 : "=&v"(v) : "v"(p) : "memory");
    return v;
}
__device__ __forceinline__ void cload4x2(const float* p0, const float* p1,
                                         f4& a, f4& b){
    asm volatile("global_load_dwordx4 %0, %2, off sc0 sc1\n\t"
                 "global_load_dwordx4 %1, %3, off sc0 sc1\n\t"
                 "s_waitcnt vmcnt(0)"
                 : "=&v"(a), "=&v"(b) : "v"(p0), "v"(p1) : "memory");
}
__device__ __forceinline__ void cload4x4(const float* p0, const float* p1,
                                         const float* p2, const float* p3,
                                         f4& a, f4& b, f4& c, f4& d){
    asm volatile("global_load_dwordx4 %0, %4, off sc0 sc1\n\t"
                 "global_load_dwordx4 %1, %5, off sc0 sc1\n\t"
                 "global_load_dwordx4 %2, %6, off sc0 sc1\n\t"
                 "global_load_dwordx4 %3, %7, off sc0 sc1\n\t"
                 "s_waitcnt vmcnt(0)"
                 : "=&v"(a), "=&v"(b), "=&v"(c), "=&v"(d)
                 : "v"(p0), "v"(p1), "v"(p2), "v"(p3) : "memory");
}
__device__ __forceinline__ void cstore4(float* p, f4 v){
    asm volatile("global_store_dwordx4 %0, %1, off sc0 sc1"
                 :: "v"(p), "v"(v) : "memory");
}
__device__ __forceinline__ void cstore1(float* p, float v){
    asm volatile("global_store_dword %0, %1, off sc0 sc1"
                 :: "v"(p), "v"(v) : "memory");
}

// ---- packed-flag protocol ----
__device__ __forceinline__ void multi_wait_d(const unsigned int* f, int n,
                                             unsigned int tgt, int tid){
    if (tid < n) {
        const unsigned int* p = f + tid;
        while (__hip_atomic_load(p, __ATOMIC_RELAXED,
                                 __HIP_MEMORY_SCOPE_AGENT) < tgt)
            __builtin_amdgcn_s_sleep(2);
    }
    __syncthreads();
}
__device__ __forceinline__ void flag_set_d(unsigned int* f, unsigned int v, int tid){
    asm volatile("s_waitcnt vmcnt(0)" ::: "memory");
    __syncthreads();
    if (tid == 0)
        __hip_atomic_store(f, v, __ATOMIC_RELAXED, __HIP_MEMORY_SCOPE_AGENT);
}

__global__ void dnc_zero(float* ws){
    unsigned int* z = (unsigned int*)(ws + WS_FLAGS);
    for (int e = threadIdx.x; e < D_TOTAL; e += blockDim.x) z[e] = 0u;
}

// ---- pooled LDS (floats) ----
#define O_MEM 0         // 8704 (128 x 68)
#define O_RW2 8704      // 1024: rw double-buffered [2][4][128]
#define O_WW2 9728      // 256: ww double-buffered [2][128]
#define O_USG 9984      // 128
#define O_PRC 10112     // 128
#define O_KEY 10720     // 256
#define O_WK  10976     // 64
#define O_ER  11040     // 64
#define O_WV  11104     // 64
#define O_RS  11168     // 4
#define O_FG  11172     // 4
#define O_MD  11176     // 12
#define O_NK  11188     // 4
#define O_SC  11192     // 8
#define O_NRM 11200     // 2 x 128 double-buffered row norms
#define O_WCW 11456     // 128
#define O_UU  11584     // 128
#define O_SU  11712     // 128
#define O_CUM 11840     // 128
#define O_RNK 11968     // 128 (int)
#define O_CCW 12096     // 512
#define O_RED 12608     // 16
#define O_PF  12624     // 4096: J fwd partials [8][4][128]
#define O_PB  16720     // 4096: J bwd partials [8][4][128]
#define O_PK  12624     // 2048: K partials [8][4][64] (aliases PF; disjoint phases)
#define O_LK  20816     // 128*129 link matrix
#define S_SZ  (20816 + NM*LKS)     // 37328 floats = 149,312 B; 1 block/CU
// gates role (disjoint):
#define G_RVS 264       // rv staging stride (264%32=8: 4 D-groups offset 8 banks)
#define G_ACC 8448      // [32][17]
#define G_C   8992      // [32][5]
#define G_H   9216      // [32][512] h(t-1) staging
#define G_OH  25600     // [32][5] out H-part partials (hoisted into B slack)
#define G_WRV 25760     // [16][256] wrv table in LDS (spill fix: frees 16 VGPRs)

__global__ __launch_bounds__(TPB) void dnc_pipe2(
    const float* __restrict__ x, const float* __restrict__ W_ih,
    const float* __restrict__ W_hh, const float* __restrict__ b_ih,
    const float* __restrict__ b_hh, const float* __restrict__ W_xi,
    const float* __restrict__ b_xi, const float* __restrict__ W_o,
    const float* __restrict__ b_o, float* __restrict__ out,
    float* __restrict__ ws)
{
    __shared__ __align__(16) float S[S_SZ];

    const int tid = threadIdx.x;
    const int wv  = tid >> 6;
    const int l   = tid & 63;
    const int bid = blockIdx.x;

    float* __restrict__ pubH  = ws + WS_PUBH;
    float* __restrict__ pubRV = ws + WS_PUBRV;
    float* __restrict__ pubXI = ws + WS_PUBXI;
    unsigned int* __restrict__ FLGD = (unsigned int*)(ws + WS_FLAGS);

    if (bid < NBATCH) {
        // ========================= STATE block =========================
        const int b = bid;
        float* lk = S+O_LK;
        float* mem = S+O_MEM;
        float* usg = S+O_USG;  float* prc = S+O_PRC;
        float* keys = S+O_KEY; float* wkey = S+O_WK; float* ers = S+O_ER;
        float* wvec = S+O_WV;  float* rstr = S+O_RS; float* fgte = S+O_FG;
        float* modes = S+O_MD; float* nkey = S+O_NK; float* sc = S+O_SC;
        float* nrm = S+O_NRM;  float* wcw = S+O_WCW;
        float* uu = S+O_UU;    float* su = S+O_SU;   float* cum = S+O_CUM;
        int*   rnk = (int*)(S+O_RNK);
        float* ccw = S+O_CCW;  float* red = S+O_RED;

        for (int e = tid; e < NM*LKS; e += TPB) lk[e] = 0.0f;
        for (int e = tid; e < NM*NW; e += TPB) mem[(e>>6)*MS + (e&63)] = EPSF;
        for (int e = tid; e < 2*NR*NM; e += TPB) S[O_RW2+e]=0.0f;
        for (int e = tid; e < 2*NM; e += TPB) S[O_WW2+e]=0.0f;
        for (int e = tid; e < NM; e += TPB){ usg[e]=0.0f; prc[e]=0.0f; }
        for (int e = tid; e < 2*NM; e += TPB) nrm[e] = 8.0f*EPSF; // ||EPS row||
        __syncthreads();

        for (int t = 0; t < NT; ++t) {
            const int par = t & 1;
            float* nmo = nrm + 128*par;            // old norms = prev step's new
            float* nmn = nrm + 128*(par^1);
            float* rwC = S + O_RW2 + 512*par;      // rw(t-1)
            float* rwN = S + O_RW2 + 512*(par^1);  // rw(t) written this step
            float* wwP = S + O_WW2 + 128*(par^1);  // ww(t-1)
            float* wwC = S + O_WW2 + 128*par;      // ww(t) written this step

            // P1+P2 fused: xi(t) ready; DIRECT coherent loads into unpack
            multi_wait_d(&FLGD[D_X], NXB, (unsigned)(t+1), tid);
            {
                const float* xb = pubXI + (size_t)par*NBATCH*480 + b*480;
                if (tid < 256)       keys[tid] = tanhf(cload1f(xb+tid));
                else if (tid < 260)  rstr[tid-256] = sftp(cload1f(xb+tid));
                else if (tid < 324)  wkey[tid-260] = tanhf(cload1f(xb+tid));
                else if (tid == 324) sc[0] = sftp(cload1f(xb+324));
                else if (tid < 389)  ers[tid-325] = sigm(cload1f(xb+tid));
                else if (tid < 453)  wvec[tid-389] = tanhf(cload1f(xb+tid));
                else if (tid < 457)  fgte[tid-453] = sigm(cload1f(xb+tid));
                else if (tid == 457) sc[1] = sigm(cload1f(xb+457));
                else if (tid == 458) sc[2] = sigm(cload1f(xb+458));
                else if (tid < 471) {
                    // tid 459..470 = wave 7 lanes 11..22 (all active here)
                    float xv = cload1f(xb + tid);
                    int r = tid - 459;             // 0..11
                    float a0 = __shfl(xv, 11 + 3*r);
                    float a1 = __shfl(xv, 12 + 3*r);
                    float a2 = __shfl(xv, 13 + 3*r);
                    if (r < 4) {
                        float mx = fmaxf(a0, fmaxf(a1, a2));
                        float e0=expf(a0-mx), e1=expf(a1-mx), e2=expf(a2-mx);
                        float si = 1.0f/(e0+e1+e2);
                        modes[3*r]=e0*si; modes[3*r+1]=e1*si; modes[3*r+2]=e2*si;
                    }
                }
            }
            __syncthreads();

            // P3: key norms (waves 0-4) ∥ usage+uu (waves 6-7)
            if (wv < 4) {
                float v = keys[wv*NW + l];
                float s2 = wave_red(v*v);
                if (l == 0) nkey[wv] = sqrtf(s2);
            } else if (wv == 4) {
                float v = wkey[l];
                float s2 = wave_red(v*v);
                if (l == 0) sc[3] = sqrtf(s2);
            } else if (wv == 6 || wv == 7) {
                int m = tid - 384;
                float u = usg[m];
                u = u + (1.0f - u)*wwP[m];
                float psi = 1.0f;
                #pragma unroll
                for (int r = 0; r < NR; ++r) psi *= (1.0f - fgte[r]*rwC[r*NM+m]);
                u *= psi;
                usg[m] = u;
                uu[m] = 5e-6f + (1.0f - 5e-6f)*u;
            }
            __syncthreads();

            // P4: F1 write-content logits — f4 reads, 8 thr/row
            {
                const int m = tid >> 3, s = tid & 7;
                const f4* mem4 = (const f4*)(S + O_MEM);
                const f4* wk4  = (const f4*)(S + O_WK);
                f4 m0 = mem4[m*MS4 + s*2], m1 = mem4[m*MS4 + s*2 + 1];
                f4 k0 = wk4[s*2], k1 = wk4[s*2 + 1];
                float d = dot4(m0, k0) + dot4(m1, k1);
                d += __shfl_down(d, 4); d += __shfl_down(d, 2); d += __shfl_down(d, 1);
                if (s == 0) wcw[m] = d/(sc[3]*nmo[m] + EPSF) * sc[0];
            }
            __syncthreads();

            // P5: wcw softmax (wave 0) ∥ G2 rank (waves 8-15)
            if (tid < 64) {
                float w0 = wcw[l], w1 = wcw[l+64];
                float mx = fmaxf(w0, w1);
                #pragma unroll
                for (int o = 32; o > 0; o >>= 1) mx = fmaxf(mx, __shfl_down(mx, o));
                float M = __shfl(mx, 0);
                float e0 = expf(w0 - M), e1 = expf(w1 - M);
                float s = wave_red(e0 + e1);
                float inv = 1.0f/__shfl(s, 0);
                wcw[l] = e0*inv; wcw[l+64] = e1*inv;
            } else if (tid >= 512) {
                const int q = tid - 512, m = q >> 2, s = q & 3;
                const float um = uu[m];
                int rk = 0;
                #pragma unroll 8
                for (int k = 0; k < 32; ++k) {
                    int j = 4*k + s;
                    float uj = uu[j];
                    rk += (uj < um) || (uj == um && j < m);
                }
                rk += __shfl_down(rk, 1); rk += __shfl_down(rk, 2);
                if (s == 0) { rnk[m] = rk; su[rk] = um; }
            }
            __syncthreads();

            // P6: product scan (wave 0)
            if (tid < 64) {
                float a = su[tid], bb = su[64+tid];
                #pragma unroll
                for (int o = 1; o < 64; o <<= 1) {
                    float ta = __shfl_up(a, o);
                    float tb = __shfl_up(bb, o);
                    if (tid >= o) { a *= ta; bb *= tb; }
                }
                float P0 = __shfl(a, 63);
                cum[tid] = a;
                cum[64+tid] = P0*bb;
            }
            __syncthreads();

            // P7: alloc + wwC + per-wave alloc-sum partials
            if (tid < NM) {
                int rk = rnk[tid];
                float excl = (rk == 0) ? 1.0f : cum[rk-1];
                float al = (1.0f - uu[tid])*excl;
                wwC[tid] = sc[2]*(sc[1]*al + (1.0f - sc[1])*wcw[tid]);
                float sal = wave_red(al);
                if (l == 0) red[2 + wv] = sal;
            }
            __syncthreads();

            // P8: sc[4] analytic + mem erase/write + nmn via 8-thread f4 groups
            if (tid == 1023)
                sc[4] = sc[2]*(sc[1]*(red[2]+red[3]) + (1.0f - sc[1]));
            #pragma unroll
            for (int ri = 0; ri < 8; ++ri) {
                int row = wv*8 + ri;
                float wm = wwC[row];
                float v = mem[row*MS + l];
                mem[row*MS + l] = v*(1.0f - wm*ers[l]) + wm*wvec[l];
            }
            {
                // same-wave norm: rows wv*8..wv*8+7 just written by THIS wave
                const int row = wv*8 + (l>>3);
                const f4* mem4 = (const f4*)(S + O_MEM);
                f4 m0 = mem4[row*MS4 + (l&7)*2];
                f4 m1 = mem4[row*MS4 + (l&7)*2 + 1];
                float s2 = dot4(m0,m0) + dot4(m1,m1);
                s2 += __shfl_down(s2, 4); s2 += __shfl_down(s2, 2);
                s2 += __shfl_down(s2, 1);
                if ((l & 7) == 0) nmn[row] = sqrtf(s2);
            }
            __syncthreads();

            // P9: I logits (waves 0-7, keys via broadcast b128)
            //     ∥ J row-scan + FUSED link update (waves 8-15, readlane-fed)
            if (tid < 512) {
                const int m = tid >> 2, s = tid & 3;
                const f4* mem4 = (const f4*)(S + O_MEM);
                const f4* key4 = (const f4*)(S + O_KEY);
                float a0=0.f, a1=0.f, a2=0.f, a3=0.f;
                #pragma unroll
                for (int c = 0; c < 4; ++c) {
                    f4 mv = mem4[m*MS4 + s*4 + c];
                    f4 k0 = key4[0*16 + s*4 + c];   // broadcast (4 addrs/wave)
                    f4 k1 = key4[1*16 + s*4 + c];
                    f4 k2 = key4[2*16 + s*4 + c];
                    f4 k3 = key4[3*16 + s*4 + c];
                    a0 += dot4(mv, k0); a1 += dot4(mv, k1);
                    a2 += dot4(mv, k2); a3 += dot4(mv, k3);
                }
                a0 += __shfl_down(a0,1); a0 += __shfl_down(a0,2);
                a1 += __shfl_down(a1,1); a1 += __shfl_down(a1,2);
                a2 += __shfl_down(a2,1); a2 += __shfl_down(a2,2);
                a3 += __shfl_down(a3,1); a3 += __shfl_down(a3,2);
                if (s == 0) {
                    float nm = nmn[m];
                    ccw[0*NM+m] = a0/(nkey[0]*nm + EPSF)*rstr[0];
                    ccw[1*NM+m] = a1/(nkey[1]*nm + EPSF)*rstr[1];
                    ccw[2*NM+m] = a2/(nkey[2]*nm + EPSF)*rstr[2];
                    ccw[3*NM+m] = a3/(nkey[3]*nm + EPSF)*rstr[3];
                }
            } else {
                const int wj = wv - 8;          // 0..7: i-chunk of 16
                const int i0 = wj*16;
                const float wmA = wwC[l], wmB = wwC[64+l];   // lane-local
                // per-wave preloads: lanes hold the 16-chunk of rw/prc/ww
                float srw  = rwC[(l>>4)*NM + i0 + (l&15)];
                float sprc = prc[i0 + (l&15)];
                float swwc = wwC[i0 + (l&15)];
                float fA0=0,fA1=0,fA2=0,fA3=0, fB0=0,fB1=0,fB2=0,fB3=0;
                #pragma unroll
                for (int ii = 0; ii < 16; ++ii) {
                    const int i = i0 + ii;
                    float pri = rdlane(sprc, ii);
                    float wwi = rdlane(swwc, ii);
                    float r0 = rdlane(srw, ii);
                    float r1 = rdlane(srw, 16+ii);
                    float r2 = rdlane(srw, 32+ii);
                    float r3 = rdlane(srw, 48+ii);
                    // row A: element (l, i) — update + use
                    float lrA = lk[l*LKS + i];
                    float nA = (i == l) ? 0.0f
                             : (1.0f - wmA - wwi)*lrA + wmA*pri;
                    lk[l*LKS + i] = nA;
                    // row B: element (l+64, i)
                    float lrB = lk[(l+64)*LKS + i];
                    float nB = (i == l+64) ? 0.0f
                             : (1.0f - wmB - wwi)*lrB + wmB*pri;
                    lk[(l+64)*LKS + i] = nB;
                    fA0 += nA*r0; fA1 += nA*r1; fA2 += nA*r2; fA3 += nA*r3;
                    fB0 += nB*r0; fB1 += nB*r1; fB2 += nB*r2; fB3 += nB*r3;
                }
                float* Pf = S + O_PF + wj*512;
                Pf[0*NM+l]=fA0; Pf[1*NM+l]=fA1; Pf[2*NM+l]=fA2; Pf[3*NM+l]=fA3;
                Pf[0*NM+64+l]=fB0; Pf[1*NM+64+l]=fB1;
                Pf[2*NM+64+l]=fB2; Pf[3*NM+64+l]=fB3;
            }
            __syncthreads();

            // P10: ccw softmax (waves 0-3) ∥ precedence (tid 256-383)
            //      ∥ J col-scan on NEW lk (waves 8-15, readlane-fed)
            if (tid < 256) {
                float v0 = ccw[wv*NM + l], v1 = ccw[wv*NM + 64 + l];
                float mx = fmaxf(v0, v1);
                #pragma unroll
                for (int o = 32; o > 0; o >>= 1) mx = fmaxf(mx, __shfl_down(mx, o));
                float M = __shfl(mx, 0);
                float e0 = expf(v0 - M), e1 = expf(v1 - M);
                float s = wave_red(e0 + e1);
                float inv = 1.0f/__shfl(s, 0);
                ccw[wv*NM + l] = e0*inv; ccw[wv*NM + 64 + l] = e1*inv;
            } else if (tid < 384) {
                int m = tid - 256;
                prc[m] = (1.0f - sc[4])*prc[m] + wwC[m];
            } else if (wv >= 8) {
                const int wj = wv - 8;
                const int i0 = wj*16;
                float srw = rwC[(l>>4)*NM + i0 + (l&15)];
                float bA0=0,bA1=0,bA2=0,bA3=0, bB0=0,bB1=0,bB2=0,bB3=0;
                #pragma unroll
                for (int ii = 0; ii < 16; ++ii) {
                    const int i = i0 + ii;
                    float r0 = rdlane(srw, ii);
                    float r1 = rdlane(srw, 16+ii);
                    float r2 = rdlane(srw, 32+ii);
                    float r3 = rdlane(srw, 48+ii);
                    float lcA = lk[i*LKS + l];       // col j=l (new lk)
                    float lcB = lk[i*LKS + 64 + l];  // col j=l+64
                    bA0 += lcA*r0; bA1 += lcA*r1; bA2 += lcA*r2; bA3 += lcA*r3;
                    bB0 += lcB*r0; bB1 += lcB*r1; bB2 += lcB*r2; bB3 += lcB*r3;
                }
                float* Pb = S + O_PB + wj*512;
                Pb[0*NM+l]=bA0; Pb[1*NM+l]=bA1; Pb[2*NM+l]=bA2; Pb[3*NM+l]=bA3;
                Pb[0*NM+64+l]=bB0; Pb[1*NM+64+l]=bB1;
                Pb[2*NM+64+l]=bB2; Pb[3*NM+64+l]=bB3;
            }
            __syncthreads();

            // P11: J-combine + mode mix -> rwN (new read weights, double-buffered)
            if (tid < 512) {
                const int r = tid >> 7, m = tid & 127;
                float fs = 0.0f, bs = 0.0f;
                #pragma unroll
                for (int c = 0; c < 8; ++c) {
                    fs += S[O_PF + c*512 + r*NM + m];
                    bs += S[O_PB + c*512 + r*NM + m];
                }
                rwN[r*NM + m] = modes[3*r]*bs + modes[3*r+1]*fs
                              + modes[3*r+2]*ccw[r*NM + m];
            }
            __syncthreads();

            // P12: K main (waves 0-7): lane=w, rwN via readlane
            if (wv < 8) {
                const int m0 = wv*16;
                float srn = rwN[(l>>4)*NM + m0 + (l&15)];
                float a0=0.f, a1=0.f, a2=0.f, a3=0.f;
                #pragma unroll
                for (int mm = 0; mm < 16; ++mm) {
                    const int m = m0 + mm;
                    float rn0 = rdlane(srn, mm);
                    float rn1 = rdlane(srn, 16+mm);
                    float rn2 = rdlane(srn, 32+mm);
                    float rn3 = rdlane(srn, 48+mm);
                    float mv = mem[m*MS + l];
                    a0 += rn0*mv; a1 += rn1*mv; a2 += rn2*mv; a3 += rn3*mv;
                }
                float* Pk = S + O_PK + wv*256;
                Pk[0*64+l]=a0; Pk[1*64+l]=a1; Pk[2*64+l]=a2; Pk[3*64+l]=a3;
            }
            __syncthreads();

            // P13: K reduce -> publish rv DIRECT to LLC (coalesced scalar stores)
            if (tid < 256) {
                const int r = tid >> 6, w = tid & 63;
                float s = 0.0f;
                #pragma unroll
                for (int c = 0; c < 8; ++c) s += S[O_PK + c*256 + r*64 + w];
                cstore1(&pubRV[(size_t)par*NBATCH*NR*NW + b*NR*NW + r*NW + w], s);
            }
            flag_set_d(&FLGD[D_R + b], (unsigned)(t+1), tid);
        }
    } else {
        // ===== GATES block: 4 units (16 gate rows) + LSTM + 4 xi + 4 out ====
        const int g = bid - 32;            // owns units u = 4g .. 4g+3
        const int gate = wv >> 2, j = wv & 3;
        const int r = gate*NH + 4*g + j;   // weight row: gate, unit 4g+j
        const f4* WA = (const f4*)(W_ih + (size_t)r*NI);
        f4 wx0 = WA[l], wx1 = WA[l+64];
        const f4* WB = (const f4*)(W_hh + (size_t)r*NH);
        f4 wh0 = WB[l], wh1 = WB[l+64];
        const float bias = b_ih[r] + b_hh[r];
        float* accS = S + G_ACC;   // [32][17]
        float* cSg  = S + G_C;     // [32][5]
        float* hStg = S + G_H;     // [32][512] h(t-1) staging
        float* oH   = S + G_OH;    // [32][5] out H-part (hoisted into B slack)
        const int sbi = tid >> 7, sk4 = (tid & 127) << 2;

        if (tid < 160) cSg[tid] = 0.0f;
        for (int e = tid; e < NBATCH*NH; e += TPB) hStg[e] = 0.0f;  // h(-1)=0
        // stage wrv (W_ih cols 512..767) into LDS once: frees 16 VGPRs (no spill)
        *(f4*)&S[G_WRV + wv*256 + l*4] = WA[128 + l];
        __syncthreads();

        for (int t = 0; t <= NT; ++t) {          // NT+1 iters (epilogue at NT)
            const int par = t & 1, parp = (t+1) & 1;   // parp = parity of t-1

            // A: stage ALL h(t-1); then xi(t-1) from our 8KB W_xi slice
            if (t >= 1) {
                multi_wait_d(&FLGD[D_G], 128, (unsigned)t, tid);   // h(t-1) all
                const float* hIn = pubH + (size_t)parp*NBATCH*NH;
                f4 a0, a1, a2, a3;
                cload4x4(hIn + tid*4, hIn + (tid+1024)*4,
                         hIn + (tid+2048)*4, hIn + (tid+3072)*4,
                         a0, a1, a2, a3);
                *(f4*)&hStg[tid*4]          = a0;
                *(f4*)&hStg[(tid+1024)*4]   = a1;
                *(f4*)&hStg[(tid+2048)*4]   = a2;
                *(f4*)&hStg[(tid+3072)*4]   = a3;
                __syncthreads();
                if (g < NXB) {
                    float* xOut = pubXI + (size_t)parp*NBATCH*480;
                    #pragma unroll
                    for (int bb = 0; bb < 2; ++bb) {
                        const int bi = 2*wv + bb;
                        const f4* H4 = (const f4*)(hStg + bi*512);
                        f4 res = {0.0f, 0.0f, 0.0f, 0.0f};
                        #pragma unroll
                        for (int jj = 0; jj < 4; ++jj) {
                            const int row = 4*g + jj;
                            if (row < NXI) {
                                const f4* WX = (const f4*)(W_xi + (size_t)row*NH);
                                float a = dot4(WX[l], H4[l])
                                        + dot4(WX[l+64], H4[l+64]);
                                a = wave_red(a);
                                res[jj] = a + b_xi[row];
                            }
                        }
                        if (l == 0) cstore4(&xOut[(size_t)bi*480 + 4*g], res);
                    }
                    flag_set_d(&FLGD[D_X + g], (unsigned)t, tid);
                }
            }

            // B: heavy phase x(t)·W_ih + h(t-1)·W_hh + out-H hoist (slack)
            if (t < NT) {
                for (int p = 0; p < 4; ++p) {
                    const int b0 = p*8;
                    *(f4*)&S[sbi*512 + sk4] =
                        *(const f4*)&x[((size_t)(b0+sbi)*NT + t)*NH + sk4];
                    __syncthreads();
                    #pragma unroll
                    for (int bi = 0; bi < 8; ++bi) {
                        const f4* X4 = (const f4*)(S + bi*512);
                        const f4* H4 = (const f4*)(hStg + (b0+bi)*512);
                        float a = dot4(wx0, X4[l]) + dot4(wx1, X4[l+64])
                                + dot4(wh0, H4[l]) + dot4(wh1, H4[l+64]);
                        a = wave_red(a);
                        if (l == 0) accS[(b0+bi)*17 + wv] = a + bias;
                    }
                    __syncthreads();
                }
                // B-tail: out(t-1) H-part from hStg (= h(t-1)) — off-chain
                #pragma unroll
                for (int bb = 0; bb < 2; ++bb) {
                    const int bi = 2*wv + bb;
                    const f4* H4 = (const f4*)(hStg + bi*512);
                    #pragma unroll
                    for (int jj = 0; jj < 4; ++jj) {
                        const int row = 4*g + jj;
                        const f4* WO = (const f4*)(W_o + (size_t)row*NI);
                        float a = dot4(WO[l], H4[l]) + dot4(WO[l+64], H4[l+64]);
                        a = wave_red(a);
                        if (l == 0) oH[bi*5 + jj] = a;
                    }
                }
            }

            // C: rv(t-1) — the critical-path input (staged at stride 264)
            {
                const int bi0 = tid >> 6, k40 = (tid & 63) << 2;
                if (t >= 1) {
                    multi_wait_d(&FLGD[D_R], 32, (unsigned)t, tid);
                    const float* rIn = pubRV + (size_t)parp*NBATCH*NR*NW;
                    f4 a0, a1;
                    cload4x2(&rIn[bi0*256 + k40], &rIn[(bi0+16)*256 + k40], a0, a1);
                    *(f4*)&S[bi0*G_RVS + k40] = a0;
                    *(f4*)&S[(bi0+16)*G_RVS + k40] = a1;
                } else {
                    f4 z = {0.0f, 0.0f, 0.0f, 0.0f};
                    *(f4*)&S[bi0*G_RVS + k40] = z;
                    *(f4*)&S[(bi0+16)*G_RVS + k40] = z;
                }
            }
            __syncthreads();

            // D: rv dot in 16-lane groups — lane-contiguous b128 (conflict-free),
            //    wrv from LDS table (broadcast) + LSTM + publish h(t)
            if (t < NT) {
                const int grp = l >> 4, qv = l & 15;
                const f4* wrvT4 = (const f4*)(S + G_WRV + wv*256);
                #pragma unroll
                for (int p = 0; p < 8; ++p) {
                    const int bi = p*4 + grp;
                    const f4* RV4 = (const f4*)(S + bi*G_RVS);
                    float d = dot4(wrvT4[qv],      RV4[qv])
                            + dot4(wrvT4[16+qv],   RV4[16+qv])
                            + dot4(wrvT4[32+qv],   RV4[32+qv])
                            + dot4(wrvT4[48+qv],   RV4[48+qv]);
                    d += __shfl_down(d, 8); d += __shfl_down(d, 4);
                    d += __shfl_down(d, 2); d += __shfl_down(d, 1);
                    if (qv == 0) accS[bi*17 + wv] += d;
                }
                __syncthreads();
                if (tid < 32) {
                    const int bi = tid;
                    const float* acc = accS + bi*17;
                    f4 hq;
                    #pragma unroll
                    for (int jj = 0; jj < 4; ++jj) {
                        float i_ = sigm(acc[0*4 + jj]);
                        float f_ = sigm(acc[1*4 + jj]);
                        float g_ = tanhf(acc[2*4 + jj]);
                        float o_ = sigm(acc[3*4 + jj]);
                        float c  = f_*cSg[bi*5 + jj] + i_*g_;
                        cSg[bi*5 + jj] = c;
                        hq[jj] = o_*tanhf(c);
                    }
                    cstore4(&pubH[(size_t)par*NBATCH*NH + (size_t)bi*NH + 4*g], hq);
                }
                flag_set_d(&FLGD[D_G + g], (unsigned)(t+1), tid);
            }

            // E: out(t-1) = hoisted H-part + rv-part (short on-chain segment)
            if (t >= 1) {
                #pragma unroll
                for (int bb = 0; bb < 2; ++bb) {
                    const int bi = 2*wv + bb;
                    const f4* H4 = (const f4*)(hStg + bi*512);
                    const f4* RV4 = (const f4*)(S + bi*G_RVS);
                    f4 res;
                    #pragma unroll
                    for (int jj = 0; jj < 4; ++jj) {
                        const int row = 4*g + jj;
                        const f4* WO = (const f4*)(W_o + (size_t)row*NI);
                        float a = dot4(WO[128+l], RV4[l]);
                        if (t == NT) {
                            // epilogue: B didn't run; hStg = h(NT-1), compute
                            a += dot4(WO[l], H4[l]) + dot4(WO[l+64], H4[l+64]);
                        }
                        a = wave_red(a);
                        if (l == 0) {
                            float hp = (t < NT) ? oH[bi*5 + jj] : 0.0f;
                            res[jj] = a + hp + b_o[row];
                        }
                    }
                    if (l == 0)
                        *(f4*)&out[((size_t)bi*NT + (t-1))*NH + 4*g] = res;
                }
            }
        }
    }
}

extern "C" void kernel_launch(void* const* d_in, const int* in_sizes, int n_in,
                              void* d_out, int out_size, void* d_ws, size_t ws_size,
                              hipStream_t stream) {
    (void)in_sizes; (void)n_in; (void)out_size; (void)ws_size;
    const float* x    = (const float*)d_in[0];
    const float* W_ih = (const float*)d_in[1];
    const float* W_hh = (const float*)d_in[2];
    const float* b_ih = (const float*)d_in[3];
    const float* b_hh = (const float*)d_in[4];
    const float* W_xi = (const float*)d_in[5];
    const float* b_xi = (const float*)d_in[6];
    const float* W_o  = (const float*)d_in[7];
    const float* b_o  = (const float*)d_in[8];
    float* out = (float*)d_out;
    float* ws  = (float*)d_ws;

    dnc_zero<<<1, 512, 0, stream>>>(ws);

    void* args[] = { (void*)&x, (void*)&W_ih, (void*)&W_hh, (void*)&b_ih,
                     (void*)&b_hh, (void*)&W_xi, (void*)&b_xi, (void*)&W_o,
                     (void*)&b_o, (void*)&out, (void*)&ws };
    hipLaunchCooperativeKernel((void*)dnc_pipe2, dim3(NBLK), dim3(TPB),
                               args, 0, stream);
}